// Round 15
// baseline (665.221 us; speedup 1.0000x reference)
//
#include <hip/hip_runtime.h>
#include <hip/hip_bf16.h>
#include <math.h>

// Problem constants
#define NTR   7680      // N*T
#define NJ    25
#define NKEEP 17
#define NDRP  8
#define NL    19
#define NROW  192000    // NT*J == N*J*T
#define NTT   120
#define RSP   24        // padded rows per r in spatial block

typedef __attribute__((ext_vector_type(8))) short bf16x8;
typedef __attribute__((ext_vector_type(4))) float f32x4;

// fast gelu: v * sigmoid(1.5957691*v*(1+0.044715*v^2)); NaN-safe at both tails.
__device__ __forceinline__ float gelu_fast(float v){
    float u = v * (1.f + 0.044715f * v * v) * 1.5957691216057308f;
    return v / (1.f + __expf(-u));
}
__device__ __forceinline__ unsigned short f2bf(float v){
    union { __hip_bfloat16 h; unsigned short u; } c;
    c.h = __float2bfloat16(v);
    return c.u;
}
__device__ __forceinline__ float bf2f(unsigned short u){
    union { unsigned u; float f; } a; a.u = ((unsigned)u) << 16; return a.f;
}

// ---------------------------------------------------------------- all weight preprocessing in one kernel
// Norm-folding: WinB *= sn1w[k], F1B *= sn2w[k] (k = input channel)
__global__ void k_prep(const float* __restrict__ s_in_w, const float* __restrict__ s_out_w,
                       const float* __restrict__ s_f1w,  const float* __restrict__ s_f2w,
                       const float* __restrict__ t_in_w, const float* __restrict__ t_out_w,
                       const float* __restrict__ t_f1w,  const float* __restrict__ t_f2w,
                       const float* __restrict__ gcnw,
                       const float* __restrict__ sn1w,   const float* __restrict__ sn2w,
                       unsigned short* __restrict__ WM)
{
    int i = blockIdx.x * 256 + threadIdx.x;
    if (i < 65536){
        const float* src;
        const float* nw = nullptr;
        int base;
        if      (i < 12288){ src = s_in_w;  base = 0;     nw = sn1w; }
        else if (i < 16384){ src = s_out_w; base = 12288; }
        else if (i < 24576){ src = s_f1w;   base = 16384; nw = sn2w; }
        else if (i < 32768){ src = s_f2w;   base = 24576; }
        else if (i < 45056){ src = t_in_w;  base = 32768; }
        else if (i < 49152){ src = t_out_w; base = 45056; }
        else if (i < 57344){ src = t_f1w;   base = 49152; }
        else               { src = t_f2w;   base = 57344; }
        int loc = i - base;
        float4 v = *(const float4*)(src + loc * 4);
        if (nw){
            float4 w = *(const float4*)(nw + ((loc * 4) & 127));
            v.x *= w.x; v.y *= w.y; v.z *= w.z; v.w *= w.w;
        }
        ushort4 o; o.x = f2bf(v.x); o.y = f2bf(v.y); o.z = f2bf(v.z); o.w = f2bf(v.w);
        *(ushort4*)(WM + i * 4) = o;
    } else if (i < 81920){
        int j = i - 65536;                 // gcn transpose: 16384 elems
        int d = j >> 7, c = j & 127;
        WM[262144 + d * 128 + c] = f2bf(gcnw[c * 128 + d]);
    }
}

// ---------------------------------------------------------------- GCN + RMSNorm (MFMA, fused stats, bf16 out)
__global__ __launch_bounds__(256, 3) void k_gcn_mfma(
    const float* __restrict__ x, const unsigned short* __restrict__ GWt,
    const float* __restrict__ gnw, unsigned short* __restrict__ xg)
{
    __shared__ __align__(16) unsigned short xb[64 * 136];
    __shared__ __align__(16) float yf[64 * 132];
    __shared__ float ssq[64];
    __shared__ float rstd[64];
    int tid = threadIdx.x, wv = tid >> 6, lane = tid & 63, cl = lane & 15, g = lane >> 4;
    size_t row0 = (size_t)blockIdx.x * 64;

    if (tid < 64) ssq[tid] = 0.f;
    const float4* x4 = (const float4*)(x + row0 * 128);
    for (int i = tid; i < 2048; i += 256){
        int row = i >> 5, ch = i & 31;
        float4 v = x4[row * 32 + ch];
        ushort4 o; o.x = f2bf(v.x); o.y = f2bf(v.y); o.z = f2bf(v.z); o.w = f2bf(v.w);
        *(ushort4*)(xb + row * 136 + ch * 4) = o;
    }
    __syncthreads();
    for (int job = wv; job < 32; job += 4){
        int rt = job >> 3, ct = job & 7, col = ct * 16 + cl;
        f32x4 acc = {0.f, 0.f, 0.f, 0.f};
        #pragma unroll
        for (int ks = 0; ks < 4; ks++){
            bf16x8 a = *(const bf16x8*)(xb + (rt*16 + cl)*136 + ks*32 + g*8);
            bf16x8 b = *(const bf16x8*)(GWt + col*128 + ks*32 + g*8);
            acc = __builtin_amdgcn_mfma_f32_16x16x32_bf16(a, b, acc, 0, 0, 0);
        }
        #pragma unroll
        for (int reg = 0; reg < 4; reg++){
            int row = rt*16 + g*4 + reg;
            float v = acc[reg];
            yf[row*132 + col] = v;
            float p = v * v;
            p += __shfl_xor(p, 1, 64); p += __shfl_xor(p, 2, 64);
            p += __shfl_xor(p, 4, 64); p += __shfl_xor(p, 8, 64);
            if (cl == 0) atomicAdd(&ssq[row], p);
        }
    }
    __syncthreads();
    if (tid < 64) rstd[tid] = rsqrtf(ssq[tid] * 0.0078125f + 1e-6f);
    __syncthreads();
    for (int i = tid; i < 2048; i += 256){
        int row = i >> 5, ch = i & 31;
        float4 v = *(const float4*)(yf + row*132 + ch*4);
        float4 w4 = *(const float4*)(gnw + ch*4);
        float r = rstd[row];
        ushort4 u;
        u.x = f2bf(v.x * r * w4.x); u.y = f2bf(v.y * r * w4.y);
        u.z = f2bf(v.z * r * w4.z); u.w = f2bf(v.w * r * w4.w);
        *(ushort4*)(xg + (row0 + row)*128 + ch*4) = u;
    }
}

// ---------------------------------------------------------------- per-row token selection
__global__ void k_select(const float* __restrict__ sc, int* __restrict__ order,
                         int* __restrict__ slot, float* __restrict__ ph){
    int r = blockIdx.x * blockDim.x + threadIdx.x;
    if (r >= NTR) return;
    float s[NJ]; int id[NJ];
    for (int j = 0; j < NJ; j++){ s[j] = sc[r * NJ + j]; id[j] = j; }
    for (int m = 1; m < NJ; m++){
        float sv = s[m]; int iv = id[m]; int p = m;
        while (p > 0 && s[p-1] < sv){ s[p] = s[p-1]; id[p] = id[p-1]; p--; }
        s[p] = sv; id[p] = iv;
    }
    for (int j = 0; j < NJ; j++) order[r * NJ + j] = id[j];
    for (int i = 0; i < NKEEP; i++)  slot[r * NJ + id[i]] = 1 + i;
    for (int i = NKEEP; i < NJ; i++) slot[r * NJ + id[i]] = 18;
    float m8 = s[NKEEP];
    float e[NDRP]; float sum = 0.f;
    for (int i = 0; i < NDRP; i++){ e[i] = expf(s[NKEEP + i] - m8); sum += e[i]; }
    float inv = 1.f / sum;
    for (int i = 0; i < NDRP; i++) ph[r * NDRP + i] = e[i] * inv;
}

// ---------------------------------------------------------------- spatial transformer v8: fewer barriers
// sm u16 layout: xs[48][136] | Pb[8][32][40] | qk[48][264] | U2: vT[8][32][40] / ao[48][136]
__global__ __launch_bounds__(512, 4) void k_spatial8(
    const unsigned short* __restrict__ xg, const int* __restrict__ order, const float* __restrict__ ph,
    const float* __restrict__ cls_tok,
    const unsigned short* __restrict__ WinB, const float* __restrict__ inb,
    const unsigned short* __restrict__ WoutB, const float* __restrict__ outb,
    const unsigned short* __restrict__ F1B, const float* __restrict__ f1b,
    const unsigned short* __restrict__ F2B, const float* __restrict__ f2b,
    unsigned short* __restrict__ delta, float* __restrict__ next_attn)
{
    __shared__ __align__(16) unsigned short sm[39680];
    __shared__ float rstd[48];
    __shared__ float ss2[48];
    __shared__ float clsp[8][20];
    __shared__ int   ord_s[2][NJ];
    __shared__ float ph_s[2][NDRP];
    unsigned short* xs = sm;             // [48][136] x_slow -> x_msa
    unsigned short* Pb = sm + 6528;      // [8][32][40]
    unsigned short* qk = sm + 16768;     // [48][264]
    unsigned short* vT = sm + 29440;     // [8][32][40]
    unsigned short* ao = sm + 29440;     // [48][136] overlays vT

    int tid = threadIdx.x;
    int r0 = blockIdx.x * 2;
    int wv = tid >> 6, lane = tid & 63, cl = lane & 15, g = lane >> 4;
    const float scale = 0.17677669529663687f;

    if (tid < 2*NJ)   ord_s[tid/NJ][tid%NJ] = order[(r0 + tid/NJ)*NJ + tid%NJ];
    if (tid < 2*NDRP) ph_s[tid>>3][tid&7]   = ph[(r0 + (tid>>3))*NDRP + (tid&7)];
    if (tid < 48) ss2[tid] = 0.f;
    for (int i = tid; i < 1280; i += 512)
        *(uint4*)(vT + i*8) = make_uint4(0,0,0,0);   // zero U2 (pad keys must be 0)
    __syncthreads();   // ord_s/ph_s visible before gather

    // ---- build x_slow (bf16 gather) + fused rmsnorm1 stats (32 lanes per row) ----
    {
        int ln = tid & 31;
        for (int j = tid >> 5; j < 48; j += 16){
            int rr = j / RSP, t = j - rr * RSP;
            const unsigned short* xgr = xg + (size_t)(r0 + rr) * NJ * 128;
            float v0, v1, v2, v3;
            if (t == 0){
                float4 cv = *(const float4*)(cls_tok + ln*4);
                v0 = cv.x; v1 = cv.y; v2 = cv.z; v3 = cv.w;
            } else if (t <= NKEEP){
                ushort4 u = *(const ushort4*)(xgr + ord_s[rr][t-1]*128 + ln*4);
                v0 = bf2f(u.x); v1 = bf2f(u.y); v2 = bf2f(u.z); v3 = bf2f(u.w);
            } else if (t == 18){
                v0 = v1 = v2 = v3 = 0.f;
                for (int i = 0; i < NDRP; i++){
                    ushort4 u = *(const ushort4*)(xgr + ord_s[rr][NKEEP+i]*128 + ln*4);
                    float w = ph_s[rr][i];
                    v0 = fmaf(bf2f(u.x),w,v0); v1 = fmaf(bf2f(u.y),w,v1);
                    v2 = fmaf(bf2f(u.z),w,v2); v3 = fmaf(bf2f(u.w),w,v3);
                }
            } else { v0 = v1 = v2 = v3 = 0.f; }
            ushort4 o4; o4.x=f2bf(v0); o4.y=f2bf(v1); o4.z=f2bf(v2); o4.w=f2bf(v3);
            *(ushort4*)(xs + j*136 + ln*4) = o4;
            float p = v0*v0 + v1*v1 + v2*v2 + v3*v3;
            p += __shfl_xor(p, 1, 64); p += __shfl_xor(p, 2, 64);
            p += __shfl_xor(p, 4, 64); p += __shfl_xor(p, 8, 64);
            p += __shfl_xor(p, 16, 64);
            if (ln == 0) rstd[j] = rsqrtf(p * 0.0078125f + 1e-6f);
        }
    }
    __syncthreads();

    // ---- qkv GEMM on RAW xs (sn1w folded into WinB); epilogue scales by rstd[row] ----
    {
        int col = wv*16 + cl;
        bf16x8 Bq[4], Bk[4], Bv[4];
        #pragma unroll
        for (int ks = 0; ks < 4; ks++){
            Bq[ks] = *(const bf16x8*)(WinB + col*128        + ks*32 + g*8);
            Bk[ks] = *(const bf16x8*)(WinB + (128+col)*128  + ks*32 + g*8);
            Bv[ks] = *(const bf16x8*)(WinB + (256+col)*128  + ks*32 + g*8);
        }
        float bq = inb[col], bk = inb[128+col], bv = inb[256+col];
        int h = col >> 5, d = col & 31;
        #pragma unroll
        for (int rt = 0; rt < 3; rt++){
            bf16x8 A[4];
            #pragma unroll
            for (int ks = 0; ks < 4; ks++)
                A[ks] = *(const bf16x8*)(xs + (rt*16 + cl)*136 + ks*32 + g*8);
            f32x4 aq = {0,0,0,0}, ak = {0,0,0,0}, av = {0,0,0,0};
            #pragma unroll
            for (int ks = 0; ks < 4; ks++){
                aq = __builtin_amdgcn_mfma_f32_16x16x32_bf16(A[ks], Bq[ks], aq, 0, 0, 0);
                ak = __builtin_amdgcn_mfma_f32_16x16x32_bf16(A[ks], Bk[ks], ak, 0, 0, 0);
                av = __builtin_amdgcn_mfma_f32_16x16x32_bf16(A[ks], Bv[ks], av, 0, 0, 0);
            }
            #pragma unroll
            for (int reg = 0; reg < 4; reg++){
                int row = rt*16 + g*4 + reg;
                float rs = rstd[row];
                qk[row*264 + col]       = f2bf((aq[reg]*rs + bq) * scale);
                qk[row*264 + 128 + col] = f2bf(ak[reg]*rs + bk);
                int rr = row >= RSP; int key = row - rr*RSP;
                vT[(rr*4 + h)*1280 + d*40 + key] = f2bf(av[reg]*rs + bv);
            }
        }
    }
    __syncthreads();

    // ---- attention: 1 (rr,h) pair per wave; P region is per-wave -> NO mid barrier ----
    {
        int qh = wv;
        int rr = qh >> 2, h = qh & 3;
        bf16x8 aq[2];
        #pragma unroll
        for (int qt = 0; qt < 2; qt++)
            aq[qt] = *(const bf16x8*)(qk + (rr*RSP + qt*16 + cl)*264 + h*32 + g*8);
        f32x4 lg[2][2];
        #pragma unroll
        for (int kt = 0; kt < 2; kt++){
            bf16x8 bk = *(const bf16x8*)(qk + (rr*RSP + kt*16 + cl)*264 + 128 + h*32 + g*8);
            f32x4 z = {0.f, 0.f, 0.f, 0.f};
            lg[0][kt] = __builtin_amdgcn_mfma_f32_16x16x32_bf16(aq[0], bk, z, 0, 0, 0);
            lg[1][kt] = __builtin_amdgcn_mfma_f32_16x16x32_bf16(aq[1], bk, z, 0, 0, 0);
        }
        #pragma unroll
        for (int qt = 0; qt < 2; qt++){
            #pragma unroll
            for (int reg = 0; reg < 4; reg++){
                float l0 = lg[qt][0][reg];
                float l1 = (cl >= 3) ? -1e30f : lg[qt][1][reg];
                float m = fmaxf(l0, l1);
                m = fmaxf(m, __shfl_xor(m, 1, 64));
                m = fmaxf(m, __shfl_xor(m, 2, 64));
                m = fmaxf(m, __shfl_xor(m, 4, 64));
                m = fmaxf(m, __shfl_xor(m, 8, 64));
                float e0 = __expf(l0 - m), e1 = __expf(l1 - m);
                float ssum = e0 + e1;
                ssum += __shfl_xor(ssum, 1, 64); ssum += __shfl_xor(ssum, 2, 64);
                ssum += __shfl_xor(ssum, 4, 64); ssum += __shfl_xor(ssum, 8, 64);
                float inv = 1.f / ssum;
                e0 *= inv; e1 *= inv;
                int q = qt*16 + g*4 + reg;
                Pb[qh*1280 + q*40 + cl]      = f2bf(e0);
                Pb[qh*1280 + q*40 + 16 + cl] = f2bf(e1);
                if (qt == 0 && g == 0 && reg == 0){
                    clsp[qh][cl] = e0;
                    if (cl < 4) clsp[qh][16 + cl] = e1;
                }
            }
        }
        // no barrier: Pb[qh] and vT[qh] consumed only by this wave; PV writes only
        // the qk columns (h*32..) that this wave alone read as Q.
        bf16x8 ap[2];
        #pragma unroll
        for (int qt = 0; qt < 2; qt++)
            ap[qt] = *(const bf16x8*)(Pb + qh*1280 + (qt*16 + cl)*40 + g*8);
        #pragma unroll
        for (int dt = 0; dt < 2; dt++){
            bf16x8 bv = *(const bf16x8*)(vT + qh*1280 + (dt*16 + cl)*40 + g*8);
            #pragma unroll
            for (int qt = 0; qt < 2; qt++){
                f32x4 z = {0.f, 0.f, 0.f, 0.f};
                f32x4 oa = __builtin_amdgcn_mfma_f32_16x16x32_bf16(ap[qt], bv, z, 0, 0, 0);
                #pragma unroll
                for (int reg = 0; reg < 4; reg++){
                    int q = qt*16 + g*4 + reg;
                    if (q < 19)
                        qk[(rr*RSP + q)*264 + h*32 + dt*16 + cl] = f2bf(oa[reg]);
                    else if (q < RSP)
                        qk[(rr*RSP + q)*264 + h*32 + dt*16 + cl] = 0;
                }
            }
        }
        __syncthreads();
    }

    // ---- next_attn ----
    if (tid < 36){
        int rr2 = tid / 18, t = tid - rr2*18;
        float v = 0.25f * (clsp[rr2*4+0][1+t] + clsp[rr2*4+1][1+t] +
                           clsp[rr2*4+2][1+t] + clsp[rr2*4+3][1+t]);
        int r = r0 + rr2;
        if (t < NKEEP) next_attn[r*NJ + ord_s[rr2][t]] = v;
        else { for (int i = 0; i < NDRP; i++) next_attn[r*NJ + ord_s[rr2][NKEEP+i]] = v; }
    }

    // ---- out-proj: B resident; fused rmsnorm2 stats on x_msa ----
    {
        int col = wv*16 + cl;
        bf16x8 B[4];
        #pragma unroll
        for (int ks = 0; ks < 4; ks++)
            B[ks] = *(const bf16x8*)(WoutB + col*128 + ks*32 + g*8);
        float bias = outb[col];
        #pragma unroll
        for (int rt = 0; rt < 3; rt++){
            bf16x8 A[4];
            #pragma unroll
            for (int ks = 0; ks < 4; ks++)
                A[ks] = *(const bf16x8*)(qk + (rt*16 + cl)*264 + ks*32 + g*8);
            f32x4 acc = {0,0,0,0};
            #pragma unroll
            for (int ks = 0; ks < 4; ks++)
                acc = __builtin_amdgcn_mfma_f32_16x16x32_bf16(A[ks], B[ks], acc, 0, 0, 0);
            #pragma unroll
            for (int reg = 0; reg < 4; reg++){
                int row = rt*16 + g*4 + reg;
                float v = acc[reg] + bias;
                float msa = bf2f(xs[row*136 + col]) + v;
                ao[row*136 + col] = f2bf(v);
                xs[row*136 + col] = f2bf(msa);
                float p = msa * msa;
                p += __shfl_xor(p, 1, 64); p += __shfl_xor(p, 2, 64);
                p += __shfl_xor(p, 4, 64); p += __shfl_xor(p, 8, 64);
                if (cl == 0) atomicAdd(&ss2[row], p);
            }
        }
    }
    __syncthreads();

    if (tid < 48) rstd[tid] = rsqrtf(ss2[tid] * 0.0078125f + 1e-6f);
    __syncthreads();

    // ---- ffn1 + gelu on RAW x_msa (sn2w folded into F1B); epilogue scales by rstd[row] ----
    {
        int c0 = wv*16 + cl, c1 = c0 + 128;
        bf16x8 B0[4], B1[4];
        #pragma unroll
        for (int ks = 0; ks < 4; ks++){
            B0[ks] = *(const bf16x8*)(F1B + c0*128 + ks*32 + g*8);
            B1[ks] = *(const bf16x8*)(F1B + c1*128 + ks*32 + g*8);
        }
        float b0 = f1b[c0], b1 = f1b[c1];
        #pragma unroll
        for (int rt = 0; rt < 3; rt++){
            bf16x8 A[4];
            #pragma unroll
            for (int ks = 0; ks < 4; ks++)
                A[ks] = *(const bf16x8*)(xs + (rt*16 + cl)*136 + ks*32 + g*8);
            f32x4 a0 = {0,0,0,0}, a1 = {0,0,0,0};
            #pragma unroll
            for (int ks = 0; ks < 4; ks++){
                a0 = __builtin_amdgcn_mfma_f32_16x16x32_bf16(A[ks], B0[ks], a0, 0, 0, 0);
                a1 = __builtin_amdgcn_mfma_f32_16x16x32_bf16(A[ks], B1[ks], a1, 0, 0, 0);
            }
            #pragma unroll
            for (int reg = 0; reg < 4; reg++){
                int row = rt*16 + g*4 + reg;
                float rs = rstd[row];
                qk[row*264 + c0] = f2bf(gelu_fast(a0[reg]*rs + b0));
                qk[row*264 + c1] = f2bf(gelu_fast(a1[reg]*rs + b1));
            }
        }
    }
    __syncthreads();

    // ---- ffn2 + delta: B resident (8 k-slices) ----
    {
        int col = wv*16 + cl;
        bf16x8 B[8];
        #pragma unroll
        for (int ks = 0; ks < 8; ks++)
            B[ks] = *(const bf16x8*)(F2B + col*256 + ks*32 + g*8);
        float bias = f2b[col];
        #pragma unroll
        for (int rt = 0; rt < 3; rt++){
            bf16x8 A[8];
            #pragma unroll
            for (int ks = 0; ks < 8; ks++)
                A[ks] = *(const bf16x8*)(qk + (rt*16 + cl)*264 + ks*32 + g*8);
            f32x4 acc = {0,0,0,0};
            #pragma unroll
            for (int ks = 0; ks < 8; ks++)
                acc = __builtin_amdgcn_mfma_f32_16x16x32_bf16(A[ks], B[ks], acc, 0, 0, 0);
            #pragma unroll
            for (int reg = 0; reg < 4; reg++){
                int row = rt*16 + g*4 + reg;
                int rr = row >= RSP; int tok = row - rr*RSP;
                if (tok < 19){
                    float dv = acc[reg] + bias + bf2f(ao[row*136 + col]);
                    delta[((size_t)(r0 + rr)*19 + tok)*128 + col] = f2bf(dv);
                }
            }
        }
    }
}

// ---------------------------------------------------------------- scatter: bf16 xg in, bf16 xsp out
__global__ void k_scatter3(const unsigned short* __restrict__ xg, const unsigned short* __restrict__ delta,
                           const int* __restrict__ slot, unsigned short* __restrict__ xb){
    int i = blockIdx.x * 256 + threadIdx.x;   // 6,144,000 quads
    int e = i * 4;
    int c = e & 127; int rem = e >> 7;
    int t = rem % NTT; int nj = rem / NTT; int j = nj % NJ; int n = nj / NJ;
    int r = n * NTT + t;
    int sl = slot[r * NJ + j];
    ushort4 xv = *(const ushort4*)(xg + ((size_t)r * NJ + j) * 128 + c);
    ushort4 dv = *(const ushort4*)(delta + ((size_t)r * 19 + sl) * 128 + c);
    ushort4 ob;
    ob.x = f2bf(2.f * bf2f(xv.x) + bf2f(dv.x));
    ob.y = f2bf(2.f * bf2f(xv.y) + bf2f(dv.y));
    ob.z = f2bf(2.f * bf2f(xv.z) + bf2f(dv.z));
    ob.w = f2bf(2.f * bf2f(xv.w) + bf2f(dv.w));
    *(ushort4*)(xb + e) = ob;
}

// ---------------------------------------------------------------- temporal attention: 4 waves per (nj, head), bf16 out
// P region is per-wave -> NO barriers in the attention loop (waves drift freely)
__global__ __launch_bounds__(256, 3) void k_tattn2(
    const unsigned short* __restrict__ xb, const unsigned short* __restrict__ Wb,
    const float* __restrict__ inb, unsigned short* __restrict__ o)
{
    // LDS u16: q[120][40] | k[120][40] | vT[32][136] | P[4][16][136] = 45,312 B
    __shared__ __align__(16) unsigned short smem[22656];
    unsigned short* q_s = smem;
    unsigned short* k_s = smem + 4800;
    unsigned short* vT  = smem + 9600;
    unsigned short* P_s = smem + 13952;

    int tid = threadIdx.x;
    int l = tid & 63, cl = l & 15, g = l >> 4, wv = tid >> 6;
    int nj = blockIdx.x >> 2;
    int h  = blockIdx.x & 3;

    vT[(tid >> 3) * 136 + 120 + (tid & 7)] = 0;   // zero pad key cols

    const unsigned short* xrow = xb + (size_t)nj * (NTT * 128);
    const float scale = 0.17677669529663687f;

    bf16x8 bfr[6][4];
    float bias[6];
    #pragma unroll
    for (int pc = 0; pc < 6; ++pc){
        int p = pc >> 1, s = pc & 1;
        int col = p * 128 + h * 32 + s * 16 + cl;
        bias[pc] = inb[col];
        #pragma unroll
        for (int ks = 0; ks < 4; ++ks)
            bfr[pc][ks] = *(const bf16x8*)(Wb + col * 128 + ks * 32 + g * 8);
    }

    for (int mt = wv; mt < 8; mt += 4){
        bf16x8 af[4];
        #pragma unroll
        for (int ks = 0; ks < 4; ++ks)
            af[ks] = *(const bf16x8*)(xrow + (mt * 16 + cl) * 128 + ks * 32 + g * 8);
        #pragma unroll
        for (int pc = 0; pc < 6; ++pc){
            f32x4 acc = {0.f, 0.f, 0.f, 0.f};
            #pragma unroll
            for (int ks = 0; ks < 4; ++ks)
                acc = __builtin_amdgcn_mfma_f32_16x16x32_bf16(af[ks], bfr[pc][ks], acc, 0, 0, 0);
            int p = pc >> 1, s = pc & 1;
            int d = s * 16 + cl;
            #pragma unroll
            for (int reg = 0; reg < 4; ++reg){
                int t = mt * 16 + g * 4 + reg;
                if (t < NTT){
                    float v = acc[reg] + bias[pc];
                    if (p == 0)      q_s[t * 40 + d] = f2bf(v * scale);
                    else if (p == 1) k_s[t * 40 + d] = f2bf(v);
                    else             vT[d * 136 + t] = f2bf(v);
                }
            }
        }
    }
    __syncthreads();   // q/k/vT stable from here; below only per-wave P region is touched

    for (int s = 0; s < 2; ++s){
        int mt = wv + s * 4;
        bf16x8 aq = *(const bf16x8*)(q_s + (mt * 16 + cl) * 40 + g * 8);
        f32x4 lg[8];
        #pragma unroll
        for (int jt = 0; jt < 8; ++jt){
            bf16x8 bk = *(const bf16x8*)(k_s + (jt * 16 + cl) * 40 + g * 8);
            f32x4 z = {0.f, 0.f, 0.f, 0.f};
            lg[jt] = __builtin_amdgcn_mfma_f32_16x16x32_bf16(aq, bk, z, 0, 0, 0);
        }
        if (cl >= 8){ lg[7][0] = -1e30f; lg[7][1] = -1e30f; lg[7][2] = -1e30f; lg[7][3] = -1e30f; }

        float inv[4];
        #pragma unroll
        for (int reg = 0; reg < 4; ++reg){
            float m = lg[0][reg];
            #pragma unroll
            for (int jt = 1; jt < 8; ++jt) m = fmaxf(m, lg[jt][reg]);
            m = fmaxf(m, __shfl_xor(m, 1, 64));
            m = fmaxf(m, __shfl_xor(m, 2, 64));
            m = fmaxf(m, __shfl_xor(m, 4, 64));
            m = fmaxf(m, __shfl_xor(m, 8, 64));
            float sum = 0.f;
            #pragma unroll
            for (int jt = 0; jt < 8; ++jt){ float e = __expf(lg[jt][reg] - m); lg[jt][reg] = e; sum += e; }
            sum += __shfl_xor(sum, 1, 64); sum += __shfl_xor(sum, 2, 64);
            sum += __shfl_xor(sum, 4, 64); sum += __shfl_xor(sum, 8, 64);
            inv[reg] = 1.f / sum;
        }

        unsigned short* Pw = P_s + wv * 2176;   // per-wave region: no barriers needed
        #pragma unroll
        for (int jt = 0; jt < 8; ++jt){
            #pragma unroll
            for (int reg = 0; reg < 4; ++reg)
                Pw[(g * 4 + reg) * 136 + jt * 16 + cl] = f2bf(lg[jt][reg] * inv[reg]);
        }

        bf16x8 ap[4];
        #pragma unroll
        for (int ks = 0; ks < 4; ++ks)
            ap[ks] = *(const bf16x8*)(Pw + cl * 136 + ks * 32 + g * 8);
        #pragma unroll
        for (int nt = 0; nt < 2; ++nt){
            f32x4 oacc = {0.f, 0.f, 0.f, 0.f};
            #pragma unroll
            for (int ks = 0; ks < 4; ++ks){
                bf16x8 bv = *(const bf16x8*)(vT + (nt * 16 + cl) * 136 + ks * 32 + g * 8);
                oacc = __builtin_amdgcn_mfma_f32_16x16x32_bf16(ap[ks], bv, oacc, 0, 0, 0);
            }
            #pragma unroll
            for (int reg = 0; reg < 4; ++reg){
                int t = mt * 16 + g * 4 + reg;
                if (t < NTT)
                    o[((size_t)nj * NTT + t) * 128 + h * 32 + nt * 16 + cl] = f2bf(oacc[reg]);
            }
        }
    }
}

// ---------------------------------------------------------------- fused temporal MLP block
__global__ __launch_bounds__(256, 4) void k_tblock(
    const unsigned short* __restrict__ o, const unsigned short* __restrict__ WoB,
    const float* __restrict__ ob, const unsigned short* __restrict__ xbres,
    const float* __restrict__ lnw, const float* __restrict__ lnb,
    const unsigned short* __restrict__ F1B, const float* __restrict__ f1b,
    const unsigned short* __restrict__ F2B, const float* __restrict__ f2b,
    const float* __restrict__ ln2w, const float* __restrict__ ln2b,
    const float* __restrict__ tnw, const float* __restrict__ x,
    float* __restrict__ out)
{
    __shared__ __align__(16) float yf[32 * 132];            // also hb u16[32][264], then yf2
    __shared__ __align__(16) unsigned short xbuf[32 * 136];
    __shared__ int xib[32];
    int tid = threadIdx.x, wv = tid >> 6, lane = tid & 63, cl = lane & 15, g = lane >> 4;
    size_t row0 = (size_t)blockIdx.x * 32;

    if (tid < 32){
        int grow = (int)row0 + tid;
        int t = grow % NTT; int njq = grow / NTT; int j = njq % NJ; int n = njq / NJ;
        xib[tid] = ((n * NTT + t) * NJ + j) * 128;
    }

    // ---- phase 1: out-proj + residual -> yf ----
    {
        int c0 = wv*16 + cl, c1 = c0 + 64;
        bf16x8 B0[4], B1[4];
        #pragma unroll
        for (int ks = 0; ks < 4; ks++){
            B0[ks] = *(const bf16x8*)(WoB + c0*128 + ks*32 + g*8);
            B1[ks] = *(const bf16x8*)(WoB + c1*128 + ks*32 + g*8);
        }
        float b0 = ob[c0], b1 = ob[c1];
        #pragma unroll
        for (int rt = 0; rt < 2; rt++){
            bf16x8 A[4];
            #pragma unroll
            for (int ks = 0; ks < 4; ks++)
                A[ks] = *(const bf16x8*)(o + (row0 + rt*16 + cl)*128 + ks*32 + g*8);
            f32x4 a0 = {0,0,0,0}, a1 = {0,0,0,0};
            #pragma unroll
            for (int ks = 0; ks < 4; ks++){
                a0 = __builtin_amdgcn_mfma_f32_16x16x32_bf16(A[ks], B0[ks], a0, 0, 0, 0);
                a1 = __builtin_amdgcn_mfma_f32_16x16x32_bf16(A[ks], B1[ks], a1, 0, 0, 0);
            }
            #pragma unroll
            for (int reg = 0; reg < 4; reg++){
                int row = rt*16 + g*4 + reg;
                yf[row*132 + c0] = a0[reg] + b0 + bf2f(xbres[(row0 + row)*128 + c0]);
                yf[row*132 + c1] = a1[reg] + b1 + bf2f(xbres[(row0 + row)*128 + c1]);
            }
        }
    }
    __syncthreads();

    // ---- phase 2: LN1 stats + apply (8 lanes/row) -> xbuf ----
    {
        int row = tid >> 3, sub = tid & 7;
        float4 v[4];
        float s1 = 0.f, s2 = 0.f;
        #pragma unroll
        for (int k = 0; k < 4; k++){
            v[k] = *(const float4*)(yf + row*132 + sub*16 + k*4);
            s1 += v[k].x + v[k].y + v[k].z + v[k].w;
            s2 += v[k].x*v[k].x + v[k].y*v[k].y + v[k].z*v[k].z + v[k].w*v[k].w;
        }
        s1 += __shfl_xor(s1, 1, 64); s2 += __shfl_xor(s2, 1, 64);
        s1 += __shfl_xor(s1, 2, 64); s2 += __shfl_xor(s2, 2, 64);
        s1 += __shfl_xor(s1, 4, 64); s2 += __shfl_xor(s2, 4, 64);
        float m = s1 * 0.0078125f;
        float rv = rsqrtf(s2 * 0.0078125f - m*m + 1e-5f);
        #pragma unroll
        for (int k = 0; k < 4; k++){
            float4 w4 = *(const float4*)(lnw + sub*16 + k*4);
            float4 b4 = *(const float4*)(lnb + sub*16 + k*4);
            ushort4 u;
            u.x = f2bf((v[k].x - m) * rv * w4.x + b4.x);
            u.y = f2bf((v[k].y - m) * rv * w4.y + b4.y);
            u.z = f2bf((v[k].z - m) * rv * w4.z + b4.z);
            u.w = f2bf((v[k].w - m) * rv * w4.w + b4.w);
            *(ushort4*)(xbuf + row*136 + sub*16 + k*4) = u;
        }
    }
    __syncthreads();

    // ---- phase 3: FFN1 + gelu -> hb (overlays yf) ----
    unsigned short* hb = (unsigned short*)yf;   // [32][264]
    #pragma unroll
    for (int s = 0; s < 4; s++){
        int c = wv*16 + cl + s*64;
        bf16x8 B[4];
        #pragma unroll
        for (int ks = 0; ks < 4; ks++)
            B[ks] = *(const bf16x8*)(F1B + c*128 + ks*32 + g*8);
        float bias = f1b[c];
        #pragma unroll
        for (int rt = 0; rt < 2; rt++){
            bf16x8 A[4];
            #pragma unroll
            for (int ks = 0; ks < 4; ks++)
                A[ks] = *(const bf16x8*)(xbuf + (rt*16 + cl)*136 + ks*32 + g*8);
            f32x4 acc = {0,0,0,0};
            #pragma unroll
            for (int ks = 0; ks < 4; ks++)
                acc = __builtin_amdgcn_mfma_f32_16x16x32_bf16(A[ks], B[ks], acc, 0, 0, 0);
            #pragma unroll
            for (int reg = 0; reg < 4; reg++){
                int row = rt*16 + g*4 + reg;
                hb[row*264 + c] = f2bf(gelu_fast(acc[reg] + bias));
            }
        }
    }
    __syncthreads();

    // ---- phase 4: FFN2 into registers, then overlay-write yf2 ----
    float ys[2][2][4];
    #pragma unroll
    for (int s = 0; s < 2; s++){
        int c = wv*16 + cl + s*64;
        bf16x8 B[8];
        #pragma unroll
        for (int ks = 0; ks < 8; ks++)
            B[ks] = *(const bf16x8*)(F2B + c*256 + ks*32 + g*8);
        float bias = f2b[c];
        #pragma unroll
        for (int rt = 0; rt < 2; rt++){
            bf16x8 A[8];
            #pragma unroll
            for (int ks = 0; ks < 8; ks++)
                A[ks] = *(const bf16x8*)(hb + (rt*16 + cl)*264 + ks*32 + g*8);
            f32x4 acc = {0,0,0,0};
            #pragma unroll
            for (int ks = 0; ks < 8; ks++)
                acc = __builtin_amdgcn_mfma_f32_16x16x32_bf16(A[ks], B[ks], acc, 0, 0, 0);
            #pragma unroll
            for (int reg = 0; reg < 4; reg++){
                int row = rt*16 + g*4 + reg;
                ys[s][rt][reg] = acc[reg] + bias + bf2f(xbuf[row*136 + c]);
            }
        }
    }
    __syncthreads();
    #pragma unroll
    for (int s = 0; s < 2; s++){
        int c = wv*16 + cl + s*64;
        #pragma unroll
        for (int rt = 0; rt < 2; rt++)
            #pragma unroll
            for (int reg = 0; reg < 4; reg++)
                yf[(rt*16 + g*4 + reg)*132 + c] = ys[s][rt][reg];
    }
    __syncthreads();

    // ---- phase 5: LN2 + RMSNorm + residuals + final write ----
    {
        int row = tid >> 3, sub = tid & 7;
        float4 v[4];
        float s1 = 0.f, s2 = 0.f;
        #pragma unroll
        for (int k = 0; k < 4; k++){
            v[k] = *(const float4*)(yf + row*132 + sub*16 + k*4);
            s1 += v[k].x + v[k].y + v[k].z + v[k].w;
            s2 += v[k].x*v[k].x + v[k].y*v[k].y + v[k].z*v[k].z + v[k].w*v[k].w;
        }
        s1 += __shfl_xor(s1, 1, 64); s2 += __shfl_xor(s2, 1, 64);
        s1 += __shfl_xor(s1, 2, 64); s2 += __shfl_xor(s2, 2, 64);
        s1 += __shfl_xor(s1, 4, 64); s2 += __shfl_xor(s2, 4, 64);
        float m = s1 * 0.0078125f;
        float rv = rsqrtf(s2 * 0.0078125f - m*m + 1e-5f);
        float z[4][4];
        float s3 = 0.f;
        #pragma unroll
        for (int k = 0; k < 4; k++){
            float4 w4 = *(const float4*)(ln2w + sub*16 + k*4);
            float4 b4 = *(const float4*)(ln2b + sub*16 + k*4);
            z[k][0] = (v[k].x - m) * rv * w4.x + b4.x;
            z[k][1] = (v[k].y - m) * rv * w4.y + b4.y;
            z[k][2] = (v[k].z - m) * rv * w4.z + b4.z;
            z[k][3] = (v[k].w - m) * rv * w4.w + b4.w;
            s3 += z[k][0]*z[k][0] + z[k][1]*z[k][1] + z[k][2]*z[k][2] + z[k][3]*z[k][3];
        }
        s3 += __shfl_xor(s3, 1, 64); s3 += __shfl_xor(s3, 2, 64); s3 += __shfl_xor(s3, 4, 64);
        float sr = rsqrtf(s3 * 0.0078125f + 1e-6f);
        int xb0 = xib[row] + sub*16;
        #pragma unroll
        for (int k = 0; k < 4; k++){
            float4 tw4 = *(const float4*)(tnw + sub*16 + k*4);
            ushort4 xr = *(const ushort4*)(xbres + (row0 + row)*128 + sub*16 + k*4);
            float4 xv = *(const float4*)(x + xb0 + k*4);
            float4 ov;
            ov.x = z[k][0] * sr * tw4.x + bf2f(xr.x) + xv.x;
            ov.y = z[k][1] * sr * tw4.y + bf2f(xr.y) + xv.y;
            ov.z = z[k][2] * sr * tw4.z + bf2f(xr.z) + xv.z;
            ov.w = z[k][3] * sr * tw4.w + bf2f(xr.w) + xv.w;
            *(float4*)(out + xb0 + k*4) = ov;
        }
    }
}

// ================================================================ launch
extern "C" void kernel_launch(void* const* d_in, const int* in_sizes, int n_in,
                              void* d_out, int out_size, void* d_ws, size_t ws_size,
                              hipStream_t stream) {
    (void)in_sizes; (void)n_in; (void)out_size;
    const float* x      = (const float*)d_in[0];
    const float* sc     = (const float*)d_in[1];
    const float* gcnw   = (const float*)d_in[2];
    const float* gnw    = (const float*)d_in[3];
    const float* cls    = (const float*)d_in[4];
    const float* sn1    = (const float*)d_in[5];
    const float* sn2    = (const float*)d_in[6];
    const float* s_in_w = (const float*)d_in[7];
    const float* s_in_b = (const float*)d_in[8];
    const float* s_out_w= (const float*)d_in[9];
    const float* s_out_b= (const float*)d_in[10];
    const float* s_f1w  = (const float*)d_in[11];
    const float* s_f1b  = (const float*)d_in[12];
    const float* s_f2w  = (const float*)d_in[13];
    const float* s_f2b  = (const float*)d_in[14];
    const float* t_in_w = (const float*)d_in[15];
    const float* t_in_b = (const float*)d_in[16];
    const float* t_out_w= (const float*)d_in[17];
    const float* t_out_b= (const float*)d_in[18];
    const float* t_ln1w = (const float*)d_in[19];
    const float* t_ln1b = (const float*)d_in[20];
    const float* t_ln2w = (const float*)d_in[21];
    const float* t_ln2b = (const float*)d_in[22];
    const float* t_f1w  = (const float*)d_in[23];
    const float* t_f1b  = (const float*)d_in[24];
    const float* t_f2w  = (const float*)d_in[25];
    const float* t_f2b  = (const float*)d_in[26];
    const float* tnw    = (const float*)d_in[27];

    char* ws = (char*)d_ws;
    const size_t SZ_BIG = 98304000;                 // 192000*128*4
    char*  R1 = ws;                                 // xg (bf16)
    char*  R2 = ws + SZ_BIG;                        // o (bf16)
    char*  R3 = ws + 2 * SZ_BIG;                    // delta (bf16) | xb (bf16)
    char* p = ws + 3 * SZ_BIG;
    int*   ORD  = (int*)p;   p += 768000;
    int*   SLOT = (int*)p;   p += 768000;
    float* PH   = (float*)p; p += 245760;
    unsigned short* WM = (unsigned short*)p; p += 557056;
    if (ws_size < (size_t)(p - ws)) return;

    unsigned short* WinB  = WM;              // s_in_w·sn1w  [384][128]
    unsigned short* WoutB = WM + 49152;      // s_out_w [128][128]
    unsigned short* F1B   = WM + 65536;      // s_f1w·sn2w   [256][128]
    unsigned short* F2B   = WM + 98304;      // s_f2w   [128][256]
    unsigned short* WB    = WM + 131072;     // t_in_w  [384][128]
    unsigned short* WoBt  = WM + 180224;     // t_out_w [128][128]
    unsigned short* F1Bt  = WM + 196608;     // t_f1w   [256][128]
    unsigned short* F2Bt  = WM + 229376;     // t_f2w   [128][256]
    unsigned short* GWt   = WM + 262144;     // gcn_w[0]^T [128][128]

    unsigned short* XG  = (unsigned short*)R1;                    // xg bf16 [192000][128]
    unsigned short* DLT = (unsigned short*)R3;                    // delta [7680*19][128]
    unsigned short* XB  = (unsigned short*)(R3 + 37355520);       // xsp bf16 [192000][128]
    unsigned short* OB  = (unsigned short*)R2;                    // o bf16  [192000][128]

    float* out0 = (float*)d_out;
    float* next_attn = out0 + 24576000;

    k_prep<<<320, 256, 0, stream>>>(s_in_w, s_out_w, s_f1w, s_f2w,
                                    t_in_w, t_out_w, t_f1w, t_f2w, gcnw,
                                    sn1, sn2, WM);
    k_gcn_mfma<<<3000, 256, 0, stream>>>(x, GWt, gnw, XG);
    k_select<<<30, 256, 0, stream>>>(sc, ORD, SLOT, PH);
    k_spatial8<<<3840, 512, 0, stream>>>(XG, ORD, PH, cls,
                                         WinB, s_in_b, WoutB, s_out_b,
                                         F1B, s_f1b, F2B, s_f2b,
                                         DLT, next_attn);
    k_scatter3<<<24000, 256, 0, stream>>>(XG, DLT, SLOT, XB);
    k_tattn2<<<6400, 256, 0, stream>>>(XB, WB, t_in_b, OB);
    k_tblock<<<6000, 256, 0, stream>>>(OB, WoBt, t_out_b, XB,
                                       t_ln1w, t_ln1b, F1Bt, t_f1b,
                                       F2Bt, t_f2b, t_ln2w, t_ln2b,
                                       tnw, x, out0);
}

// Round 16
// 654.680 us; speedup vs baseline: 1.0161x; 1.0161x over previous
//
#include <hip/hip_runtime.h>
#include <hip/hip_bf16.h>
#include <math.h>

// Problem constants
#define NTR   7680      // N*T
#define NJ    25
#define NKEEP 17
#define NDRP  8
#define NL    19
#define NROW  192000    // NT*J == N*J*T
#define NTT   120
#define RSP   24        // padded rows per r in spatial block

typedef __attribute__((ext_vector_type(8))) short bf16x8;
typedef __attribute__((ext_vector_type(4))) float f32x4;

__device__ __forceinline__ float gelu_exact(float v){
    return 0.5f * v * (1.0f + erff(v * 0.70710678118654752440f));
}
__device__ __forceinline__ unsigned short f2bf(float v){
    union { __hip_bfloat16 h; unsigned short u; } c;
    c.h = __float2bfloat16(v);
    return c.u;
}
__device__ __forceinline__ float bf2f(unsigned short u){
    union { unsigned u; float f; } a; a.u = ((unsigned)u) << 16; return a.f;
}

// ---------------------------------------------------------------- all weight preprocessing in one kernel
// Norm-folding: WinB *= sn1w[k], F1B *= sn2w[k] (k = input channel)
__global__ void k_prep(const float* __restrict__ s_in_w, const float* __restrict__ s_out_w,
                       const float* __restrict__ s_f1w,  const float* __restrict__ s_f2w,
                       const float* __restrict__ t_in_w, const float* __restrict__ t_out_w,
                       const float* __restrict__ t_f1w,  const float* __restrict__ t_f2w,
                       const float* __restrict__ gcnw,
                       const float* __restrict__ sn1w,   const float* __restrict__ sn2w,
                       unsigned short* __restrict__ WM)
{
    int i = blockIdx.x * 256 + threadIdx.x;
    if (i < 65536){
        const float* src;
        const float* nw = nullptr;
        int base;
        if      (i < 12288){ src = s_in_w;  base = 0;     nw = sn1w; }
        else if (i < 16384){ src = s_out_w; base = 12288; }
        else if (i < 24576){ src = s_f1w;   base = 16384; nw = sn2w; }
        else if (i < 32768){ src = s_f2w;   base = 24576; }
        else if (i < 45056){ src = t_in_w;  base = 32768; }
        else if (i < 49152){ src = t_out_w; base = 45056; }
        else if (i < 57344){ src = t_f1w;   base = 49152; }
        else               { src = t_f2w;   base = 57344; }
        int loc = i - base;
        float4 v = *(const float4*)(src + loc * 4);
        if (nw){
            float4 w = *(const float4*)(nw + ((loc * 4) & 127));
            v.x *= w.x; v.y *= w.y; v.z *= w.z; v.w *= w.w;
        }
        ushort4 o; o.x = f2bf(v.x); o.y = f2bf(v.y); o.z = f2bf(v.z); o.w = f2bf(v.w);
        *(ushort4*)(WM + i * 4) = o;
    } else if (i < 81920){
        int j = i - 65536;                 // gcn transpose: 16384 elems
        int d = j >> 7, c = j & 127;
        WM[262144 + d * 128 + c] = f2bf(gcnw[c * 128 + d]);
    }
}

// ---------------------------------------------------------------- GCN + RMSNorm (MFMA, fused stats, bf16 out)
__global__ __launch_bounds__(256, 3) void k_gcn_mfma(
    const float* __restrict__ x, const unsigned short* __restrict__ GWt,
    const float* __restrict__ gnw, unsigned short* __restrict__ xg)
{
    __shared__ __align__(16) unsigned short xb[64 * 136];
    __shared__ __align__(16) float yf[64 * 132];
    __shared__ float ssq[64];
    __shared__ float rstd[64];
    int tid = threadIdx.x, wv = tid >> 6, lane = tid & 63, cl = lane & 15, g = lane >> 4;
    size_t row0 = (size_t)blockIdx.x * 64;

    if (tid < 64) ssq[tid] = 0.f;
    const float4* x4 = (const float4*)(x + row0 * 128);
    for (int i = tid; i < 2048; i += 256){
        int row = i >> 5, ch = i & 31;
        float4 v = x4[row * 32 + ch];
        ushort4 o; o.x = f2bf(v.x); o.y = f2bf(v.y); o.z = f2bf(v.z); o.w = f2bf(v.w);
        *(ushort4*)(xb + row * 136 + ch * 4) = o;
    }
    __syncthreads();
    for (int job = wv; job < 32; job += 4){
        int rt = job >> 3, ct = job & 7, col = ct * 16 + cl;
        f32x4 acc = {0.f, 0.f, 0.f, 0.f};
        #pragma unroll
        for (int ks = 0; ks < 4; ks++){
            bf16x8 a = *(const bf16x8*)(xb + (rt*16 + cl)*136 + ks*32 + g*8);
            bf16x8 b = *(const bf16x8*)(GWt + col*128 + ks*32 + g*8);
            acc = __builtin_amdgcn_mfma_f32_16x16x32_bf16(a, b, acc, 0, 0, 0);
        }
        #pragma unroll
        for (int reg = 0; reg < 4; reg++){
            int row = rt*16 + g*4 + reg;
            float v = acc[reg];
            yf[row*132 + col] = v;
            float p = v * v;
            p += __shfl_xor(p, 1, 64); p += __shfl_xor(p, 2, 64);
            p += __shfl_xor(p, 4, 64); p += __shfl_xor(p, 8, 64);
            if (cl == 0) atomicAdd(&ssq[row], p);
        }
    }
    __syncthreads();
    if (tid < 64) rstd[tid] = rsqrtf(ssq[tid] * 0.0078125f + 1e-6f);
    __syncthreads();
    for (int i = tid; i < 2048; i += 256){
        int row = i >> 5, ch = i & 31;
        float4 v = *(const float4*)(yf + row*132 + ch*4);
        float4 w4 = *(const float4*)(gnw + ch*4);
        float r = rstd[row];
        ushort4 u;
        u.x = f2bf(v.x * r * w4.x); u.y = f2bf(v.y * r * w4.y);
        u.z = f2bf(v.z * r * w4.z); u.w = f2bf(v.w * r * w4.w);
        *(ushort4*)(xg + (row0 + row)*128 + ch*4) = u;
    }
}

// ---------------------------------------------------------------- per-row token selection
__global__ void k_select(const float* __restrict__ sc, int* __restrict__ order,
                         int* __restrict__ slot, float* __restrict__ ph){
    int r = blockIdx.x * blockDim.x + threadIdx.x;
    if (r >= NTR) return;
    float s[NJ]; int id[NJ];
    for (int j = 0; j < NJ; j++){ s[j] = sc[r * NJ + j]; id[j] = j; }
    for (int m = 1; m < NJ; m++){
        float sv = s[m]; int iv = id[m]; int p = m;
        while (p > 0 && s[p-1] < sv){ s[p] = s[p-1]; id[p] = id[p-1]; p--; }
        s[p] = sv; id[p] = iv;
    }
    for (int j = 0; j < NJ; j++) order[r * NJ + j] = id[j];
    for (int i = 0; i < NKEEP; i++)  slot[r * NJ + id[i]] = 1 + i;
    for (int i = NKEEP; i < NJ; i++) slot[r * NJ + id[i]] = 18;
    float m8 = s[NKEEP];
    float e[NDRP]; float sum = 0.f;
    for (int i = 0; i < NDRP; i++){ e[i] = expf(s[NKEEP + i] - m8); sum += e[i]; }
    float inv = 1.f / sum;
    for (int i = 0; i < NDRP; i++) ph[r * NDRP + i] = e[i] * inv;
}

// ---------------------------------------------------------------- spatial transformer v8: fewer barriers
// sm u16 layout: xs[48][136] | Pb[8][32][40] | qk[48][264] | U2: vT[8][32][40] / ao[48][136]
__global__ __launch_bounds__(512, 4) void k_spatial8(
    const unsigned short* __restrict__ xg, const int* __restrict__ order, const float* __restrict__ ph,
    const float* __restrict__ cls_tok,
    const unsigned short* __restrict__ WinB, const float* __restrict__ inb,
    const unsigned short* __restrict__ WoutB, const float* __restrict__ outb,
    const unsigned short* __restrict__ F1B, const float* __restrict__ f1b,
    const unsigned short* __restrict__ F2B, const float* __restrict__ f2b,
    unsigned short* __restrict__ delta, float* __restrict__ next_attn)
{
    __shared__ __align__(16) unsigned short sm[39680];
    __shared__ float rstd[48];
    __shared__ float ss2[48];
    __shared__ float clsp[8][20];
    __shared__ int   ord_s[2][NJ];
    __shared__ float ph_s[2][NDRP];
    unsigned short* xs = sm;             // [48][136] x_slow -> x_msa
    unsigned short* Pb = sm + 6528;      // [8][32][40]
    unsigned short* qk = sm + 16768;     // [48][264]
    unsigned short* vT = sm + 29440;     // [8][32][40]
    unsigned short* ao = sm + 29440;     // [48][136] overlays vT

    int tid = threadIdx.x;
    int r0 = blockIdx.x * 2;
    int wv = tid >> 6, lane = tid & 63, cl = lane & 15, g = lane >> 4;
    const float scale = 0.17677669529663687f;

    if (tid < 2*NJ)   ord_s[tid/NJ][tid%NJ] = order[(r0 + tid/NJ)*NJ + tid%NJ];
    if (tid < 2*NDRP) ph_s[tid>>3][tid&7]   = ph[(r0 + (tid>>3))*NDRP + (tid&7)];
    if (tid < 48) ss2[tid] = 0.f;
    for (int i = tid; i < 1280; i += 512)
        *(uint4*)(vT + i*8) = make_uint4(0,0,0,0);   // zero U2 (pad keys must be 0)
    __syncthreads();   // ord_s/ph_s visible before gather

    // ---- build x_slow (bf16 gather) + fused rmsnorm1 stats (32 lanes per row) ----
    {
        int ln = tid & 31;
        for (int j = tid >> 5; j < 48; j += 16){
            int rr = j / RSP, t = j - rr * RSP;
            const unsigned short* xgr = xg + (size_t)(r0 + rr) * NJ * 128;
            float v0, v1, v2, v3;
            if (t == 0){
                float4 cv = *(const float4*)(cls_tok + ln*4);
                v0 = cv.x; v1 = cv.y; v2 = cv.z; v3 = cv.w;
            } else if (t <= NKEEP){
                ushort4 u = *(const ushort4*)(xgr + ord_s[rr][t-1]*128 + ln*4);
                v0 = bf2f(u.x); v1 = bf2f(u.y); v2 = bf2f(u.z); v3 = bf2f(u.w);
            } else if (t == 18){
                v0 = v1 = v2 = v3 = 0.f;
                for (int i = 0; i < NDRP; i++){
                    ushort4 u = *(const ushort4*)(xgr + ord_s[rr][NKEEP+i]*128 + ln*4);
                    float w = ph_s[rr][i];
                    v0 = fmaf(bf2f(u.x),w,v0); v1 = fmaf(bf2f(u.y),w,v1);
                    v2 = fmaf(bf2f(u.z),w,v2); v3 = fmaf(bf2f(u.w),w,v3);
                }
            } else { v0 = v1 = v2 = v3 = 0.f; }
            ushort4 o4; o4.x=f2bf(v0); o4.y=f2bf(v1); o4.z=f2bf(v2); o4.w=f2bf(v3);
            *(ushort4*)(xs + j*136 + ln*4) = o4;
            float p = v0*v0 + v1*v1 + v2*v2 + v3*v3;
            p += __shfl_xor(p, 1, 64); p += __shfl_xor(p, 2, 64);
            p += __shfl_xor(p, 4, 64); p += __shfl_xor(p, 8, 64);
            p += __shfl_xor(p, 16, 64);
            if (ln == 0) rstd[j] = rsqrtf(p * 0.0078125f + 1e-6f);
        }
    }
    __syncthreads();

    // ---- qkv GEMM on RAW xs (sn1w folded into WinB); epilogue scales by rstd[row] ----
    {
        int col = wv*16 + cl;
        bf16x8 Bq[4], Bk[4], Bv[4];
        #pragma unroll
        for (int ks = 0; ks < 4; ks++){
            Bq[ks] = *(const bf16x8*)(WinB + col*128        + ks*32 + g*8);
            Bk[ks] = *(const bf16x8*)(WinB + (128+col)*128  + ks*32 + g*8);
            Bv[ks] = *(const bf16x8*)(WinB + (256+col)*128  + ks*32 + g*8);
        }
        float bq = inb[col], bk = inb[128+col], bv = inb[256+col];
        int h = col >> 5, d = col & 31;
        #pragma unroll
        for (int rt = 0; rt < 3; rt++){
            bf16x8 A[4];
            #pragma unroll
            for (int ks = 0; ks < 4; ks++)
                A[ks] = *(const bf16x8*)(xs + (rt*16 + cl)*136 + ks*32 + g*8);
            f32x4 aq = {0,0,0,0}, ak = {0,0,0,0}, av = {0,0,0,0};
            #pragma unroll
            for (int ks = 0; ks < 4; ks++){
                aq = __builtin_amdgcn_mfma_f32_16x16x32_bf16(A[ks], Bq[ks], aq, 0, 0, 0);
                ak = __builtin_amdgcn_mfma_f32_16x16x32_bf16(A[ks], Bk[ks], ak, 0, 0, 0);
                av = __builtin_amdgcn_mfma_f32_16x16x32_bf16(A[ks], Bv[ks], av, 0, 0, 0);
            }
            #pragma unroll
            for (int reg = 0; reg < 4; reg++){
                int row = rt*16 + g*4 + reg;
                float rs = rstd[row];
                qk[row*264 + col]       = f2bf((aq[reg]*rs + bq) * scale);
                qk[row*264 + 128 + col] = f2bf(ak[reg]*rs + bk);
                int rr = row >= RSP; int key = row - rr*RSP;
                vT[(rr*4 + h)*1280 + d*40 + key] = f2bf(av[reg]*rs + bv);
            }
        }
    }
    __syncthreads();

    // ---- attention: 1 (rr,h) pair per wave; P region is per-wave -> NO mid barrier ----
    {
        int qh = wv;
        int rr = qh >> 2, h = qh & 3;
        bf16x8 aq[2];
        #pragma unroll
        for (int qt = 0; qt < 2; qt++)
            aq[qt] = *(const bf16x8*)(qk + (rr*RSP + qt*16 + cl)*264 + h*32 + g*8);
        f32x4 lg[2][2];
        #pragma unroll
        for (int kt = 0; kt < 2; kt++){
            bf16x8 bk = *(const bf16x8*)(qk + (rr*RSP + kt*16 + cl)*264 + 128 + h*32 + g*8);
            f32x4 z = {0.f, 0.f, 0.f, 0.f};
            lg[0][kt] = __builtin_amdgcn_mfma_f32_16x16x32_bf16(aq[0], bk, z, 0, 0, 0);
            lg[1][kt] = __builtin_amdgcn_mfma_f32_16x16x32_bf16(aq[1], bk, z, 0, 0, 0);
        }
        #pragma unroll
        for (int qt = 0; qt < 2; qt++){
            #pragma unroll
            for (int reg = 0; reg < 4; reg++){
                float l0 = lg[qt][0][reg];
                float l1 = (cl >= 3) ? -1e30f : lg[qt][1][reg];
                float m = fmaxf(l0, l1);
                m = fmaxf(m, __shfl_xor(m, 1, 64));
                m = fmaxf(m, __shfl_xor(m, 2, 64));
                m = fmaxf(m, __shfl_xor(m, 4, 64));
                m = fmaxf(m, __shfl_xor(m, 8, 64));
                float e0 = __expf(l0 - m), e1 = __expf(l1 - m);
                float ssum = e0 + e1;
                ssum += __shfl_xor(ssum, 1, 64); ssum += __shfl_xor(ssum, 2, 64);
                ssum += __shfl_xor(ssum, 4, 64); ssum += __shfl_xor(ssum, 8, 64);
                float inv = 1.f / ssum;
                e0 *= inv; e1 *= inv;
                int q = qt*16 + g*4 + reg;
                Pb[qh*1280 + q*40 + cl]      = f2bf(e0);
                Pb[qh*1280 + q*40 + 16 + cl] = f2bf(e1);
                if (qt == 0 && g == 0 && reg == 0){
                    clsp[qh][cl] = e0;
                    if (cl < 4) clsp[qh][16 + cl] = e1;
                }
            }
        }
        // no barrier: Pb[qh] and vT[qh] consumed only by this wave; PV writes only
        // the qk columns (h*32..) that this wave alone read as Q.
        bf16x8 ap[2];
        #pragma unroll
        for (int qt = 0; qt < 2; qt++)
            ap[qt] = *(const bf16x8*)(Pb + qh*1280 + (qt*16 + cl)*40 + g*8);
        #pragma unroll
        for (int dt = 0; dt < 2; dt++){
            bf16x8 bv = *(const bf16x8*)(vT + qh*1280 + (dt*16 + cl)*40 + g*8);
            #pragma unroll
            for (int qt = 0; qt < 2; qt++){
                f32x4 z = {0.f, 0.f, 0.f, 0.f};
                f32x4 oa = __builtin_amdgcn_mfma_f32_16x16x32_bf16(ap[qt], bv, z, 0, 0, 0);
                #pragma unroll
                for (int reg = 0; reg < 4; reg++){
                    int q = qt*16 + g*4 + reg;
                    if (q < 19)
                        qk[(rr*RSP + q)*264 + h*32 + dt*16 + cl] = f2bf(oa[reg]);
                    else if (q < RSP)
                        qk[(rr*RSP + q)*264 + h*32 + dt*16 + cl] = 0;
                }
            }
        }
        __syncthreads();
    }

    // ---- next_attn ----
    if (tid < 36){
        int rr2 = tid / 18, t = tid - rr2*18;
        float v = 0.25f * (clsp[rr2*4+0][1+t] + clsp[rr2*4+1][1+t] +
                           clsp[rr2*4+2][1+t] + clsp[rr2*4+3][1+t]);
        int r = r0 + rr2;
        if (t < NKEEP) next_attn[r*NJ + ord_s[rr2][t]] = v;
        else { for (int i = 0; i < NDRP; i++) next_attn[r*NJ + ord_s[rr2][NKEEP+i]] = v; }
    }

    // ---- out-proj: B resident; fused rmsnorm2 stats on x_msa ----
    {
        int col = wv*16 + cl;
        bf16x8 B[4];
        #pragma unroll
        for (int ks = 0; ks < 4; ks++)
            B[ks] = *(const bf16x8*)(WoutB + col*128 + ks*32 + g*8);
        float bias = outb[col];
        #pragma unroll
        for (int rt = 0; rt < 3; rt++){
            bf16x8 A[4];
            #pragma unroll
            for (int ks = 0; ks < 4; ks++)
                A[ks] = *(const bf16x8*)(qk + (rt*16 + cl)*264 + ks*32 + g*8);
            f32x4 acc = {0,0,0,0};
            #pragma unroll
            for (int ks = 0; ks < 4; ks++)
                acc = __builtin_amdgcn_mfma_f32_16x16x32_bf16(A[ks], B[ks], acc, 0, 0, 0);
            #pragma unroll
            for (int reg = 0; reg < 4; reg++){
                int row = rt*16 + g*4 + reg;
                float v = acc[reg] + bias;
                float msa = bf2f(xs[row*136 + col]) + v;
                ao[row*136 + col] = f2bf(v);
                xs[row*136 + col] = f2bf(msa);
                float p = msa * msa;
                p += __shfl_xor(p, 1, 64); p += __shfl_xor(p, 2, 64);
                p += __shfl_xor(p, 4, 64); p += __shfl_xor(p, 8, 64);
                if (cl == 0) atomicAdd(&ss2[row], p);
            }
        }
    }
    __syncthreads();

    if (tid < 48) rstd[tid] = rsqrtf(ss2[tid] * 0.0078125f + 1e-6f);
    __syncthreads();

    // ---- ffn1 + gelu on RAW x_msa (sn2w folded into F1B); epilogue scales by rstd[row] ----
    {
        int c0 = wv*16 + cl, c1 = c0 + 128;
        bf16x8 B0[4], B1[4];
        #pragma unroll
        for (int ks = 0; ks < 4; ks++){
            B0[ks] = *(const bf16x8*)(F1B + c0*128 + ks*32 + g*8);
            B1[ks] = *(const bf16x8*)(F1B + c1*128 + ks*32 + g*8);
        }
        float b0 = f1b[c0], b1 = f1b[c1];
        #pragma unroll
        for (int rt = 0; rt < 3; rt++){
            bf16x8 A[4];
            #pragma unroll
            for (int ks = 0; ks < 4; ks++)
                A[ks] = *(const bf16x8*)(xs + (rt*16 + cl)*136 + ks*32 + g*8);
            f32x4 a0 = {0,0,0,0}, a1 = {0,0,0,0};
            #pragma unroll
            for (int ks = 0; ks < 4; ks++){
                a0 = __builtin_amdgcn_mfma_f32_16x16x32_bf16(A[ks], B0[ks], a0, 0, 0, 0);
                a1 = __builtin_amdgcn_mfma_f32_16x16x32_bf16(A[ks], B1[ks], a1, 0, 0, 0);
            }
            #pragma unroll
            for (int reg = 0; reg < 4; reg++){
                int row = rt*16 + g*4 + reg;
                float rs = rstd[row];
                qk[row*264 + c0] = f2bf(gelu_exact(a0[reg]*rs + b0));
                qk[row*264 + c1] = f2bf(gelu_exact(a1[reg]*rs + b1));
            }
        }
    }
    __syncthreads();

    // ---- ffn2 + delta: B resident (8 k-slices) ----
    {
        int col = wv*16 + cl;
        bf16x8 B[8];
        #pragma unroll
        for (int ks = 0; ks < 8; ks++)
            B[ks] = *(const bf16x8*)(F2B + col*256 + ks*32 + g*8);
        float bias = f2b[col];
        #pragma unroll
        for (int rt = 0; rt < 3; rt++){
            bf16x8 A[8];
            #pragma unroll
            for (int ks = 0; ks < 8; ks++)
                A[ks] = *(const bf16x8*)(qk + (rt*16 + cl)*264 + ks*32 + g*8);
            f32x4 acc = {0,0,0,0};
            #pragma unroll
            for (int ks = 0; ks < 8; ks++)
                acc = __builtin_amdgcn_mfma_f32_16x16x32_bf16(A[ks], B[ks], acc, 0, 0, 0);
            #pragma unroll
            for (int reg = 0; reg < 4; reg++){
                int row = rt*16 + g*4 + reg;
                int rr = row >= RSP; int tok = row - rr*RSP;
                if (tok < 19){
                    float dv = acc[reg] + bias + bf2f(ao[row*136 + col]);
                    delta[((size_t)(r0 + rr)*19 + tok)*128 + col] = f2bf(dv);
                }
            }
        }
    }
}

// ---------------------------------------------------------------- scatter: bf16 xg in, bf16 xsp out
__global__ void k_scatter3(const unsigned short* __restrict__ xg, const unsigned short* __restrict__ delta,
                           const int* __restrict__ slot, unsigned short* __restrict__ xb){
    int i = blockIdx.x * 256 + threadIdx.x;   // 6,144,000 quads
    int e = i * 4;
    int c = e & 127; int rem = e >> 7;
    int t = rem % NTT; int nj = rem / NTT; int j = nj % NJ; int n = nj / NJ;
    int r = n * NTT + t;
    int sl = slot[r * NJ + j];
    ushort4 xv = *(const ushort4*)(xg + ((size_t)r * NJ + j) * 128 + c);
    ushort4 dv = *(const ushort4*)(delta + ((size_t)r * 19 + sl) * 128 + c);
    ushort4 ob;
    ob.x = f2bf(2.f * bf2f(xv.x) + bf2f(dv.x));
    ob.y = f2bf(2.f * bf2f(xv.y) + bf2f(dv.y));
    ob.z = f2bf(2.f * bf2f(xv.z) + bf2f(dv.z));
    ob.w = f2bf(2.f * bf2f(xv.w) + bf2f(dv.w));
    *(ushort4*)(xb + e) = ob;
}

// ---------------------------------------------------------------- temporal attention: 4 waves per (nj, head), bf16 out
// P region is per-wave -> NO barriers in the attention loop (waves drift freely)
__global__ __launch_bounds__(256, 3) void k_tattn2(
    const unsigned short* __restrict__ xb, const unsigned short* __restrict__ Wb,
    const float* __restrict__ inb, unsigned short* __restrict__ o)
{
    // LDS u16: q[120][40] | k[120][40] | vT[32][136] | P[4][16][136] = 45,312 B
    __shared__ __align__(16) unsigned short smem[22656];
    unsigned short* q_s = smem;
    unsigned short* k_s = smem + 4800;
    unsigned short* vT  = smem + 9600;
    unsigned short* P_s = smem + 13952;

    int tid = threadIdx.x;
    int l = tid & 63, cl = l & 15, g = l >> 4, wv = tid >> 6;
    int nj = blockIdx.x >> 2;
    int h  = blockIdx.x & 3;

    vT[(tid >> 3) * 136 + 120 + (tid & 7)] = 0;   // zero pad key cols

    const unsigned short* xrow = xb + (size_t)nj * (NTT * 128);
    const float scale = 0.17677669529663687f;

    bf16x8 bfr[6][4];
    float bias[6];
    #pragma unroll
    for (int pc = 0; pc < 6; ++pc){
        int p = pc >> 1, s = pc & 1;
        int col = p * 128 + h * 32 + s * 16 + cl;
        bias[pc] = inb[col];
        #pragma unroll
        for (int ks = 0; ks < 4; ++ks)
            bfr[pc][ks] = *(const bf16x8*)(Wb + col * 128 + ks * 32 + g * 8);
    }

    for (int mt = wv; mt < 8; mt += 4){
        bf16x8 af[4];
        #pragma unroll
        for (int ks = 0; ks < 4; ++ks)
            af[ks] = *(const bf16x8*)(xrow + (mt * 16 + cl) * 128 + ks * 32 + g * 8);
        #pragma unroll
        for (int pc = 0; pc < 6; ++pc){
            f32x4 acc = {0.f, 0.f, 0.f, 0.f};
            #pragma unroll
            for (int ks = 0; ks < 4; ++ks)
                acc = __builtin_amdgcn_mfma_f32_16x16x32_bf16(af[ks], bfr[pc][ks], acc, 0, 0, 0);
            int p = pc >> 1, s = pc & 1;
            int d = s * 16 + cl;
            #pragma unroll
            for (int reg = 0; reg < 4; ++reg){
                int t = mt * 16 + g * 4 + reg;
                if (t < NTT){
                    float v = acc[reg] + bias[pc];
                    if (p == 0)      q_s[t * 40 + d] = f2bf(v * scale);
                    else if (p == 1) k_s[t * 40 + d] = f2bf(v);
                    else             vT[d * 136 + t] = f2bf(v);
                }
            }
        }
    }
    __syncthreads();   // q/k/vT stable from here; below only per-wave P region is touched

    for (int s = 0; s < 2; ++s){
        int mt = wv + s * 4;
        bf16x8 aq = *(const bf16x8*)(q_s + (mt * 16 + cl) * 40 + g * 8);
        f32x4 lg[8];
        #pragma unroll
        for (int jt = 0; jt < 8; ++jt){
            bf16x8 bk = *(const bf16x8*)(k_s + (jt * 16 + cl) * 40 + g * 8);
            f32x4 z = {0.f, 0.f, 0.f, 0.f};
            lg[jt] = __builtin_amdgcn_mfma_f32_16x16x32_bf16(aq, bk, z, 0, 0, 0);
        }
        if (cl >= 8){ lg[7][0] = -1e30f; lg[7][1] = -1e30f; lg[7][2] = -1e30f; lg[7][3] = -1e30f; }

        float inv[4];
        #pragma unroll
        for (int reg = 0; reg < 4; ++reg){
            float m = lg[0][reg];
            #pragma unroll
            for (int jt = 1; jt < 8; ++jt) m = fmaxf(m, lg[jt][reg]);
            m = fmaxf(m, __shfl_xor(m, 1, 64));
            m = fmaxf(m, __shfl_xor(m, 2, 64));
            m = fmaxf(m, __shfl_xor(m, 4, 64));
            m = fmaxf(m, __shfl_xor(m, 8, 64));
            float sum = 0.f;
            #pragma unroll
            for (int jt = 0; jt < 8; ++jt){ float e = __expf(lg[jt][reg] - m); lg[jt][reg] = e; sum += e; }
            sum += __shfl_xor(sum, 1, 64); sum += __shfl_xor(sum, 2, 64);
            sum += __shfl_xor(sum, 4, 64); sum += __shfl_xor(sum, 8, 64);
            inv[reg] = 1.f / sum;
        }

        unsigned short* Pw = P_s + wv * 2176;   // per-wave region: no barriers needed
        #pragma unroll
        for (int jt = 0; jt < 8; ++jt){
            #pragma unroll
            for (int reg = 0; reg < 4; ++reg)
                Pw[(g * 4 + reg) * 136 + jt * 16 + cl] = f2bf(lg[jt][reg] * inv[reg]);
        }

        bf16x8 ap[4];
        #pragma unroll
        for (int ks = 0; ks < 4; ++ks)
            ap[ks] = *(const bf16x8*)(Pw + cl * 136 + ks * 32 + g * 8);
        #pragma unroll
        for (int nt = 0; nt < 2; ++nt){
            f32x4 oacc = {0.f, 0.f, 0.f, 0.f};
            #pragma unroll
            for (int ks = 0; ks < 4; ++ks){
                bf16x8 bv = *(const bf16x8*)(vT + (nt * 16 + cl) * 136 + ks * 32 + g * 8);
                oacc = __builtin_amdgcn_mfma_f32_16x16x32_bf16(ap[ks], bv, oacc, 0, 0, 0);
            }
            #pragma unroll
            for (int reg = 0; reg < 4; ++reg){
                int t = mt * 16 + g * 4 + reg;
                if (t < NTT)
                    o[((size_t)nj * NTT + t) * 128 + h * 32 + nt * 16 + cl] = f2bf(oacc[reg]);
            }
        }
    }
}

// ---------------------------------------------------------------- fused temporal MLP block
__global__ __launch_bounds__(256, 4) void k_tblock(
    const unsigned short* __restrict__ o, const unsigned short* __restrict__ WoB,
    const float* __restrict__ ob, const unsigned short* __restrict__ xbres,
    const float* __restrict__ lnw, const float* __restrict__ lnb,
    const unsigned short* __restrict__ F1B, const float* __restrict__ f1b,
    const unsigned short* __restrict__ F2B, const float* __restrict__ f2b,
    const float* __restrict__ ln2w, const float* __restrict__ ln2b,
    const float* __restrict__ tnw, const float* __restrict__ x,
    float* __restrict__ out)
{
    __shared__ __align__(16) float yf[32 * 132];            // also hb u16[32][264], then yf2
    __shared__ __align__(16) unsigned short xbuf[32 * 136];
    __shared__ int xib[32];
    int tid = threadIdx.x, wv = tid >> 6, lane = tid & 63, cl = lane & 15, g = lane >> 4;
    size_t row0 = (size_t)blockIdx.x * 32;

    if (tid < 32){
        int grow = (int)row0 + tid;
        int t = grow % NTT; int njq = grow / NTT; int j = njq % NJ; int n = njq / NJ;
        xib[tid] = ((n * NTT + t) * NJ + j) * 128;
    }

    // ---- phase 1: out-proj + residual -> yf ----
    {
        int c0 = wv*16 + cl, c1 = c0 + 64;
        bf16x8 B0[4], B1[4];
        #pragma unroll
        for (int ks = 0; ks < 4; ks++){
            B0[ks] = *(const bf16x8*)(WoB + c0*128 + ks*32 + g*8);
            B1[ks] = *(const bf16x8*)(WoB + c1*128 + ks*32 + g*8);
        }
        float b0 = ob[c0], b1 = ob[c1];
        #pragma unroll
        for (int rt = 0; rt < 2; rt++){
            bf16x8 A[4];
            #pragma unroll
            for (int ks = 0; ks < 4; ks++)
                A[ks] = *(const bf16x8*)(o + (row0 + rt*16 + cl)*128 + ks*32 + g*8);
            f32x4 a0 = {0,0,0,0}, a1 = {0,0,0,0};
            #pragma unroll
            for (int ks = 0; ks < 4; ks++){
                a0 = __builtin_amdgcn_mfma_f32_16x16x32_bf16(A[ks], B0[ks], a0, 0, 0, 0);
                a1 = __builtin_amdgcn_mfma_f32_16x16x32_bf16(A[ks], B1[ks], a1, 0, 0, 0);
            }
            #pragma unroll
            for (int reg = 0; reg < 4; reg++){
                int row = rt*16 + g*4 + reg;
                yf[row*132 + c0] = a0[reg] + b0 + bf2f(xbres[(row0 + row)*128 + c0]);
                yf[row*132 + c1] = a1[reg] + b1 + bf2f(xbres[(row0 + row)*128 + c1]);
            }
        }
    }
    __syncthreads();

    // ---- phase 2: LN1 stats + apply (8 lanes/row) -> xbuf ----
    {
        int row = tid >> 3, sub = tid & 7;
        float4 v[4];
        float s1 = 0.f, s2 = 0.f;
        #pragma unroll
        for (int k = 0; k < 4; k++){
            v[k] = *(const float4*)(yf + row*132 + sub*16 + k*4);
            s1 += v[k].x + v[k].y + v[k].z + v[k].w;
            s2 += v[k].x*v[k].x + v[k].y*v[k].y + v[k].z*v[k].z + v[k].w*v[k].w;
        }
        s1 += __shfl_xor(s1, 1, 64); s2 += __shfl_xor(s2, 1, 64);
        s1 += __shfl_xor(s1, 2, 64); s2 += __shfl_xor(s2, 2, 64);
        s1 += __shfl_xor(s1, 4, 64); s2 += __shfl_xor(s2, 4, 64);
        float m = s1 * 0.0078125f;
        float rv = rsqrtf(s2 * 0.0078125f - m*m + 1e-5f);
        #pragma unroll
        for (int k = 0; k < 4; k++){
            float4 w4 = *(const float4*)(lnw + sub*16 + k*4);
            float4 b4 = *(const float4*)(lnb + sub*16 + k*4);
            ushort4 u;
            u.x = f2bf((v[k].x - m) * rv * w4.x + b4.x);
            u.y = f2bf((v[k].y - m) * rv * w4.y + b4.y);
            u.z = f2bf((v[k].z - m) * rv * w4.z + b4.z);
            u.w = f2bf((v[k].w - m) * rv * w4.w + b4.w);
            *(ushort4*)(xbuf + row*136 + sub*16 + k*4) = u;
        }
    }
    __syncthreads();

    // ---- phase 3: FFN1 + gelu -> hb (overlays yf) ----
    unsigned short* hb = (unsigned short*)yf;   // [32][264]
    #pragma unroll
    for (int s = 0; s < 4; s++){
        int c = wv*16 + cl + s*64;
        bf16x8 B[4];
        #pragma unroll
        for (int ks = 0; ks < 4; ks++)
            B[ks] = *(const bf16x8*)(F1B + c*128 + ks*32 + g*8);
        float bias = f1b[c];
        #pragma unroll
        for (int rt = 0; rt < 2; rt++){
            bf16x8 A[4];
            #pragma unroll
            for (int ks = 0; ks < 4; ks++)
                A[ks] = *(const bf16x8*)(xbuf + (rt*16 + cl)*136 + ks*32 + g*8);
            f32x4 acc = {0,0,0,0};
            #pragma unroll
            for (int ks = 0; ks < 4; ks++)
                acc = __builtin_amdgcn_mfma_f32_16x16x32_bf16(A[ks], B[ks], acc, 0, 0, 0);
            #pragma unroll
            for (int reg = 0; reg < 4; reg++){
                int row = rt*16 + g*4 + reg;
                hb[row*264 + c] = f2bf(gelu_exact(acc[reg] + bias));
            }
        }
    }
    __syncthreads();

    // ---- phase 4: FFN2 into registers, then overlay-write yf2 ----
    float ys[2][2][4];
    #pragma unroll
    for (int s = 0; s < 2; s++){
        int c = wv*16 + cl + s*64;
        bf16x8 B[8];
        #pragma unroll
        for (int ks = 0; ks < 8; ks++)
            B[ks] = *(const bf16x8*)(F2B + c*256 + ks*32 + g*8);
        float bias = f2b[c];
        #pragma unroll
        for (int rt = 0; rt < 2; rt++){
            bf16x8 A[8];
            #pragma unroll
            for (int ks = 0; ks < 8; ks++)
                A[ks] = *(const bf16x8*)(hb + (rt*16 + cl)*264 + ks*32 + g*8);
            f32x4 acc = {0,0,0,0};
            #pragma unroll
            for (int ks = 0; ks < 8; ks++)
                acc = __builtin_amdgcn_mfma_f32_16x16x32_bf16(A[ks], B[ks], acc, 0, 0, 0);
            #pragma unroll
            for (int reg = 0; reg < 4; reg++){
                int row = rt*16 + g*4 + reg;
                ys[s][rt][reg] = acc[reg] + bias + bf2f(xbuf[row*136 + c]);
            }
        }
    }
    __syncthreads();
    #pragma unroll
    for (int s = 0; s < 2; s++){
        int c = wv*16 + cl + s*64;
        #pragma unroll
        for (int rt = 0; rt < 2; rt++)
            #pragma unroll
            for (int reg = 0; reg < 4; reg++)
                yf[(rt*16 + g*4 + reg)*132 + c] = ys[s][rt][reg];
    }
    __syncthreads();

    // ---- phase 5: LN2 + RMSNorm + residuals + final write ----
    {
        int row = tid >> 3, sub = tid & 7;
        float4 v[4];
        float s1 = 0.f, s2 = 0.f;
        #pragma unroll
        for (int k = 0; k < 4; k++){
            v[k] = *(const float4*)(yf + row*132 + sub*16 + k*4);
            s1 += v[k].x + v[k].y + v[k].z + v[k].w;
            s2 += v[k].x*v[k].x + v[k].y*v[k].y + v[k].z*v[k].z + v[k].w*v[k].w;
        }
        s1 += __shfl_xor(s1, 1, 64); s2 += __shfl_xor(s2, 1, 64);
        s1 += __shfl_xor(s1, 2, 64); s2 += __shfl_xor(s2, 2, 64);
        s1 += __shfl_xor(s1, 4, 64); s2 += __shfl_xor(s2, 4, 64);
        float m = s1 * 0.0078125f;
        float rv = rsqrtf(s2 * 0.0078125f - m*m + 1e-5f);
        float z[4][4];
        float s3 = 0.f;
        #pragma unroll
        for (int k = 0; k < 4; k++){
            float4 w4 = *(const float4*)(ln2w + sub*16 + k*4);
            float4 b4 = *(const float4*)(ln2b + sub*16 + k*4);
            z[k][0] = (v[k].x - m) * rv * w4.x + b4.x;
            z[k][1] = (v[k].y - m) * rv * w4.y + b4.y;
            z[k][2] = (v[k].z - m) * rv * w4.z + b4.z;
            z[k][3] = (v[k].w - m) * rv * w4.w + b4.w;
            s3 += z[k][0]*z[k][0] + z[k][1]*z[k][1] + z[k][2]*z[k][2] + z[k][3]*z[k][3];
        }
        s3 += __shfl_xor(s3, 1, 64); s3 += __shfl_xor(s3, 2, 64); s3 += __shfl_xor(s3, 4, 64);
        float sr = rsqrtf(s3 * 0.0078125f + 1e-6f);
        int xb0 = xib[row] + sub*16;
        #pragma unroll
        for (int k = 0; k < 4; k++){
            float4 tw4 = *(const float4*)(tnw + sub*16 + k*4);
            ushort4 xr = *(const ushort4*)(xbres + (row0 + row)*128 + sub*16 + k*4);
            float4 xv = *(const float4*)(x + xb0 + k*4);
            float4 ov;
            ov.x = z[k][0] * sr * tw4.x + bf2f(xr.x) + xv.x;
            ov.y = z[k][1] * sr * tw4.y + bf2f(xr.y) + xv.y;
            ov.z = z[k][2] * sr * tw4.z + bf2f(xr.z) + xv.z;
            ov.w = z[k][3] * sr * tw4.w + bf2f(xr.w) + xv.w;
            *(float4*)(out + xb0 + k*4) = ov;
        }
    }
}

// ================================================================ launch
extern "C" void kernel_launch(void* const* d_in, const int* in_sizes, int n_in,
                              void* d_out, int out_size, void* d_ws, size_t ws_size,
                              hipStream_t stream) {
    (void)in_sizes; (void)n_in; (void)out_size;
    const float* x      = (const float*)d_in[0];
    const float* sc     = (const float*)d_in[1];
    const float* gcnw   = (const float*)d_in[2];
    const float* gnw    = (const float*)d_in[3];
    const float* cls    = (const float*)d_in[4];
    const float* sn1    = (const float*)d_in[5];
    const float* sn2    = (const float*)d_in[6];
    const float* s_in_w = (const float*)d_in[7];
    const float* s_in_b = (const float*)d_in[8];
    const float* s_out_w= (const float*)d_in[9];
    const float* s_out_b= (const float*)d_in[10];
    const float* s_f1w  = (const float*)d_in[11];
    const float* s_f1b  = (const float*)d_in[12];
    const float* s_f2w  = (const float*)d_in[13];
    const float* s_f2b  = (const float*)d_in[14];
    const float* t_in_w = (const float*)d_in[15];
    const float* t_in_b = (const float*)d_in[16];
    const float* t_out_w= (const float*)d_in[17];
    const float* t_out_b= (const float*)d_in[18];
    const float* t_ln1w = (const float*)d_in[19];
    const float* t_ln1b = (const float*)d_in[20];
    const float* t_ln2w = (const float*)d_in[21];
    const float* t_ln2b = (const float*)d_in[22];
    const float* t_f1w  = (const float*)d_in[23];
    const float* t_f1b  = (const float*)d_in[24];
    const float* t_f2w  = (const float*)d_in[25];
    const float* t_f2b  = (const float*)d_in[26];
    const float* tnw    = (const float*)d_in[27];

    char* ws = (char*)d_ws;
    const size_t SZ_BIG = 98304000;                 // 192000*128*4
    char*  R1 = ws;                                 // xg (bf16)
    char*  R2 = ws + SZ_BIG;                        // o (bf16)
    char*  R3 = ws + 2 * SZ_BIG;                    // delta (bf16) | xb (bf16)
    char* p = ws + 3 * SZ_BIG;
    int*   ORD  = (int*)p;   p += 768000;
    int*   SLOT = (int*)p;   p += 768000;
    float* PH   = (float*)p; p += 245760;
    unsigned short* WM = (unsigned short*)p; p += 557056;
    if (ws_size < (size_t)(p - ws)) return;

    unsigned short* WinB  = WM;              // s_in_w·sn1w  [384][128]
    unsigned short* WoutB = WM + 49152;      // s_out_w [128][128]
    unsigned short* F1B   = WM + 65536;      // s_f1w·sn2w   [256][128]
    unsigned short* F2B   = WM + 98304;      // s_f2w   [128][256]
    unsigned short* WB    = WM + 131072;     // t_in_w  [384][128]
    unsigned short* WoBt  = WM + 180224;     // t_out_w [128][128]
    unsigned short* F1Bt  = WM + 196608;     // t_f1w   [256][128]
    unsigned short* F2Bt  = WM + 229376;     // t_f2w   [128][256]
    unsigned short* GWt   = WM + 262144;     // gcn_w[0]^T [128][128]

    unsigned short* XG  = (unsigned short*)R1;                    // xg bf16 [192000][128]
    unsigned short* DLT = (unsigned short*)R3;                    // delta [7680*19][128]
    unsigned short* XB  = (unsigned short*)(R3 + 37355520);       // xsp bf16 [192000][128]
    unsigned short* OB  = (unsigned short*)R2;                    // o bf16  [192000][128]

    float* out0 = (float*)d_out;
    float* next_attn = out0 + 24576000;

    k_prep<<<320, 256, 0, stream>>>(s_in_w, s_out_w, s_f1w, s_f2w,
                                    t_in_w, t_out_w, t_f1w, t_f2w, gcnw,
                                    sn1, sn2, WM);
    k_gcn_mfma<<<3000, 256, 0, stream>>>(x, GWt, gnw, XG);
    k_select<<<30, 256, 0, stream>>>(sc, ORD, SLOT, PH);
    k_spatial8<<<3840, 512, 0, stream>>>(XG, ORD, PH, cls,
                                         WinB, s_in_b, WoutB, s_out_b,
                                         F1B, s_f1b, F2B, s_f2b,
                                         DLT, next_attn);
    k_scatter3<<<24000, 256, 0, stream>>>(XG, DLT, SLOT, XB);
    k_tattn2<<<6400, 256, 0, stream>>>(XB, WB, t_in_b, OB);
    k_tblock<<<6000, 256, 0, stream>>>(OB, WoBt, t_out_b, XB,
                                       t_ln1w, t_ln1b, F1Bt, t_f1b,
                                       F2Bt, t_f2b, t_ln2w, t_ln2b,
                                       tnw, x, out0);
}

// Round 17
// 630.608 us; speedup vs baseline: 1.0549x; 1.0382x over previous
//
#include <hip/hip_runtime.h>
#include <hip/hip_bf16.h>
#include <math.h>

// Problem constants
#define NTR   7680      // N*T
#define NJ    25
#define NKEEP 17
#define NDRP  8
#define NL    19
#define NROW  192000    // NT*J == N*J*T
#define NTT   120
#define RSP   24        // padded rows per r in spatial block

typedef __attribute__((ext_vector_type(8))) short bf16x8;
typedef __attribute__((ext_vector_type(4))) float f32x4;

__device__ __forceinline__ float gelu_exact(float v){
    return 0.5f * v * (1.0f + erff(v * 0.70710678118654752440f));
}
__device__ __forceinline__ unsigned short f2bf(float v){
    union { __hip_bfloat16 h; unsigned short u; } c;
    c.h = __float2bfloat16(v);
    return c.u;
}
__device__ __forceinline__ float bf2f(unsigned short u){
    union { unsigned u; float f; } a; a.u = ((unsigned)u) << 16; return a.f;
}

// ---------------------------------------------------------------- all weight preprocessing in one kernel
// Norm-folding: WinB *= sn1w[k], F1B *= sn2w[k] (k = input channel)
__global__ void k_prep(const float* __restrict__ s_in_w, const float* __restrict__ s_out_w,
                       const float* __restrict__ s_f1w,  const float* __restrict__ s_f2w,
                       const float* __restrict__ t_in_w, const float* __restrict__ t_out_w,
                       const float* __restrict__ t_f1w,  const float* __restrict__ t_f2w,
                       const float* __restrict__ gcnw,
                       const float* __restrict__ sn1w,   const float* __restrict__ sn2w,
                       unsigned short* __restrict__ WM)
{
    int i = blockIdx.x * 256 + threadIdx.x;
    if (i < 65536){
        const float* src;
        const float* nw = nullptr;
        int base;
        if      (i < 12288){ src = s_in_w;  base = 0;     nw = sn1w; }
        else if (i < 16384){ src = s_out_w; base = 12288; }
        else if (i < 24576){ src = s_f1w;   base = 16384; nw = sn2w; }
        else if (i < 32768){ src = s_f2w;   base = 24576; }
        else if (i < 45056){ src = t_in_w;  base = 32768; }
        else if (i < 49152){ src = t_out_w; base = 45056; }
        else if (i < 57344){ src = t_f1w;   base = 49152; }
        else               { src = t_f2w;   base = 57344; }
        int loc = i - base;
        float4 v = *(const float4*)(src + loc * 4);
        if (nw){
            float4 w = *(const float4*)(nw + ((loc * 4) & 127));
            v.x *= w.x; v.y *= w.y; v.z *= w.z; v.w *= w.w;
        }
        ushort4 o; o.x = f2bf(v.x); o.y = f2bf(v.y); o.z = f2bf(v.z); o.w = f2bf(v.w);
        *(ushort4*)(WM + i * 4) = o;
    } else if (i < 81920){
        int j = i - 65536;                 // gcn transpose: 16384 elems
        int d = j >> 7, c = j & 127;
        WM[262144 + d * 128 + c] = f2bf(gcnw[c * 128 + d]);
    }
}

// ---------------------------------------------------------------- per-row token selection
__global__ void k_select(const float* __restrict__ sc, int* __restrict__ order,
                         int* __restrict__ slot, float* __restrict__ ph){
    int r = blockIdx.x * blockDim.x + threadIdx.x;
    if (r >= NTR) return;
    float s[NJ]; int id[NJ];
    for (int j = 0; j < NJ; j++){ s[j] = sc[r * NJ + j]; id[j] = j; }
    for (int m = 1; m < NJ; m++){
        float sv = s[m]; int iv = id[m]; int p = m;
        while (p > 0 && s[p-1] < sv){ s[p] = s[p-1]; id[p] = id[p-1]; p--; }
        s[p] = sv; id[p] = iv;
    }
    for (int j = 0; j < NJ; j++) order[r * NJ + j] = id[j];
    for (int i = 0; i < NKEEP; i++)  slot[r * NJ + id[i]] = 1 + i;
    for (int i = NKEEP; i < NJ; i++) slot[r * NJ + id[i]] = 18;
    float m8 = s[NKEEP];
    float e[NDRP]; float sum = 0.f;
    for (int i = 0; i < NDRP; i++){ e[i] = expf(s[NKEEP + i] - m8); sum += e[i]; }
    float inv = 1.f / sum;
    for (int i = 0; i < NDRP; i++) ph[r * NDRP + i] = e[i] * inv;
}

// ---------------------------------------------------------------- spatial transformer v9: fused GCN phase-0
// sm u16 layout: xs[48][136] | U1: xstage[64][136]/Pb[8][32][40] | U3: xgl[50][136]/qk[48][264] |
//                U2: vT[8][32][40] / ao[48][136]
__global__ __launch_bounds__(512, 4) void k_spatial9(
    const float* __restrict__ x, const unsigned short* __restrict__ GWt, const float* __restrict__ gnw,
    const int* __restrict__ order, const float* __restrict__ ph,
    const float* __restrict__ cls_tok,
    const unsigned short* __restrict__ WinB, const float* __restrict__ inb,
    const unsigned short* __restrict__ WoutB, const float* __restrict__ outb,
    const unsigned short* __restrict__ F1B, const float* __restrict__ f1b,
    const unsigned short* __restrict__ F2B, const float* __restrict__ f2b,
    unsigned short* __restrict__ xg_out,
    unsigned short* __restrict__ delta, float* __restrict__ next_attn)
{
    __shared__ __align__(16) unsigned short sm[39680];
    __shared__ float rstd[48];
    __shared__ float ss2[48];
    __shared__ float clsp[8][20];      // attention cls-probs; ALSO gss[64] scratch in phase-0
    __shared__ int   ord_s[2][NJ];
    __shared__ float ph_s[2][NDRP];
    unsigned short* xs     = sm;             // [48][136] x_slow -> x_msa
    unsigned short* xstage = sm + 6528;      // [64][136] phase-0 staging (overlays Pb)
    unsigned short* Pb     = sm + 6528;      // [8][32][40]
    unsigned short* xgl    = sm + 16768;     // [50][136] gcn output (overlays qk)
    unsigned short* qk     = sm + 16768;     // [48][264]
    unsigned short* vT     = sm + 29440;     // [8][32][40]
    unsigned short* ao     = sm + 29440;     // [48][136] overlays vT
    float* gss = &clsp[0][0];                // [64] gcn rms scratch

    int tid = threadIdx.x;
    int r0 = blockIdx.x * 2;
    int wv = tid >> 6, lane = tid & 63, cl = lane & 15, g = lane >> 4;
    const float scale = 0.17677669529663687f;

    if (tid < 2*NJ)   ord_s[tid/NJ][tid%NJ] = order[(r0 + tid/NJ)*NJ + tid%NJ];
    if (tid < 2*NDRP) ph_s[tid>>3][tid&7]   = ph[(r0 + (tid>>3))*NDRP + (tid&7)];
    if (tid < 48) ss2[tid] = 0.f;
    if (tid < 64) gss[tid] = 0.f;
    for (int i = tid; i < 1280; i += 512)
        *(uint4*)(vT + i*8) = make_uint4(0,0,0,0);   // zero U2 (pad keys must be 0)

    // ---- phase 0a: stage x (f32 -> bf16) rows 0..49, zero pad rows 50..63 ----
    {
        const float* xr = x + (size_t)r0 * NJ * 128;
        for (int i = tid; i < 2048; i += 512){
            int row = i >> 5, ch = i & 31;
            ushort4 u;
            if (row < 50){
                float4 v = *(const float4*)(xr + row*128 + ch*4);
                u.x = f2bf(v.x); u.y = f2bf(v.y); u.z = f2bf(v.z); u.w = f2bf(v.w);
            } else { u.x = 0; u.y = 0; u.z = 0; u.w = 0; }
            *(ushort4*)(xstage + row*136 + ch*4) = u;
        }
    }
    __syncthreads();   // ord_s/ph_s/gss/xstage visible

    // ---- phase 0b: GCN GEMM (B resident, col-tile = wv) + fused RMS stats ----
    f32x4 gacc[4];
    {
        int col = wv*16 + cl;
        bf16x8 Bg[4];
        #pragma unroll
        for (int ks = 0; ks < 4; ks++)
            Bg[ks] = *(const bf16x8*)(GWt + col*128 + ks*32 + g*8);
        #pragma unroll
        for (int rt = 0; rt < 4; rt++){
            bf16x8 A[4];
            #pragma unroll
            for (int ks = 0; ks < 4; ks++)
                A[ks] = *(const bf16x8*)(xstage + (rt*16 + cl)*136 + ks*32 + g*8);
            f32x4 acc = {0,0,0,0};
            #pragma unroll
            for (int ks = 0; ks < 4; ks++)
                acc = __builtin_amdgcn_mfma_f32_16x16x32_bf16(A[ks], Bg[ks], acc, 0, 0, 0);
            gacc[rt] = acc;
            #pragma unroll
            for (int reg = 0; reg < 4; reg++){
                int row = rt*16 + g*4 + reg;
                float p = acc[reg] * acc[reg];
                p += __shfl_xor(p, 1, 64); p += __shfl_xor(p, 2, 64);
                p += __shfl_xor(p, 4, 64); p += __shfl_xor(p, 8, 64);
                if (cl == 0) atomicAdd(&gss[row], p);
            }
        }
    }
    __syncthreads();
    if (tid < 64) gss[tid] = rsqrtf(gss[tid] * 0.0078125f + 1e-6f);
    __syncthreads();
    // ---- phase 0c: apply gnw * rstd -> xgl (LDS) ----
    {
        int col = wv*16 + cl;
        float gw = gnw[col];
        #pragma unroll
        for (int rt = 0; rt < 4; rt++){
            #pragma unroll
            for (int reg = 0; reg < 4; reg++){
                int row = rt*16 + g*4 + reg;
                if (row < 50)
                    xgl[row*136 + col] = f2bf(gacc[rt][reg] * gss[row] * gw);
            }
        }
    }
    __syncthreads();   // xgl complete

    // ---- phase 0d: vectorized copy xgl -> global XG (for k_scatter3) ----
    {
        unsigned short* dst = xg_out + (size_t)r0 * NJ * 128;
        for (int i = tid; i < 1600; i += 512){   // 50 rows x 32 quads
            int row = i >> 5, ch = i & 31;
            *(ushort4*)(dst + row*128 + ch*4) = *(const ushort4*)(xgl + row*136 + ch*4);
        }
    }

    // ---- build x_slow (gather from LDS xgl) + fused rmsnorm1 stats (32 lanes per row) ----
    {
        int ln = tid & 31;
        for (int j = tid >> 5; j < 48; j += 16){
            int rr = j / RSP, t = j - rr * RSP;
            const unsigned short* xgr = xgl + rr * NJ * 136;
            float v0, v1, v2, v3;
            if (t == 0){
                float4 cv = *(const float4*)(cls_tok + ln*4);
                v0 = cv.x; v1 = cv.y; v2 = cv.z; v3 = cv.w;
            } else if (t <= NKEEP){
                ushort4 u = *(const ushort4*)(xgr + ord_s[rr][t-1]*136 + ln*4);
                v0 = bf2f(u.x); v1 = bf2f(u.y); v2 = bf2f(u.z); v3 = bf2f(u.w);
            } else if (t == 18){
                v0 = v1 = v2 = v3 = 0.f;
                for (int i = 0; i < NDRP; i++){
                    ushort4 u = *(const ushort4*)(xgr + ord_s[rr][NKEEP+i]*136 + ln*4);
                    float w = ph_s[rr][i];
                    v0 = fmaf(bf2f(u.x),w,v0); v1 = fmaf(bf2f(u.y),w,v1);
                    v2 = fmaf(bf2f(u.z),w,v2); v3 = fmaf(bf2f(u.w),w,v3);
                }
            } else { v0 = v1 = v2 = v3 = 0.f; }
            ushort4 o4; o4.x=f2bf(v0); o4.y=f2bf(v1); o4.z=f2bf(v2); o4.w=f2bf(v3);
            *(ushort4*)(xs + j*136 + ln*4) = o4;
            float p = v0*v0 + v1*v1 + v2*v2 + v3*v3;
            p += __shfl_xor(p, 1, 64); p += __shfl_xor(p, 2, 64);
            p += __shfl_xor(p, 4, 64); p += __shfl_xor(p, 8, 64);
            p += __shfl_xor(p, 16, 64);
            if (ln == 0) rstd[j] = rsqrtf(p * 0.0078125f + 1e-6f);
        }
    }
    __syncthreads();   // xgl dead; qkv may overwrite qk region

    // ---- qkv GEMM on RAW xs (sn1w folded into WinB); epilogue scales by rstd[row] ----
    {
        int col = wv*16 + cl;
        bf16x8 Bq[4], Bk[4], Bv[4];
        #pragma unroll
        for (int ks = 0; ks < 4; ks++){
            Bq[ks] = *(const bf16x8*)(WinB + col*128        + ks*32 + g*8);
            Bk[ks] = *(const bf16x8*)(WinB + (128+col)*128  + ks*32 + g*8);
            Bv[ks] = *(const bf16x8*)(WinB + (256+col)*128  + ks*32 + g*8);
        }
        float bq = inb[col], bk = inb[128+col], bv = inb[256+col];
        int h = col >> 5, d = col & 31;
        #pragma unroll
        for (int rt = 0; rt < 3; rt++){
            bf16x8 A[4];
            #pragma unroll
            for (int ks = 0; ks < 4; ks++)
                A[ks] = *(const bf16x8*)(xs + (rt*16 + cl)*136 + ks*32 + g*8);
            f32x4 aq = {0,0,0,0}, ak = {0,0,0,0}, av = {0,0,0,0};
            #pragma unroll
            for (int ks = 0; ks < 4; ks++){
                aq = __builtin_amdgcn_mfma_f32_16x16x32_bf16(A[ks], Bq[ks], aq, 0, 0, 0);
                ak = __builtin_amdgcn_mfma_f32_16x16x32_bf16(A[ks], Bk[ks], ak, 0, 0, 0);
                av = __builtin_amdgcn_mfma_f32_16x16x32_bf16(A[ks], Bv[ks], av, 0, 0, 0);
            }
            #pragma unroll
            for (int reg = 0; reg < 4; reg++){
                int row = rt*16 + g*4 + reg;
                float rs = rstd[row];
                qk[row*264 + col]       = f2bf((aq[reg]*rs + bq) * scale);
                qk[row*264 + 128 + col] = f2bf(ak[reg]*rs + bk);
                int rr = row >= RSP; int key = row - rr*RSP;
                vT[(rr*4 + h)*1280 + d*40 + key] = f2bf(av[reg]*rs + bv);
            }
        }
    }
    __syncthreads();

    // ---- attention: 1 (rr,h) pair per wave; P region is per-wave -> NO mid barrier ----
    {
        int qh = wv;
        int rr = qh >> 2, h = qh & 3;
        bf16x8 aq[2];
        #pragma unroll
        for (int qt = 0; qt < 2; qt++)
            aq[qt] = *(const bf16x8*)(qk + (rr*RSP + qt*16 + cl)*264 + h*32 + g*8);
        f32x4 lg[2][2];
        #pragma unroll
        for (int kt = 0; kt < 2; kt++){
            bf16x8 bk = *(const bf16x8*)(qk + (rr*RSP + kt*16 + cl)*264 + 128 + h*32 + g*8);
            f32x4 z = {0.f, 0.f, 0.f, 0.f};
            lg[0][kt] = __builtin_amdgcn_mfma_f32_16x16x32_bf16(aq[0], bk, z, 0, 0, 0);
            lg[1][kt] = __builtin_amdgcn_mfma_f32_16x16x32_bf16(aq[1], bk, z, 0, 0, 0);
        }
        #pragma unroll
        for (int qt = 0; qt < 2; qt++){
            #pragma unroll
            for (int reg = 0; reg < 4; reg++){
                float l0 = lg[qt][0][reg];
                float l1 = (cl >= 3) ? -1e30f : lg[qt][1][reg];
                float m = fmaxf(l0, l1);
                m = fmaxf(m, __shfl_xor(m, 1, 64));
                m = fmaxf(m, __shfl_xor(m, 2, 64));
                m = fmaxf(m, __shfl_xor(m, 4, 64));
                m = fmaxf(m, __shfl_xor(m, 8, 64));
                float e0 = __expf(l0 - m), e1 = __expf(l1 - m);
                float ssum = e0 + e1;
                ssum += __shfl_xor(ssum, 1, 64); ssum += __shfl_xor(ssum, 2, 64);
                ssum += __shfl_xor(ssum, 4, 64); ssum += __shfl_xor(ssum, 8, 64);
                float inv = 1.f / ssum;
                e0 *= inv; e1 *= inv;
                int q = qt*16 + g*4 + reg;
                Pb[qh*1280 + q*40 + cl]      = f2bf(e0);
                Pb[qh*1280 + q*40 + 16 + cl] = f2bf(e1);
                if (qt == 0 && g == 0 && reg == 0){
                    clsp[qh][cl] = e0;
                    if (cl < 4) clsp[qh][16 + cl] = e1;
                }
            }
        }
        // no barrier: Pb[qh] and vT[qh] consumed only by this wave; PV writes only
        // the qk columns (h*32..) that this wave alone read as Q.
        bf16x8 ap[2];
        #pragma unroll
        for (int qt = 0; qt < 2; qt++)
            ap[qt] = *(const bf16x8*)(Pb + qh*1280 + (qt*16 + cl)*40 + g*8);
        #pragma unroll
        for (int dt = 0; dt < 2; dt++){
            bf16x8 bv = *(const bf16x8*)(vT + qh*1280 + (dt*16 + cl)*40 + g*8);
            #pragma unroll
            for (int qt = 0; qt < 2; qt++){
                f32x4 z = {0.f, 0.f, 0.f, 0.f};
                f32x4 oa = __builtin_amdgcn_mfma_f32_16x16x32_bf16(ap[qt], bv, z, 0, 0, 0);
                #pragma unroll
                for (int reg = 0; reg < 4; reg++){
                    int q = qt*16 + g*4 + reg;
                    if (q < 19)
                        qk[(rr*RSP + q)*264 + h*32 + dt*16 + cl] = f2bf(oa[reg]);
                    else if (q < RSP)
                        qk[(rr*RSP + q)*264 + h*32 + dt*16 + cl] = 0;
                }
            }
        }
        __syncthreads();
    }

    // ---- next_attn ----
    if (tid < 36){
        int rr2 = tid / 18, t = tid - rr2*18;
        float v = 0.25f * (clsp[rr2*4+0][1+t] + clsp[rr2*4+1][1+t] +
                           clsp[rr2*4+2][1+t] + clsp[rr2*4+3][1+t]);
        int r = r0 + rr2;
        if (t < NKEEP) next_attn[r*NJ + ord_s[rr2][t]] = v;
        else { for (int i = 0; i < NDRP; i++) next_attn[r*NJ + ord_s[rr2][NKEEP+i]] = v; }
    }

    // ---- out-proj: B resident; fused rmsnorm2 stats on x_msa ----
    {
        int col = wv*16 + cl;
        bf16x8 B[4];
        #pragma unroll
        for (int ks = 0; ks < 4; ks++)
            B[ks] = *(const bf16x8*)(WoutB + col*128 + ks*32 + g*8);
        float bias = outb[col];
        #pragma unroll
        for (int rt = 0; rt < 3; rt++){
            bf16x8 A[4];
            #pragma unroll
            for (int ks = 0; ks < 4; ks++)
                A[ks] = *(const bf16x8*)(qk + (rt*16 + cl)*264 + ks*32 + g*8);
            f32x4 acc = {0,0,0,0};
            #pragma unroll
            for (int ks = 0; ks < 4; ks++)
                acc = __builtin_amdgcn_mfma_f32_16x16x32_bf16(A[ks], B[ks], acc, 0, 0, 0);
            #pragma unroll
            for (int reg = 0; reg < 4; reg++){
                int row = rt*16 + g*4 + reg;
                float v = acc[reg] + bias;
                float msa = bf2f(xs[row*136 + col]) + v;
                ao[row*136 + col] = f2bf(v);
                xs[row*136 + col] = f2bf(msa);
                float p = msa * msa;
                p += __shfl_xor(p, 1, 64); p += __shfl_xor(p, 2, 64);
                p += __shfl_xor(p, 4, 64); p += __shfl_xor(p, 8, 64);
                if (cl == 0) atomicAdd(&ss2[row], p);
            }
        }
    }
    __syncthreads();

    if (tid < 48) rstd[tid] = rsqrtf(ss2[tid] * 0.0078125f + 1e-6f);
    __syncthreads();

    // ---- ffn1 + gelu on RAW x_msa (sn2w folded into F1B); epilogue scales by rstd[row] ----
    {
        int c0 = wv*16 + cl, c1 = c0 + 128;
        bf16x8 B0[4], B1[4];
        #pragma unroll
        for (int ks = 0; ks < 4; ks++){
            B0[ks] = *(const bf16x8*)(F1B + c0*128 + ks*32 + g*8);
            B1[ks] = *(const bf16x8*)(F1B + c1*128 + ks*32 + g*8);
        }
        float b0 = f1b[c0], b1 = f1b[c1];
        #pragma unroll
        for (int rt = 0; rt < 3; rt++){
            bf16x8 A[4];
            #pragma unroll
            for (int ks = 0; ks < 4; ks++)
                A[ks] = *(const bf16x8*)(xs + (rt*16 + cl)*136 + ks*32 + g*8);
            f32x4 a0 = {0,0,0,0}, a1 = {0,0,0,0};
            #pragma unroll
            for (int ks = 0; ks < 4; ks++){
                a0 = __builtin_amdgcn_mfma_f32_16x16x32_bf16(A[ks], B0[ks], a0, 0, 0, 0);
                a1 = __builtin_amdgcn_mfma_f32_16x16x32_bf16(A[ks], B1[ks], a1, 0, 0, 0);
            }
            #pragma unroll
            for (int reg = 0; reg < 4; reg++){
                int row = rt*16 + g*4 + reg;
                float rs = rstd[row];
                qk[row*264 + c0] = f2bf(gelu_exact(a0[reg]*rs + b0));
                qk[row*264 + c1] = f2bf(gelu_exact(a1[reg]*rs + b1));
            }
        }
    }
    __syncthreads();

    // ---- ffn2 + delta: B resident (8 k-slices) ----
    {
        int col = wv*16 + cl;
        bf16x8 B[8];
        #pragma unroll
        for (int ks = 0; ks < 8; ks++)
            B[ks] = *(const bf16x8*)(F2B + col*256 + ks*32 + g*8);
        float bias = f2b[col];
        #pragma unroll
        for (int rt = 0; rt < 3; rt++){
            bf16x8 A[8];
            #pragma unroll
            for (int ks = 0; ks < 8; ks++)
                A[ks] = *(const bf16x8*)(qk + (rt*16 + cl)*264 + ks*32 + g*8);
            f32x4 acc = {0,0,0,0};
            #pragma unroll
            for (int ks = 0; ks < 8; ks++)
                acc = __builtin_amdgcn_mfma_f32_16x16x32_bf16(A[ks], B[ks], acc, 0, 0, 0);
            #pragma unroll
            for (int reg = 0; reg < 4; reg++){
                int row = rt*16 + g*4 + reg;
                int rr = row >= RSP; int tok = row - rr*RSP;
                if (tok < 19){
                    float dv = acc[reg] + bias + bf2f(ao[row*136 + col]);
                    delta[((size_t)(r0 + rr)*19 + tok)*128 + col] = f2bf(dv);
                }
            }
        }
    }
}

// ---------------------------------------------------------------- scatter: bf16 xg in, bf16 xsp out
__global__ void k_scatter3(const unsigned short* __restrict__ xg, const unsigned short* __restrict__ delta,
                           const int* __restrict__ slot, unsigned short* __restrict__ xb){
    int i = blockIdx.x * 256 + threadIdx.x;   // 6,144,000 quads
    int e = i * 4;
    int c = e & 127; int rem = e >> 7;
    int t = rem % NTT; int nj = rem / NTT; int j = nj % NJ; int n = nj / NJ;
    int r = n * NTT + t;
    int sl = slot[r * NJ + j];
    ushort4 xv = *(const ushort4*)(xg + ((size_t)r * NJ + j) * 128 + c);
    ushort4 dv = *(const ushort4*)(delta + ((size_t)r * 19 + sl) * 128 + c);
    ushort4 ob;
    ob.x = f2bf(2.f * bf2f(xv.x) + bf2f(dv.x));
    ob.y = f2bf(2.f * bf2f(xv.y) + bf2f(dv.y));
    ob.z = f2bf(2.f * bf2f(xv.z) + bf2f(dv.z));
    ob.w = f2bf(2.f * bf2f(xv.w) + bf2f(dv.w));
    *(ushort4*)(xb + e) = ob;
}

// ---------------------------------------------------------------- temporal attention: 4 waves per (nj, head), bf16 out
// P region is per-wave -> NO barriers in the attention loop (waves drift freely)
__global__ __launch_bounds__(256, 3) void k_tattn2(
    const unsigned short* __restrict__ xb, const unsigned short* __restrict__ Wb,
    const float* __restrict__ inb, unsigned short* __restrict__ o)
{
    // LDS u16: q[120][40] | k[120][40] | vT[32][136] | P[4][16][136] = 45,312 B
    __shared__ __align__(16) unsigned short smem[22656];
    unsigned short* q_s = smem;
    unsigned short* k_s = smem + 4800;
    unsigned short* vT  = smem + 9600;
    unsigned short* P_s = smem + 13952;

    int tid = threadIdx.x;
    int l = tid & 63, cl = l & 15, g = l >> 4, wv = tid >> 6;
    int nj = blockIdx.x >> 2;
    int h  = blockIdx.x & 3;

    vT[(tid >> 3) * 136 + 120 + (tid & 7)] = 0;   // zero pad key cols

    const unsigned short* xrow = xb + (size_t)nj * (NTT * 128);
    const float scale = 0.17677669529663687f;

    bf16x8 bfr[6][4];
    float bias[6];
    #pragma unroll
    for (int pc = 0; pc < 6; ++pc){
        int p = pc >> 1, s = pc & 1;
        int col = p * 128 + h * 32 + s * 16 + cl;
        bias[pc] = inb[col];
        #pragma unroll
        for (int ks = 0; ks < 4; ++ks)
            bfr[pc][ks] = *(const bf16x8*)(Wb + col * 128 + ks * 32 + g * 8);
    }

    for (int mt = wv; mt < 8; mt += 4){
        bf16x8 af[4];
        #pragma unroll
        for (int ks = 0; ks < 4; ++ks)
            af[ks] = *(const bf16x8*)(xrow + (mt * 16 + cl) * 128 + ks * 32 + g * 8);
        #pragma unroll
        for (int pc = 0; pc < 6; ++pc){
            f32x4 acc = {0.f, 0.f, 0.f, 0.f};
            #pragma unroll
            for (int ks = 0; ks < 4; ++ks)
                acc = __builtin_amdgcn_mfma_f32_16x16x32_bf16(af[ks], bfr[pc][ks], acc, 0, 0, 0);
            int p = pc >> 1, s = pc & 1;
            int d = s * 16 + cl;
            #pragma unroll
            for (int reg = 0; reg < 4; ++reg){
                int t = mt * 16 + g * 4 + reg;
                if (t < NTT){
                    float v = acc[reg] + bias[pc];
                    if (p == 0)      q_s[t * 40 + d] = f2bf(v * scale);
                    else if (p == 1) k_s[t * 40 + d] = f2bf(v);
                    else             vT[d * 136 + t] = f2bf(v);
                }
            }
        }
    }
    __syncthreads();   // q/k/vT stable from here; below only per-wave P region is touched

    for (int s = 0; s < 2; ++s){
        int mt = wv + s * 4;
        bf16x8 aq = *(const bf16x8*)(q_s + (mt * 16 + cl) * 40 + g * 8);
        f32x4 lg[8];
        #pragma unroll
        for (int jt = 0; jt < 8; ++jt){
            bf16x8 bk = *(const bf16x8*)(k_s + (jt * 16 + cl) * 40 + g * 8);
            f32x4 z = {0.f, 0.f, 0.f, 0.f};
            lg[jt] = __builtin_amdgcn_mfma_f32_16x16x32_bf16(aq, bk, z, 0, 0, 0);
        }
        if (cl >= 8){ lg[7][0] = -1e30f; lg[7][1] = -1e30f; lg[7][2] = -1e30f; lg[7][3] = -1e30f; }

        float inv[4];
        #pragma unroll
        for (int reg = 0; reg < 4; ++reg){
            float m = lg[0][reg];
            #pragma unroll
            for (int jt = 1; jt < 8; ++jt) m = fmaxf(m, lg[jt][reg]);
            m = fmaxf(m, __shfl_xor(m, 1, 64));
            m = fmaxf(m, __shfl_xor(m, 2, 64));
            m = fmaxf(m, __shfl_xor(m, 4, 64));
            m = fmaxf(m, __shfl_xor(m, 8, 64));
            float sum = 0.f;
            #pragma unroll
            for (int jt = 0; jt < 8; ++jt){ float e = __expf(lg[jt][reg] - m); lg[jt][reg] = e; sum += e; }
            sum += __shfl_xor(sum, 1, 64); sum += __shfl_xor(sum, 2, 64);
            sum += __shfl_xor(sum, 4, 64); sum += __shfl_xor(sum, 8, 64);
            inv[reg] = 1.f / sum;
        }

        unsigned short* Pw = P_s + wv * 2176;   // per-wave region: no barriers needed
        #pragma unroll
        for (int jt = 0; jt < 8; ++jt){
            #pragma unroll
            for (int reg = 0; reg < 4; ++reg)
                Pw[(g * 4 + reg) * 136 + jt * 16 + cl] = f2bf(lg[jt][reg] * inv[reg]);
        }

        bf16x8 ap[4];
        #pragma unroll
        for (int ks = 0; ks < 4; ++ks)
            ap[ks] = *(const bf16x8*)(Pw + cl * 136 + ks * 32 + g * 8);
        #pragma unroll
        for (int nt = 0; nt < 2; ++nt){
            f32x4 oacc = {0.f, 0.f, 0.f, 0.f};
            #pragma unroll
            for (int ks = 0; ks < 4; ++ks){
                bf16x8 bv = *(const bf16x8*)(vT + (nt * 16 + cl) * 136 + ks * 32 + g * 8);
                oacc = __builtin_amdgcn_mfma_f32_16x16x32_bf16(ap[ks], bv, oacc, 0, 0, 0);
            }
            #pragma unroll
            for (int reg = 0; reg < 4; ++reg){
                int t = mt * 16 + g * 4 + reg;
                if (t < NTT)
                    o[((size_t)nj * NTT + t) * 128 + h * 32 + nt * 16 + cl] = f2bf(oacc[reg]);
            }
        }
    }
}

// ---------------------------------------------------------------- fused temporal MLP block
__global__ __launch_bounds__(256, 4) void k_tblock(
    const unsigned short* __restrict__ o, const unsigned short* __restrict__ WoB,
    const float* __restrict__ ob, const unsigned short* __restrict__ xbres,
    const float* __restrict__ lnw, const float* __restrict__ lnb,
    const unsigned short* __restrict__ F1B, const float* __restrict__ f1b,
    const unsigned short* __restrict__ F2B, const float* __restrict__ f2b,
    const float* __restrict__ ln2w, const float* __restrict__ ln2b,
    const float* __restrict__ tnw, const float* __restrict__ x,
    float* __restrict__ out)
{
    __shared__ __align__(16) float yf[32 * 132];            // also hb u16[32][264], then yf2
    __shared__ __align__(16) unsigned short xbuf[32 * 136];
    __shared__ int xib[32];
    int tid = threadIdx.x, wv = tid >> 6, lane = tid & 63, cl = lane & 15, g = lane >> 4;
    size_t row0 = (size_t)blockIdx.x * 32;

    if (tid < 32){
        int grow = (int)row0 + tid;
        int t = grow % NTT; int njq = grow / NTT; int j = njq % NJ; int n = njq / NJ;
        xib[tid] = ((n * NTT + t) * NJ + j) * 128;
    }

    // ---- phase 1: out-proj + residual -> yf ----
    {
        int c0 = wv*16 + cl, c1 = c0 + 64;
        bf16x8 B0[4], B1[4];
        #pragma unroll
        for (int ks = 0; ks < 4; ks++){
            B0[ks] = *(const bf16x8*)(WoB + c0*128 + ks*32 + g*8);
            B1[ks] = *(const bf16x8*)(WoB + c1*128 + ks*32 + g*8);
        }
        float b0 = ob[c0], b1 = ob[c1];
        #pragma unroll
        for (int rt = 0; rt < 2; rt++){
            bf16x8 A[4];
            #pragma unroll
            for (int ks = 0; ks < 4; ks++)
                A[ks] = *(const bf16x8*)(o + (row0 + rt*16 + cl)*128 + ks*32 + g*8);
            f32x4 a0 = {0,0,0,0}, a1 = {0,0,0,0};
            #pragma unroll
            for (int ks = 0; ks < 4; ks++){
                a0 = __builtin_amdgcn_mfma_f32_16x16x32_bf16(A[ks], B0[ks], a0, 0, 0, 0);
                a1 = __builtin_amdgcn_mfma_f32_16x16x32_bf16(A[ks], B1[ks], a1, 0, 0, 0);
            }
            #pragma unroll
            for (int reg = 0; reg < 4; reg++){
                int row = rt*16 + g*4 + reg;
                yf[row*132 + c0] = a0[reg] + b0 + bf2f(xbres[(row0 + row)*128 + c0]);
                yf[row*132 + c1] = a1[reg] + b1 + bf2f(xbres[(row0 + row)*128 + c1]);
            }
        }
    }
    __syncthreads();

    // ---- phase 2: LN1 stats + apply (8 lanes/row) -> xbuf ----
    {
        int row = tid >> 3, sub = tid & 7;
        float4 v[4];
        float s1 = 0.f, s2 = 0.f;
        #pragma unroll
        for (int k = 0; k < 4; k++){
            v[k] = *(const float4*)(yf + row*132 + sub*16 + k*4);
            s1 += v[k].x + v[k].y + v[k].z + v[k].w;
            s2 += v[k].x*v[k].x + v[k].y*v[k].y + v[k].z*v[k].z + v[k].w*v[k].w;
        }
        s1 += __shfl_xor(s1, 1, 64); s2 += __shfl_xor(s2, 1, 64);
        s1 += __shfl_xor(s1, 2, 64); s2 += __shfl_xor(s2, 2, 64);
        s1 += __shfl_xor(s1, 4, 64); s2 += __shfl_xor(s2, 4, 64);
        float m = s1 * 0.0078125f;
        float rv = rsqrtf(s2 * 0.0078125f - m*m + 1e-5f);
        #pragma unroll
        for (int k = 0; k < 4; k++){
            float4 w4 = *(const float4*)(lnw + sub*16 + k*4);
            float4 b4 = *(const float4*)(lnb + sub*16 + k*4);
            ushort4 u;
            u.x = f2bf((v[k].x - m) * rv * w4.x + b4.x);
            u.y = f2bf((v[k].y - m) * rv * w4.y + b4.y);
            u.z = f2bf((v[k].z - m) * rv * w4.z + b4.z);
            u.w = f2bf((v[k].w - m) * rv * w4.w + b4.w);
            *(ushort4*)(xbuf + row*136 + sub*16 + k*4) = u;
        }
    }
    __syncthreads();

    // ---- phase 3: FFN1 + gelu -> hb (overlays yf) ----
    unsigned short* hb = (unsigned short*)yf;   // [32][264]
    #pragma unroll
    for (int s = 0; s < 4; s++){
        int c = wv*16 + cl + s*64;
        bf16x8 B[4];
        #pragma unroll
        for (int ks = 0; ks < 4; ks++)
            B[ks] = *(const bf16x8*)(F1B + c*128 + ks*32 + g*8);
        float bias = f1b[c];
        #pragma unroll
        for (int rt = 0; rt < 2; rt++){
            bf16x8 A[4];
            #pragma unroll
            for (int ks = 0; ks < 4; ks++)
                A[ks] = *(const bf16x8*)(xbuf + (rt*16 + cl)*136 + ks*32 + g*8);
            f32x4 acc = {0,0,0,0};
            #pragma unroll
            for (int ks = 0; ks < 4; ks++)
                acc = __builtin_amdgcn_mfma_f32_16x16x32_bf16(A[ks], B[ks], acc, 0, 0, 0);
            #pragma unroll
            for (int reg = 0; reg < 4; reg++){
                int row = rt*16 + g*4 + reg;
                hb[row*264 + c] = f2bf(gelu_exact(acc[reg] + bias));
            }
        }
    }
    __syncthreads();

    // ---- phase 4: FFN2 into registers, then overlay-write yf2 ----
    float ys[2][2][4];
    #pragma unroll
    for (int s = 0; s < 2; s++){
        int c = wv*16 + cl + s*64;
        bf16x8 B[8];
        #pragma unroll
        for (int ks = 0; ks < 8; ks++)
            B[ks] = *(const bf16x8*)(F2B + c*256 + ks*32 + g*8);
        float bias = f2b[c];
        #pragma unroll
        for (int rt = 0; rt < 2; rt++){
            bf16x8 A[8];
            #pragma unroll
            for (int ks = 0; ks < 8; ks++)
                A[ks] = *(const bf16x8*)(hb + (rt*16 + cl)*264 + ks*32 + g*8);
            f32x4 acc = {0,0,0,0};
            #pragma unroll
            for (int ks = 0; ks < 8; ks++)
                acc = __builtin_amdgcn_mfma_f32_16x16x32_bf16(A[ks], B[ks], acc, 0, 0, 0);
            #pragma unroll
            for (int reg = 0; reg < 4; reg++){
                int row = rt*16 + g*4 + reg;
                ys[s][rt][reg] = acc[reg] + bias + bf2f(xbuf[row*136 + c]);
            }
        }
    }
    __syncthreads();
    #pragma unroll
    for (int s = 0; s < 2; s++){
        int c = wv*16 + cl + s*64;
        #pragma unroll
        for (int rt = 0; rt < 2; rt++)
            #pragma unroll
            for (int reg = 0; reg < 4; reg++)
                yf[(rt*16 + g*4 + reg)*132 + c] = ys[s][rt][reg];
    }
    __syncthreads();

    // ---- phase 5: LN2 + RMSNorm + residuals + final write ----
    {
        int row = tid >> 3, sub = tid & 7;
        float4 v[4];
        float s1 = 0.f, s2 = 0.f;
        #pragma unroll
        for (int k = 0; k < 4; k++){
            v[k] = *(const float4*)(yf + row*132 + sub*16 + k*4);
            s1 += v[k].x + v[k].y + v[k].z + v[k].w;
            s2 += v[k].x*v[k].x + v[k].y*v[k].y + v[k].z*v[k].z + v[k].w*v[k].w;
        }
        s1 += __shfl_xor(s1, 1, 64); s2 += __shfl_xor(s2, 1, 64);
        s1 += __shfl_xor(s1, 2, 64); s2 += __shfl_xor(s2, 2, 64);
        s1 += __shfl_xor(s1, 4, 64); s2 += __shfl_xor(s2, 4, 64);
        float m = s1 * 0.0078125f;
        float rv = rsqrtf(s2 * 0.0078125f - m*m + 1e-5f);
        float z[4][4];
        float s3 = 0.f;
        #pragma unroll
        for (int k = 0; k < 4; k++){
            float4 w4 = *(const float4*)(ln2w + sub*16 + k*4);
            float4 b4 = *(const float4*)(ln2b + sub*16 + k*4);
            z[k][0] = (v[k].x - m) * rv * w4.x + b4.x;
            z[k][1] = (v[k].y - m) * rv * w4.y + b4.y;
            z[k][2] = (v[k].z - m) * rv * w4.z + b4.z;
            z[k][3] = (v[k].w - m) * rv * w4.w + b4.w;
            s3 += z[k][0]*z[k][0] + z[k][1]*z[k][1] + z[k][2]*z[k][2] + z[k][3]*z[k][3];
        }
        s3 += __shfl_xor(s3, 1, 64); s3 += __shfl_xor(s3, 2, 64); s3 += __shfl_xor(s3, 4, 64);
        float sr = rsqrtf(s3 * 0.0078125f + 1e-6f);
        int xb0 = xib[row] + sub*16;
        #pragma unroll
        for (int k = 0; k < 4; k++){
            float4 tw4 = *(const float4*)(tnw + sub*16 + k*4);
            ushort4 xr = *(const ushort4*)(xbres + (row0 + row)*128 + sub*16 + k*4);
            float4 xv = *(const float4*)(x + xb0 + k*4);
            float4 ov;
            ov.x = z[k][0] * sr * tw4.x + bf2f(xr.x) + xv.x;
            ov.y = z[k][1] * sr * tw4.y + bf2f(xr.y) + xv.y;
            ov.z = z[k][2] * sr * tw4.z + bf2f(xr.z) + xv.z;
            ov.w = z[k][3] * sr * tw4.w + bf2f(xr.w) + xv.w;
            *(float4*)(out + xb0 + k*4) = ov;
        }
    }
}

// ================================================================ launch
extern "C" void kernel_launch(void* const* d_in, const int* in_sizes, int n_in,
                              void* d_out, int out_size, void* d_ws, size_t ws_size,
                              hipStream_t stream) {
    (void)in_sizes; (void)n_in; (void)out_size;
    const float* x      = (const float*)d_in[0];
    const float* sc     = (const float*)d_in[1];
    const float* gcnw   = (const float*)d_in[2];
    const float* gnw    = (const float*)d_in[3];
    const float* cls    = (const float*)d_in[4];
    const float* sn1    = (const float*)d_in[5];
    const float* sn2    = (const float*)d_in[6];
    const float* s_in_w = (const float*)d_in[7];
    const float* s_in_b = (const float*)d_in[8];
    const float* s_out_w= (const float*)d_in[9];
    const float* s_out_b= (const float*)d_in[10];
    const float* s_f1w  = (const float*)d_in[11];
    const float* s_f1b  = (const float*)d_in[12];
    const float* s_f2w  = (const float*)d_in[13];
    const float* s_f2b  = (const float*)d_in[14];
    const float* t_in_w = (const float*)d_in[15];
    const float* t_in_b = (const float*)d_in[16];
    const float* t_out_w= (const float*)d_in[17];
    const float* t_out_b= (const float*)d_in[18];
    const float* t_ln1w = (const float*)d_in[19];
    const float* t_ln1b = (const float*)d_in[20];
    const float* t_ln2w = (const float*)d_in[21];
    const float* t_ln2b = (const float*)d_in[22];
    const float* t_f1w  = (const float*)d_in[23];
    const float* t_f1b  = (const float*)d_in[24];
    const float* t_f2w  = (const float*)d_in[25];
    const float* t_f2b  = (const float*)d_in[26];
    const float* tnw    = (const float*)d_in[27];

    char* ws = (char*)d_ws;
    const size_t SZ_BIG = 98304000;                 // 192000*128*4
    char*  R1 = ws;                                 // xg (bf16)
    char*  R2 = ws + SZ_BIG;                        // o (bf16)
    char*  R3 = ws + 2 * SZ_BIG;                    // delta (bf16) | xb (bf16)
    char* p = ws + 3 * SZ_BIG;
    int*   ORD  = (int*)p;   p += 768000;
    int*   SLOT = (int*)p;   p += 768000;
    float* PH   = (float*)p; p += 245760;
    unsigned short* WM = (unsigned short*)p; p += 557056;
    if (ws_size < (size_t)(p - ws)) return;

    unsigned short* WinB  = WM;              // s_in_w·sn1w  [384][128]
    unsigned short* WoutB = WM + 49152;      // s_out_w [128][128]
    unsigned short* F1B   = WM + 65536;      // s_f1w·sn2w   [256][128]
    unsigned short* F2B   = WM + 98304;      // s_f2w   [128][256]
    unsigned short* WB    = WM + 131072;     // t_in_w  [384][128]
    unsigned short* WoBt  = WM + 180224;     // t_out_w [128][128]
    unsigned short* F1Bt  = WM + 196608;     // t_f1w   [256][128]
    unsigned short* F2Bt  = WM + 229376;     // t_f2w   [128][256]
    unsigned short* GWt   = WM + 262144;     // gcn_w[0]^T [128][128]

    unsigned short* XG  = (unsigned short*)R1;                    // xg bf16 [192000][128]
    unsigned short* DLT = (unsigned short*)R3;                    // delta [7680*19][128]
    unsigned short* XB  = (unsigned short*)(R3 + 37355520);       // xsp bf16 [192000][128]
    unsigned short* OB  = (unsigned short*)R2;                    // o bf16  [192000][128]

    float* out0 = (float*)d_out;
    float* next_attn = out0 + 24576000;

    k_prep<<<320, 256, 0, stream>>>(s_in_w, s_out_w, s_f1w, s_f2w,
                                    t_in_w, t_out_w, t_f1w, t_f2w, gcnw,
                                    sn1, sn2, WM);
    k_select<<<30, 256, 0, stream>>>(sc, ORD, SLOT, PH);
    k_spatial9<<<3840, 512, 0, stream>>>(x, GWt, gnw, ORD, PH, cls,
                                         WinB, s_in_b, WoutB, s_out_b,
                                         F1B, s_f1b, F2B, s_f2b,
                                         XG, DLT, next_attn);
    k_scatter3<<<24000, 256, 0, stream>>>(XG, DLT, SLOT, XB);
    k_tattn2<<<6400, 256, 0, stream>>>(XB, WB, t_in_b, OB);
    k_tblock<<<6000, 256, 0, stream>>>(OB, WoBt, t_out_b, XB,
                                       t_ln1w, t_ln1b, F1Bt, t_f1b,
                                       F2Bt, t_f2b, t_ln2w, t_ln2b,
                                       tnw, x, out0);
}

// Round 18
// 626.725 us; speedup vs baseline: 1.0614x; 1.0062x over previous
//
#include <hip/hip_runtime.h>
#include <hip/hip_bf16.h>
#include <math.h>

// Problem constants
#define NTR   7680      // N*T
#define NJ    25
#define NKEEP 17
#define NDRP  8
#define NL    19
#define NROW  192000    // NT*J == N*J*T
#define NTT   120
#define RSP   24        // padded rows per r in spatial block

typedef __attribute__((ext_vector_type(8))) short bf16x8;
typedef __attribute__((ext_vector_type(4))) float f32x4;

__device__ __forceinline__ float gelu_exact(float v){
    return 0.5f * v * (1.0f + erff(v * 0.70710678118654752440f));
}
__device__ __forceinline__ unsigned short f2bf(float v){
    union { __hip_bfloat16 h; unsigned short u; } c;
    c.h = __float2bfloat16(v);
    return c.u;
}
__device__ __forceinline__ float bf2f(unsigned short u){
    union { unsigned u; float f; } a; a.u = ((unsigned)u) << 16; return a.f;
}

// ---------------------------------------------------------------- weight prep + token selection in ONE launch
// blocks [0,320): weight cast/fold/transpose; blocks [320,350): per-row selection sort
__global__ void k_prep2(const float* __restrict__ s_in_w, const float* __restrict__ s_out_w,
                        const float* __restrict__ s_f1w,  const float* __restrict__ s_f2w,
                        const float* __restrict__ t_in_w, const float* __restrict__ t_out_w,
                        const float* __restrict__ t_f1w,  const float* __restrict__ t_f2w,
                        const float* __restrict__ gcnw,
                        const float* __restrict__ sn1w,   const float* __restrict__ sn2w,
                        unsigned short* __restrict__ WM,
                        const float* __restrict__ sc, int* __restrict__ order,
                        int* __restrict__ slot, float* __restrict__ ph)
{
    if (blockIdx.x < 320){
        int i = blockIdx.x * 256 + threadIdx.x;
        if (i < 65536){
            const float* src;
            const float* nw = nullptr;
            int base;
            if      (i < 12288){ src = s_in_w;  base = 0;     nw = sn1w; }
            else if (i < 16384){ src = s_out_w; base = 12288; }
            else if (i < 24576){ src = s_f1w;   base = 16384; nw = sn2w; }
            else if (i < 32768){ src = s_f2w;   base = 24576; }
            else if (i < 45056){ src = t_in_w;  base = 32768; }
            else if (i < 49152){ src = t_out_w; base = 45056; }
            else if (i < 57344){ src = t_f1w;   base = 49152; }
            else               { src = t_f2w;   base = 57344; }
            int loc = i - base;
            float4 v = *(const float4*)(src + loc * 4);
            if (nw){
                float4 w = *(const float4*)(nw + ((loc * 4) & 127));
                v.x *= w.x; v.y *= w.y; v.z *= w.z; v.w *= w.w;
            }
            ushort4 o; o.x = f2bf(v.x); o.y = f2bf(v.y); o.z = f2bf(v.z); o.w = f2bf(v.w);
            *(ushort4*)(WM + i * 4) = o;
        } else if (i < 81920){
            int j = i - 65536;                 // gcn transpose: 16384 elems
            int d = j >> 7, c = j & 127;
            WM[262144 + d * 128 + c] = f2bf(gcnw[c * 128 + d]);
        }
    } else {
        int r = (blockIdx.x - 320) * 256 + threadIdx.x;
        if (r >= NTR) return;
        float s[NJ]; int id[NJ];
        for (int j = 0; j < NJ; j++){ s[j] = sc[r * NJ + j]; id[j] = j; }
        for (int m = 1; m < NJ; m++){
            float sv = s[m]; int iv = id[m]; int p = m;
            while (p > 0 && s[p-1] < sv){ s[p] = s[p-1]; id[p] = id[p-1]; p--; }
            s[p] = sv; id[p] = iv;
        }
        for (int j = 0; j < NJ; j++) order[r * NJ + j] = id[j];
        for (int i = 0; i < NKEEP; i++)  slot[r * NJ + id[i]] = 1 + i;
        for (int i = NKEEP; i < NJ; i++) slot[r * NJ + id[i]] = 18;
        float m8 = s[NKEEP];
        float e[NDRP]; float sum = 0.f;
        for (int i = 0; i < NDRP; i++){ e[i] = expf(s[NKEEP + i] - m8); sum += e[i]; }
        float inv = 1.f / sum;
        for (int i = 0; i < NDRP; i++) ph[r * NDRP + i] = e[i] * inv;
    }
}

// ---------------------------------------------------------------- spatial transformer v9: fused GCN phase-0
// sm u16 layout: xs[48][136] | U1: xstage[64][136]/Pb[8][32][40] | U3: xgl[50][136]/qk[48][264] |
//                U2: vT[8][32][40] / ao[48][136]
__global__ __launch_bounds__(512, 4) void k_spatial9(
    const float* __restrict__ x, const unsigned short* __restrict__ GWt, const float* __restrict__ gnw,
    const int* __restrict__ order, const float* __restrict__ ph,
    const float* __restrict__ cls_tok,
    const unsigned short* __restrict__ WinB, const float* __restrict__ inb,
    const unsigned short* __restrict__ WoutB, const float* __restrict__ outb,
    const unsigned short* __restrict__ F1B, const float* __restrict__ f1b,
    const unsigned short* __restrict__ F2B, const float* __restrict__ f2b,
    unsigned short* __restrict__ xg_out,
    unsigned short* __restrict__ delta, float* __restrict__ next_attn)
{
    __shared__ __align__(16) unsigned short sm[39680];
    __shared__ float rstd[48];
    __shared__ float ss2[48];
    __shared__ float clsp[8][20];      // attention cls-probs; ALSO gss[64] scratch in phase-0
    __shared__ int   ord_s[2][NJ];
    __shared__ float ph_s[2][NDRP];
    unsigned short* xs     = sm;             // [48][136] x_slow -> x_msa
    unsigned short* xstage = sm + 6528;      // [64][136] phase-0 staging (overlays Pb)
    unsigned short* Pb     = sm + 6528;      // [8][32][40]
    unsigned short* xgl    = sm + 16768;     // [50][136] gcn output (overlays qk)
    unsigned short* qk     = sm + 16768;     // [48][264]
    unsigned short* vT     = sm + 29440;     // [8][32][40]
    unsigned short* ao     = sm + 29440;     // [48][136] overlays vT
    float* gss = &clsp[0][0];                // [64] gcn rms scratch

    int tid = threadIdx.x;
    int r0 = blockIdx.x * 2;
    int wv = tid >> 6, lane = tid & 63, cl = lane & 15, g = lane >> 4;
    const float scale = 0.17677669529663687f;

    if (tid < 2*NJ)   ord_s[tid/NJ][tid%NJ] = order[(r0 + tid/NJ)*NJ + tid%NJ];
    if (tid < 2*NDRP) ph_s[tid>>3][tid&7]   = ph[(r0 + (tid>>3))*NDRP + (tid&7)];
    if (tid < 48) ss2[tid] = 0.f;
    if (tid < 64) gss[tid] = 0.f;
    for (int i = tid; i < 1280; i += 512)
        *(uint4*)(vT + i*8) = make_uint4(0,0,0,0);   // zero U2 (pad keys must be 0)

    // ---- phase 0a: stage x (f32 -> bf16) rows 0..49, zero pad rows 50..63 ----
    {
        const float* xr = x + (size_t)r0 * NJ * 128;
        for (int i = tid; i < 2048; i += 512){
            int row = i >> 5, ch = i & 31;
            ushort4 u;
            if (row < 50){
                float4 v = *(const float4*)(xr + row*128 + ch*4);
                u.x = f2bf(v.x); u.y = f2bf(v.y); u.z = f2bf(v.z); u.w = f2bf(v.w);
            } else { u.x = 0; u.y = 0; u.z = 0; u.w = 0; }
            *(ushort4*)(xstage + row*136 + ch*4) = u;
        }
    }
    __syncthreads();   // ord_s/ph_s/gss/xstage visible

    // ---- phase 0b: GCN GEMM (B resident, col-tile = wv) + fused RMS stats ----
    f32x4 gacc[4];
    {
        int col = wv*16 + cl;
        bf16x8 Bg[4];
        #pragma unroll
        for (int ks = 0; ks < 4; ks++)
            Bg[ks] = *(const bf16x8*)(GWt + col*128 + ks*32 + g*8);
        #pragma unroll
        for (int rt = 0; rt < 4; rt++){
            bf16x8 A[4];
            #pragma unroll
            for (int ks = 0; ks < 4; ks++)
                A[ks] = *(const bf16x8*)(xstage + (rt*16 + cl)*136 + ks*32 + g*8);
            f32x4 acc = {0,0,0,0};
            #pragma unroll
            for (int ks = 0; ks < 4; ks++)
                acc = __builtin_amdgcn_mfma_f32_16x16x32_bf16(A[ks], Bg[ks], acc, 0, 0, 0);
            gacc[rt] = acc;
            #pragma unroll
            for (int reg = 0; reg < 4; reg++){
                int row = rt*16 + g*4 + reg;
                float p = acc[reg] * acc[reg];
                p += __shfl_xor(p, 1, 64); p += __shfl_xor(p, 2, 64);
                p += __shfl_xor(p, 4, 64); p += __shfl_xor(p, 8, 64);
                if (cl == 0) atomicAdd(&gss[row], p);
            }
        }
    }
    __syncthreads();
    if (tid < 64) gss[tid] = rsqrtf(gss[tid] * 0.0078125f + 1e-6f);
    __syncthreads();
    // ---- phase 0c: apply gnw * rstd -> xgl (LDS) ----
    {
        int col = wv*16 + cl;
        float gw = gnw[col];
        #pragma unroll
        for (int rt = 0; rt < 4; rt++){
            #pragma unroll
            for (int reg = 0; reg < 4; reg++){
                int row = rt*16 + g*4 + reg;
                if (row < 50)
                    xgl[row*136 + col] = f2bf(gacc[rt][reg] * gss[row] * gw);
            }
        }
    }
    __syncthreads();   // xgl complete

    // ---- phase 0d: vectorized copy xgl -> global XG (for k_scatter3) ----
    {
        unsigned short* dst = xg_out + (size_t)r0 * NJ * 128;
        for (int i = tid; i < 1600; i += 512){   // 50 rows x 32 quads
            int row = i >> 5, ch = i & 31;
            *(ushort4*)(dst + row*128 + ch*4) = *(const ushort4*)(xgl + row*136 + ch*4);
        }
    }

    // ---- build x_slow (gather from LDS xgl) + fused rmsnorm1 stats (32 lanes per row) ----
    {
        int ln = tid & 31;
        for (int j = tid >> 5; j < 48; j += 16){
            int rr = j / RSP, t = j - rr * RSP;
            const unsigned short* xgr = xgl + rr * NJ * 136;
            float v0, v1, v2, v3;
            if (t == 0){
                float4 cv = *(const float4*)(cls_tok + ln*4);
                v0 = cv.x; v1 = cv.y; v2 = cv.z; v3 = cv.w;
            } else if (t <= NKEEP){
                ushort4 u = *(const ushort4*)(xgr + ord_s[rr][t-1]*136 + ln*4);
                v0 = bf2f(u.x); v1 = bf2f(u.y); v2 = bf2f(u.z); v3 = bf2f(u.w);
            } else if (t == 18){
                v0 = v1 = v2 = v3 = 0.f;
                for (int i = 0; i < NDRP; i++){
                    ushort4 u = *(const ushort4*)(xgr + ord_s[rr][NKEEP+i]*136 + ln*4);
                    float w = ph_s[rr][i];
                    v0 = fmaf(bf2f(u.x),w,v0); v1 = fmaf(bf2f(u.y),w,v1);
                    v2 = fmaf(bf2f(u.z),w,v2); v3 = fmaf(bf2f(u.w),w,v3);
                }
            } else { v0 = v1 = v2 = v3 = 0.f; }
            ushort4 o4; o4.x=f2bf(v0); o4.y=f2bf(v1); o4.z=f2bf(v2); o4.w=f2bf(v3);
            *(ushort4*)(xs + j*136 + ln*4) = o4;
            float p = v0*v0 + v1*v1 + v2*v2 + v3*v3;
            p += __shfl_xor(p, 1, 64); p += __shfl_xor(p, 2, 64);
            p += __shfl_xor(p, 4, 64); p += __shfl_xor(p, 8, 64);
            p += __shfl_xor(p, 16, 64);
            if (ln == 0) rstd[j] = rsqrtf(p * 0.0078125f + 1e-6f);
        }
    }
    __syncthreads();   // xgl dead; qkv may overwrite qk region

    // ---- qkv GEMM on RAW xs (sn1w folded into WinB); epilogue scales by rstd[row] ----
    {
        int col = wv*16 + cl;
        bf16x8 Bq[4], Bk[4], Bv[4];
        #pragma unroll
        for (int ks = 0; ks < 4; ks++){
            Bq[ks] = *(const bf16x8*)(WinB + col*128        + ks*32 + g*8);
            Bk[ks] = *(const bf16x8*)(WinB + (128+col)*128  + ks*32 + g*8);
            Bv[ks] = *(const bf16x8*)(WinB + (256+col)*128  + ks*32 + g*8);
        }
        float bq = inb[col], bk = inb[128+col], bv = inb[256+col];
        int h = col >> 5, d = col & 31;
        #pragma unroll
        for (int rt = 0; rt < 3; rt++){
            bf16x8 A[4];
            #pragma unroll
            for (int ks = 0; ks < 4; ks++)
                A[ks] = *(const bf16x8*)(xs + (rt*16 + cl)*136 + ks*32 + g*8);
            f32x4 aq = {0,0,0,0}, ak = {0,0,0,0}, av = {0,0,0,0};
            #pragma unroll
            for (int ks = 0; ks < 4; ks++){
                aq = __builtin_amdgcn_mfma_f32_16x16x32_bf16(A[ks], Bq[ks], aq, 0, 0, 0);
                ak = __builtin_amdgcn_mfma_f32_16x16x32_bf16(A[ks], Bk[ks], ak, 0, 0, 0);
                av = __builtin_amdgcn_mfma_f32_16x16x32_bf16(A[ks], Bv[ks], av, 0, 0, 0);
            }
            #pragma unroll
            for (int reg = 0; reg < 4; reg++){
                int row = rt*16 + g*4 + reg;
                float rs = rstd[row];
                qk[row*264 + col]       = f2bf((aq[reg]*rs + bq) * scale);
                qk[row*264 + 128 + col] = f2bf(ak[reg]*rs + bk);
                int rr = row >= RSP; int key = row - rr*RSP;
                vT[(rr*4 + h)*1280 + d*40 + key] = f2bf(av[reg]*rs + bv);
            }
        }
    }
    __syncthreads();

    // ---- attention: 1 (rr,h) pair per wave; P region is per-wave -> NO mid barrier ----
    {
        int qh = wv;
        int rr = qh >> 2, h = qh & 3;
        bf16x8 aq[2];
        #pragma unroll
        for (int qt = 0; qt < 2; qt++)
            aq[qt] = *(const bf16x8*)(qk + (rr*RSP + qt*16 + cl)*264 + h*32 + g*8);
        f32x4 lg[2][2];
        #pragma unroll
        for (int kt = 0; kt < 2; kt++){
            bf16x8 bk = *(const bf16x8*)(qk + (rr*RSP + kt*16 + cl)*264 + 128 + h*32 + g*8);
            f32x4 z = {0.f, 0.f, 0.f, 0.f};
            lg[0][kt] = __builtin_amdgcn_mfma_f32_16x16x32_bf16(aq[0], bk, z, 0, 0, 0);
            lg[1][kt] = __builtin_amdgcn_mfma_f32_16x16x32_bf16(aq[1], bk, z, 0, 0, 0);
        }
        #pragma unroll
        for (int qt = 0; qt < 2; qt++){
            #pragma unroll
            for (int reg = 0; reg < 4; reg++){
                float l0 = lg[qt][0][reg];
                float l1 = (cl >= 3) ? -1e30f : lg[qt][1][reg];
                float m = fmaxf(l0, l1);
                m = fmaxf(m, __shfl_xor(m, 1, 64));
                m = fmaxf(m, __shfl_xor(m, 2, 64));
                m = fmaxf(m, __shfl_xor(m, 4, 64));
                m = fmaxf(m, __shfl_xor(m, 8, 64));
                float e0 = __expf(l0 - m), e1 = __expf(l1 - m);
                float ssum = e0 + e1;
                ssum += __shfl_xor(ssum, 1, 64); ssum += __shfl_xor(ssum, 2, 64);
                ssum += __shfl_xor(ssum, 4, 64); ssum += __shfl_xor(ssum, 8, 64);
                float inv = 1.f / ssum;
                e0 *= inv; e1 *= inv;
                int q = qt*16 + g*4 + reg;
                Pb[qh*1280 + q*40 + cl]      = f2bf(e0);
                Pb[qh*1280 + q*40 + 16 + cl] = f2bf(e1);
                if (qt == 0 && g == 0 && reg == 0){
                    clsp[qh][cl] = e0;
                    if (cl < 4) clsp[qh][16 + cl] = e1;
                }
            }
        }
        // no barrier: Pb[qh] and vT[qh] consumed only by this wave; PV writes only
        // the qk columns (h*32..) that this wave alone read as Q.
        bf16x8 ap[2];
        #pragma unroll
        for (int qt = 0; qt < 2; qt++)
            ap[qt] = *(const bf16x8*)(Pb + qh*1280 + (qt*16 + cl)*40 + g*8);
        #pragma unroll
        for (int dt = 0; dt < 2; dt++){
            bf16x8 bv = *(const bf16x8*)(vT + qh*1280 + (dt*16 + cl)*40 + g*8);
            #pragma unroll
            for (int qt = 0; qt < 2; qt++){
                f32x4 z = {0.f, 0.f, 0.f, 0.f};
                f32x4 oa = __builtin_amdgcn_mfma_f32_16x16x32_bf16(ap[qt], bv, z, 0, 0, 0);
                #pragma unroll
                for (int reg = 0; reg < 4; reg++){
                    int q = qt*16 + g*4 + reg;
                    if (q < 19)
                        qk[(rr*RSP + q)*264 + h*32 + dt*16 + cl] = f2bf(oa[reg]);
                    else if (q < RSP)
                        qk[(rr*RSP + q)*264 + h*32 + dt*16 + cl] = 0;
                }
            }
        }
        __syncthreads();
    }

    // ---- next_attn ----
    if (tid < 36){
        int rr2 = tid / 18, t = tid - rr2*18;
        float v = 0.25f * (clsp[rr2*4+0][1+t] + clsp[rr2*4+1][1+t] +
                           clsp[rr2*4+2][1+t] + clsp[rr2*4+3][1+t]);
        int r = r0 + rr2;
        if (t < NKEEP) next_attn[r*NJ + ord_s[rr2][t]] = v;
        else { for (int i = 0; i < NDRP; i++) next_attn[r*NJ + ord_s[rr2][NKEEP+i]] = v; }
    }

    // ---- out-proj: B resident; fused rmsnorm2 stats on x_msa ----
    {
        int col = wv*16 + cl;
        bf16x8 B[4];
        #pragma unroll
        for (int ks = 0; ks < 4; ks++)
            B[ks] = *(const bf16x8*)(WoutB + col*128 + ks*32 + g*8);
        float bias = outb[col];
        #pragma unroll
        for (int rt = 0; rt < 3; rt++){
            bf16x8 A[4];
            #pragma unroll
            for (int ks = 0; ks < 4; ks++)
                A[ks] = *(const bf16x8*)(qk + (rt*16 + cl)*264 + ks*32 + g*8);
            f32x4 acc = {0,0,0,0};
            #pragma unroll
            for (int ks = 0; ks < 4; ks++)
                acc = __builtin_amdgcn_mfma_f32_16x16x32_bf16(A[ks], B[ks], acc, 0, 0, 0);
            #pragma unroll
            for (int reg = 0; reg < 4; reg++){
                int row = rt*16 + g*4 + reg;
                float v = acc[reg] + bias;
                float msa = bf2f(xs[row*136 + col]) + v;
                ao[row*136 + col] = f2bf(v);
                xs[row*136 + col] = f2bf(msa);
                float p = msa * msa;
                p += __shfl_xor(p, 1, 64); p += __shfl_xor(p, 2, 64);
                p += __shfl_xor(p, 4, 64); p += __shfl_xor(p, 8, 64);
                if (cl == 0) atomicAdd(&ss2[row], p);
            }
        }
    }
    __syncthreads();

    if (tid < 48) rstd[tid] = rsqrtf(ss2[tid] * 0.0078125f + 1e-6f);
    __syncthreads();

    // ---- ffn1 + gelu on RAW x_msa (sn2w folded into F1B); epilogue scales by rstd[row] ----
    {
        int c0 = wv*16 + cl, c1 = c0 + 128;
        bf16x8 B0[4], B1[4];
        #pragma unroll
        for (int ks = 0; ks < 4; ks++){
            B0[ks] = *(const bf16x8*)(F1B + c0*128 + ks*32 + g*8);
            B1[ks] = *(const bf16x8*)(F1B + c1*128 + ks*32 + g*8);
        }
        float b0 = f1b[c0], b1 = f1b[c1];
        #pragma unroll
        for (int rt = 0; rt < 3; rt++){
            bf16x8 A[4];
            #pragma unroll
            for (int ks = 0; ks < 4; ks++)
                A[ks] = *(const bf16x8*)(xs + (rt*16 + cl)*136 + ks*32 + g*8);
            f32x4 a0 = {0,0,0,0}, a1 = {0,0,0,0};
            #pragma unroll
            for (int ks = 0; ks < 4; ks++){
                a0 = __builtin_amdgcn_mfma_f32_16x16x32_bf16(A[ks], B0[ks], a0, 0, 0, 0);
                a1 = __builtin_amdgcn_mfma_f32_16x16x32_bf16(A[ks], B1[ks], a1, 0, 0, 0);
            }
            #pragma unroll
            for (int reg = 0; reg < 4; reg++){
                int row = rt*16 + g*4 + reg;
                float rs = rstd[row];
                qk[row*264 + c0] = f2bf(gelu_exact(a0[reg]*rs + b0));
                qk[row*264 + c1] = f2bf(gelu_exact(a1[reg]*rs + b1));
            }
        }
    }
    __syncthreads();

    // ---- ffn2 + delta: B resident (8 k-slices) ----
    {
        int col = wv*16 + cl;
        bf16x8 B[8];
        #pragma unroll
        for (int ks = 0; ks < 8; ks++)
            B[ks] = *(const bf16x8*)(F2B + col*256 + ks*32 + g*8);
        float bias = f2b[col];
        #pragma unroll
        for (int rt = 0; rt < 3; rt++){
            bf16x8 A[8];
            #pragma unroll
            for (int ks = 0; ks < 8; ks++)
                A[ks] = *(const bf16x8*)(qk + (rt*16 + cl)*264 + ks*32 + g*8);
            f32x4 acc = {0,0,0,0};
            #pragma unroll
            for (int ks = 0; ks < 8; ks++)
                acc = __builtin_amdgcn_mfma_f32_16x16x32_bf16(A[ks], B[ks], acc, 0, 0, 0);
            #pragma unroll
            for (int reg = 0; reg < 4; reg++){
                int row = rt*16 + g*4 + reg;
                int rr = row >= RSP; int tok = row - rr*RSP;
                if (tok < 19){
                    float dv = acc[reg] + bias + bf2f(ao[row*136 + col]);
                    delta[((size_t)(r0 + rr)*19 + tok)*128 + col] = f2bf(dv);
                }
            }
        }
    }
}

// ---------------------------------------------------------------- scatter: 2 quads/thread (same row)
__global__ void k_scatter3(const unsigned short* __restrict__ xg, const unsigned short* __restrict__ delta,
                           const int* __restrict__ slot, unsigned short* __restrict__ xb){
    int i = blockIdx.x * 256 + threadIdx.x;   // 3,072,000 threads x 8 elems
    int e = i * 8;
    int c = e & 127; int rem = e >> 7;
    int t = rem % NTT; int nj = rem / NTT; int j = nj % NJ; int n = nj / NJ;
    int r = n * NTT + t;
    int sl = slot[r * NJ + j];
    const unsigned short* xp = xg + ((size_t)r * NJ + j) * 128 + c;
    const unsigned short* dp = delta + ((size_t)r * 19 + sl) * 128 + c;
    unsigned short* op = xb + e;
    #pragma unroll
    for (int q = 0; q < 2; q++){
        ushort4 xv = *(const ushort4*)(xp + q*4);
        ushort4 dv = *(const ushort4*)(dp + q*4);
        ushort4 ob;
        ob.x = f2bf(2.f * bf2f(xv.x) + bf2f(dv.x));
        ob.y = f2bf(2.f * bf2f(xv.y) + bf2f(dv.y));
        ob.z = f2bf(2.f * bf2f(xv.z) + bf2f(dv.z));
        ob.w = f2bf(2.f * bf2f(xv.w) + bf2f(dv.w));
        *(ushort4*)(op + q*4) = ob;
    }
}

// ---------------------------------------------------------------- temporal attention: 4 waves per (nj, head), bf16 out
// P region is per-wave -> NO barriers in the attention loop (waves drift freely)
__global__ __launch_bounds__(256, 3) void k_tattn2(
    const unsigned short* __restrict__ xb, const unsigned short* __restrict__ Wb,
    const float* __restrict__ inb, unsigned short* __restrict__ o)
{
    // LDS u16: q[120][40] | k[120][40] | vT[32][136] | P[4][16][136] = 45,312 B
    __shared__ __align__(16) unsigned short smem[22656];
    unsigned short* q_s = smem;
    unsigned short* k_s = smem + 4800;
    unsigned short* vT  = smem + 9600;
    unsigned short* P_s = smem + 13952;

    int tid = threadIdx.x;
    int l = tid & 63, cl = l & 15, g = l >> 4, wv = tid >> 6;
    int nj = blockIdx.x >> 2;
    int h  = blockIdx.x & 3;

    vT[(tid >> 3) * 136 + 120 + (tid & 7)] = 0;   // zero pad key cols

    const unsigned short* xrow = xb + (size_t)nj * (NTT * 128);
    const float scale = 0.17677669529663687f;

    bf16x8 bfr[6][4];
    float bias[6];
    #pragma unroll
    for (int pc = 0; pc < 6; ++pc){
        int p = pc >> 1, s = pc & 1;
        int col = p * 128 + h * 32 + s * 16 + cl;
        bias[pc] = inb[col];
        #pragma unroll
        for (int ks = 0; ks < 4; ++ks)
            bfr[pc][ks] = *(const bf16x8*)(Wb + col * 128 + ks * 32 + g * 8);
    }

    for (int mt = wv; mt < 8; mt += 4){
        bf16x8 af[4];
        #pragma unroll
        for (int ks = 0; ks < 4; ++ks)
            af[ks] = *(const bf16x8*)(xrow + (mt * 16 + cl) * 128 + ks * 32 + g * 8);
        #pragma unroll
        for (int pc = 0; pc < 6; ++pc){
            f32x4 acc = {0.f, 0.f, 0.f, 0.f};
            #pragma unroll
            for (int ks = 0; ks < 4; ++ks)
                acc = __builtin_amdgcn_mfma_f32_16x16x32_bf16(af[ks], bfr[pc][ks], acc, 0, 0, 0);
            int p = pc >> 1, s = pc & 1;
            int d = s * 16 + cl;
            #pragma unroll
            for (int reg = 0; reg < 4; ++reg){
                int t = mt * 16 + g * 4 + reg;
                if (t < NTT){
                    float v = acc[reg] + bias[pc];
                    if (p == 0)      q_s[t * 40 + d] = f2bf(v * scale);
                    else if (p == 1) k_s[t * 40 + d] = f2bf(v);
                    else             vT[d * 136 + t] = f2bf(v);
                }
            }
        }
    }
    __syncthreads();   // q/k/vT stable from here; below only per-wave P region is touched

    for (int s = 0; s < 2; ++s){
        int mt = wv + s * 4;
        bf16x8 aq = *(const bf16x8*)(q_s + (mt * 16 + cl) * 40 + g * 8);
        f32x4 lg[8];
        #pragma unroll
        for (int jt = 0; jt < 8; ++jt){
            bf16x8 bk = *(const bf16x8*)(k_s + (jt * 16 + cl) * 40 + g * 8);
            f32x4 z = {0.f, 0.f, 0.f, 0.f};
            lg[jt] = __builtin_amdgcn_mfma_f32_16x16x32_bf16(aq, bk, z, 0, 0, 0);
        }
        if (cl >= 8){ lg[7][0] = -1e30f; lg[7][1] = -1e30f; lg[7][2] = -1e30f; lg[7][3] = -1e30f; }

        float inv[4];
        #pragma unroll
        for (int reg = 0; reg < 4; ++reg){
            float m = lg[0][reg];
            #pragma unroll
            for (int jt = 1; jt < 8; ++jt) m = fmaxf(m, lg[jt][reg]);
            m = fmaxf(m, __shfl_xor(m, 1, 64));
            m = fmaxf(m, __shfl_xor(m, 2, 64));
            m = fmaxf(m, __shfl_xor(m, 4, 64));
            m = fmaxf(m, __shfl_xor(m, 8, 64));
            float sum = 0.f;
            #pragma unroll
            for (int jt = 0; jt < 8; ++jt){ float e = __expf(lg[jt][reg] - m); lg[jt][reg] = e; sum += e; }
            sum += __shfl_xor(sum, 1, 64); sum += __shfl_xor(sum, 2, 64);
            sum += __shfl_xor(sum, 4, 64); sum += __shfl_xor(sum, 8, 64);
            inv[reg] = 1.f / sum;
        }

        unsigned short* Pw = P_s + wv * 2176;   // per-wave region: no barriers needed
        #pragma unroll
        for (int jt = 0; jt < 8; ++jt){
            #pragma unroll
            for (int reg = 0; reg < 4; ++reg)
                Pw[(g * 4 + reg) * 136 + jt * 16 + cl] = f2bf(lg[jt][reg] * inv[reg]);
        }

        bf16x8 ap[4];
        #pragma unroll
        for (int ks = 0; ks < 4; ++ks)
            ap[ks] = *(const bf16x8*)(Pw + cl * 136 + ks * 32 + g * 8);
        #pragma unroll
        for (int nt = 0; nt < 2; ++nt){
            f32x4 oacc = {0.f, 0.f, 0.f, 0.f};
            #pragma unroll
            for (int ks = 0; ks < 4; ++ks){
                bf16x8 bv = *(const bf16x8*)(vT + (nt * 16 + cl) * 136 + ks * 32 + g * 8);
                oacc = __builtin_amdgcn_mfma_f32_16x16x32_bf16(ap[ks], bv, oacc, 0, 0, 0);
            }
            #pragma unroll
            for (int reg = 0; reg < 4; ++reg){
                int t = mt * 16 + g * 4 + reg;
                if (t < NTT)
                    o[((size_t)nj * NTT + t) * 128 + h * 32 + nt * 16 + cl] = f2bf(oacc[reg]);
            }
        }
    }
}

// ---------------------------------------------------------------- fused temporal MLP block
__global__ __launch_bounds__(256, 4) void k_tblock(
    const unsigned short* __restrict__ o, const unsigned short* __restrict__ WoB,
    const float* __restrict__ ob, const unsigned short* __restrict__ xbres,
    const float* __restrict__ lnw, const float* __restrict__ lnb,
    const unsigned short* __restrict__ F1B, const float* __restrict__ f1b,
    const unsigned short* __restrict__ F2B, const float* __restrict__ f2b,
    const float* __restrict__ ln2w, const float* __restrict__ ln2b,
    const float* __restrict__ tnw, const float* __restrict__ x,
    float* __restrict__ out)
{
    __shared__ __align__(16) float yf[32 * 132];            // also hb u16[32][264], then yf2
    __shared__ __align__(16) unsigned short xbuf[32 * 136];
    __shared__ int xib[32];
    int tid = threadIdx.x, wv = tid >> 6, lane = tid & 63, cl = lane & 15, g = lane >> 4;
    size_t row0 = (size_t)blockIdx.x * 32;

    if (tid < 32){
        int grow = (int)row0 + tid;
        int t = grow % NTT; int njq = grow / NTT; int j = njq % NJ; int n = njq / NJ;
        xib[tid] = ((n * NTT + t) * NJ + j) * 128;
    }

    // ---- phase 1: out-proj + residual -> yf ----
    {
        int c0 = wv*16 + cl, c1 = c0 + 64;
        bf16x8 B0[4], B1[4];
        #pragma unroll
        for (int ks = 0; ks < 4; ks++){
            B0[ks] = *(const bf16x8*)(WoB + c0*128 + ks*32 + g*8);
            B1[ks] = *(const bf16x8*)(WoB + c1*128 + ks*32 + g*8);
        }
        float b0 = ob[c0], b1 = ob[c1];
        #pragma unroll
        for (int rt = 0; rt < 2; rt++){
            bf16x8 A[4];
            #pragma unroll
            for (int ks = 0; ks < 4; ks++)
                A[ks] = *(const bf16x8*)(o + (row0 + rt*16 + cl)*128 + ks*32 + g*8);
            f32x4 a0 = {0,0,0,0}, a1 = {0,0,0,0};
            #pragma unroll
            for (int ks = 0; ks < 4; ks++){
                a0 = __builtin_amdgcn_mfma_f32_16x16x32_bf16(A[ks], B0[ks], a0, 0, 0, 0);
                a1 = __builtin_amdgcn_mfma_f32_16x16x32_bf16(A[ks], B1[ks], a1, 0, 0, 0);
            }
            #pragma unroll
            for (int reg = 0; reg < 4; reg++){
                int row = rt*16 + g*4 + reg;
                yf[row*132 + c0] = a0[reg] + b0 + bf2f(xbres[(row0 + row)*128 + c0]);
                yf[row*132 + c1] = a1[reg] + b1 + bf2f(xbres[(row0 + row)*128 + c1]);
            }
        }
    }
    __syncthreads();

    // ---- phase 2: LN1 stats + apply (8 lanes/row) -> xbuf ----
    {
        int row = tid >> 3, sub = tid & 7;
        float4 v[4];
        float s1 = 0.f, s2 = 0.f;
        #pragma unroll
        for (int k = 0; k < 4; k++){
            v[k] = *(const float4*)(yf + row*132 + sub*16 + k*4);
            s1 += v[k].x + v[k].y + v[k].z + v[k].w;
            s2 += v[k].x*v[k].x + v[k].y*v[k].y + v[k].z*v[k].z + v[k].w*v[k].w;
        }
        s1 += __shfl_xor(s1, 1, 64); s2 += __shfl_xor(s2, 1, 64);
        s1 += __shfl_xor(s1, 2, 64); s2 += __shfl_xor(s2, 2, 64);
        s1 += __shfl_xor(s1, 4, 64); s2 += __shfl_xor(s2, 4, 64);
        float m = s1 * 0.0078125f;
        float rv = rsqrtf(s2 * 0.0078125f - m*m + 1e-5f);
        #pragma unroll
        for (int k = 0; k < 4; k++){
            float4 w4 = *(const float4*)(lnw + sub*16 + k*4);
            float4 b4 = *(const float4*)(lnb + sub*16 + k*4);
            ushort4 u;
            u.x = f2bf((v[k].x - m) * rv * w4.x + b4.x);
            u.y = f2bf((v[k].y - m) * rv * w4.y + b4.y);
            u.z = f2bf((v[k].z - m) * rv * w4.z + b4.z);
            u.w = f2bf((v[k].w - m) * rv * w4.w + b4.w);
            *(ushort4*)(xbuf + row*136 + sub*16 + k*4) = u;
        }
    }
    __syncthreads();

    // ---- phase 3: FFN1 + gelu -> hb (overlays yf) ----
    unsigned short* hb = (unsigned short*)yf;   // [32][264]
    #pragma unroll
    for (int s = 0; s < 4; s++){
        int c = wv*16 + cl + s*64;
        bf16x8 B[4];
        #pragma unroll
        for (int ks = 0; ks < 4; ks++)
            B[ks] = *(const bf16x8*)(F1B + c*128 + ks*32 + g*8);
        float bias = f1b[c];
        #pragma unroll
        for (int rt = 0; rt < 2; rt++){
            bf16x8 A[4];
            #pragma unroll
            for (int ks = 0; ks < 4; ks++)
                A[ks] = *(const bf16x8*)(xbuf + (rt*16 + cl)*136 + ks*32 + g*8);
            f32x4 acc = {0,0,0,0};
            #pragma unroll
            for (int ks = 0; ks < 4; ks++)
                acc = __builtin_amdgcn_mfma_f32_16x16x32_bf16(A[ks], B[ks], acc, 0, 0, 0);
            #pragma unroll
            for (int reg = 0; reg < 4; reg++){
                int row = rt*16 + g*4 + reg;
                hb[row*264 + c] = f2bf(gelu_exact(acc[reg] + bias));
            }
        }
    }
    __syncthreads();

    // ---- phase 4: FFN2 into registers, then overlay-write yf2 ----
    float ys[2][2][4];
    #pragma unroll
    for (int s = 0; s < 2; s++){
        int c = wv*16 + cl + s*64;
        bf16x8 B[8];
        #pragma unroll
        for (int ks = 0; ks < 8; ks++)
            B[ks] = *(const bf16x8*)(F2B + c*256 + ks*32 + g*8);
        float bias = f2b[c];
        #pragma unroll
        for (int rt = 0; rt < 2; rt++){
            bf16x8 A[8];
            #pragma unroll
            for (int ks = 0; ks < 8; ks++)
                A[ks] = *(const bf16x8*)(hb + (rt*16 + cl)*264 + ks*32 + g*8);
            f32x4 acc = {0,0,0,0};
            #pragma unroll
            for (int ks = 0; ks < 8; ks++)
                acc = __builtin_amdgcn_mfma_f32_16x16x32_bf16(A[ks], B[ks], acc, 0, 0, 0);
            #pragma unroll
            for (int reg = 0; reg < 4; reg++){
                int row = rt*16 + g*4 + reg;
                ys[s][rt][reg] = acc[reg] + bias + bf2f(xbuf[row*136 + c]);
            }
        }
    }
    __syncthreads();
    #pragma unroll
    for (int s = 0; s < 2; s++){
        int c = wv*16 + cl + s*64;
        #pragma unroll
        for (int rt = 0; rt < 2; rt++)
            #pragma unroll
            for (int reg = 0; reg < 4; reg++)
                yf[(rt*16 + g*4 + reg)*132 + c] = ys[s][rt][reg];
    }
    __syncthreads();

    // ---- phase 5: LN2 + RMSNorm + residuals + final write ----
    {
        int row = tid >> 3, sub = tid & 7;
        float4 v[4];
        float s1 = 0.f, s2 = 0.f;
        #pragma unroll
        for (int k = 0; k < 4; k++){
            v[k] = *(const float4*)(yf + row*132 + sub*16 + k*4);
            s1 += v[k].x + v[k].y + v[k].z + v[k].w;
            s2 += v[k].x*v[k].x + v[k].y*v[k].y + v[k].z*v[k].z + v[k].w*v[k].w;
        }
        s1 += __shfl_xor(s1, 1, 64); s2 += __shfl_xor(s2, 1, 64);
        s1 += __shfl_xor(s1, 2, 64); s2 += __shfl_xor(s2, 2, 64);
        s1 += __shfl_xor(s1, 4, 64); s2 += __shfl_xor(s2, 4, 64);
        float m = s1 * 0.0078125f;
        float rv = rsqrtf(s2 * 0.0078125f - m*m + 1e-5f);
        float z[4][4];
        float s3 = 0.f;
        #pragma unroll
        for (int k = 0; k < 4; k++){
            float4 w4 = *(const float4*)(ln2w + sub*16 + k*4);
            float4 b4 = *(const float4*)(ln2b + sub*16 + k*4);
            z[k][0] = (v[k].x - m) * rv * w4.x + b4.x;
            z[k][1] = (v[k].y - m) * rv * w4.y + b4.y;
            z[k][2] = (v[k].z - m) * rv * w4.z + b4.z;
            z[k][3] = (v[k].w - m) * rv * w4.w + b4.w;
            s3 += z[k][0]*z[k][0] + z[k][1]*z[k][1] + z[k][2]*z[k][2] + z[k][3]*z[k][3];
        }
        s3 += __shfl_xor(s3, 1, 64); s3 += __shfl_xor(s3, 2, 64); s3 += __shfl_xor(s3, 4, 64);
        float sr = rsqrtf(s3 * 0.0078125f + 1e-6f);
        int xb0 = xib[row] + sub*16;
        #pragma unroll
        for (int k = 0; k < 4; k++){
            float4 tw4 = *(const float4*)(tnw + sub*16 + k*4);
            ushort4 xr = *(const ushort4*)(xbres + (row0 + row)*128 + sub*16 + k*4);
            float4 xv = *(const float4*)(x + xb0 + k*4);
            float4 ov;
            ov.x = z[k][0] * sr * tw4.x + bf2f(xr.x) + xv.x;
            ov.y = z[k][1] * sr * tw4.y + bf2f(xr.y) + xv.y;
            ov.z = z[k][2] * sr * tw4.z + bf2f(xr.z) + xv.z;
            ov.w = z[k][3] * sr * tw4.w + bf2f(xr.w) + xv.w;
            *(float4*)(out + xb0 + k*4) = ov;
        }
    }
}

// ================================================================ launch
extern "C" void kernel_launch(void* const* d_in, const int* in_sizes, int n_in,
                              void* d_out, int out_size, void* d_ws, size_t ws_size,
                              hipStream_t stream) {
    (void)in_sizes; (void)n_in; (void)out_size;
    const float* x      = (const float*)d_in[0];
    const float* sc     = (const float*)d_in[1];
    const float* gcnw   = (const float*)d_in[2];
    const float* gnw    = (const float*)d_in[3];
    const float* cls    = (const float*)d_in[4];
    const float* sn1    = (const float*)d_in[5];
    const float* sn2    = (const float*)d_in[6];
    const float* s_in_w = (const float*)d_in[7];
    const float* s_in_b = (const float*)d_in[8];
    const float* s_out_w= (const float*)d_in[9];
    const float* s_out_b= (const float*)d_in[10];
    const float* s_f1w  = (const float*)d_in[11];
    const float* s_f1b  = (const float*)d_in[12];
    const float* s_f2w  = (const float*)d_in[13];
    const float* s_f2b  = (const float*)d_in[14];
    const float* t_in_w = (const float*)d_in[15];
    const float* t_in_b = (const float*)d_in[16];
    const float* t_out_w= (const float*)d_in[17];
    const float* t_out_b= (const float*)d_in[18];
    const float* t_ln1w = (const float*)d_in[19];
    const float* t_ln1b = (const float*)d_in[20];
    const float* t_ln2w = (const float*)d_in[21];
    const float* t_ln2b = (const float*)d_in[22];
    const float* t_f1w  = (const float*)d_in[23];
    const float* t_f1b  = (const float*)d_in[24];
    const float* t_f2w  = (const float*)d_in[25];
    const float* t_f2b  = (const float*)d_in[26];
    const float* tnw    = (const float*)d_in[27];

    char* ws = (char*)d_ws;
    const size_t SZ_BIG = 98304000;                 // 192000*128*4
    char*  R1 = ws;                                 // xg (bf16)
    char*  R2 = ws + SZ_BIG;                        // o (bf16)
    char*  R3 = ws + 2 * SZ_BIG;                    // delta (bf16) | xb (bf16)
    char* p = ws + 3 * SZ_BIG;
    int*   ORD  = (int*)p;   p += 768000;
    int*   SLOT = (int*)p;   p += 768000;
    float* PH   = (float*)p; p += 245760;
    unsigned short* WM = (unsigned short*)p; p += 557056;
    if (ws_size < (size_t)(p - ws)) return;

    unsigned short* WinB  = WM;              // s_in_w·sn1w  [384][128]
    unsigned short* WoutB = WM + 49152;      // s_out_w [128][128]
    unsigned short* F1B   = WM + 65536;      // s_f1w·sn2w   [256][128]
    unsigned short* F2B   = WM + 98304;      // s_f2w   [128][256]
    unsigned short* WB    = WM + 131072;     // t_in_w  [384][128]
    unsigned short* WoBt  = WM + 180224;     // t_out_w [128][128]
    unsigned short* F1Bt  = WM + 196608;     // t_f1w   [256][128]
    unsigned short* F2Bt  = WM + 229376;     // t_f2w   [128][256]
    unsigned short* GWt   = WM + 262144;     // gcn_w[0]^T [128][128]

    unsigned short* XG  = (unsigned short*)R1;                    // xg bf16 [192000][128]
    unsigned short* DLT = (unsigned short*)R3;                    // delta [7680*19][128]
    unsigned short* XB  = (unsigned short*)(R3 + 37355520);       // xsp bf16 [192000][128]
    unsigned short* OB  = (unsigned short*)R2;                    // o bf16  [192000][128]

    float* out0 = (float*)d_out;
    float* next_attn = out0 + 24576000;

    k_prep2<<<350, 256, 0, stream>>>(s_in_w, s_out_w, s_f1w, s_f2w,
                                     t_in_w, t_out_w, t_f1w, t_f2w, gcnw,
                                     sn1, sn2, WM, sc, ORD, SLOT, PH);
    k_spatial9<<<3840, 512, 0, stream>>>(x, GWt, gnw, ORD, PH, cls,
                                         WinB, s_in_b, WoutB, s_out_b,
                                         F1B, s_f1b, F2B, s_f2b,
                                         XG, DLT, next_attn);
    k_scatter3<<<12000, 256, 0, stream>>>(XG, DLT, SLOT, XB);
    k_tattn2<<<6400, 256, 0, stream>>>(XB, WB, t_in_b, OB);
    k_tblock<<<6000, 256, 0, stream>>>(OB, WoBt, t_out_b, XB,
                                       t_ln1w, t_ln1b, F1Bt, t_f1b,
                                       F2Bt, t_f2b, t_ln2w, t_ln2b,
                                       tnw, x, out0);
}

// Round 19
// 626.445 us; speedup vs baseline: 1.0619x; 1.0004x over previous
//
#include <hip/hip_runtime.h>
#include <hip/hip_bf16.h>
#include <math.h>

// Problem constants
#define NTR   7680      // N*T
#define NJ    25
#define NKEEP 17
#define NDRP  8
#define NL    19
#define NROW  192000    // NT*J == N*J*T
#define NTT   120
#define RSP   24        // padded rows per r in spatial block

typedef __attribute__((ext_vector_type(8))) short bf16x8;
typedef __attribute__((ext_vector_type(4))) float f32x4;

__device__ __forceinline__ float gelu_exact(float v){
    return 0.5f * v * (1.0f + erff(v * 0.70710678118654752440f));
}
__device__ __forceinline__ unsigned short f2bf(float v){
    union { __hip_bfloat16 h; unsigned short u; } c;
    c.h = __float2bfloat16(v);
    return c.u;
}
__device__ __forceinline__ float bf2f(unsigned short u){
    union { unsigned u; float f; } a; a.u = ((unsigned)u) << 16; return a.f;
}

// ---------------------------------------------------------------- weight prep + token selection in ONE launch
// blocks [0,320): weight cast/fold/transpose; blocks [320,350): per-row selection sort
__global__ void k_prep2(const float* __restrict__ s_in_w, const float* __restrict__ s_out_w,
                        const float* __restrict__ s_f1w,  const float* __restrict__ s_f2w,
                        const float* __restrict__ t_in_w, const float* __restrict__ t_out_w,
                        const float* __restrict__ t_f1w,  const float* __restrict__ t_f2w,
                        const float* __restrict__ gcnw,
                        const float* __restrict__ sn1w,   const float* __restrict__ sn2w,
                        unsigned short* __restrict__ WM,
                        const float* __restrict__ sc, int* __restrict__ order,
                        int* __restrict__ slot, float* __restrict__ ph)
{
    if (blockIdx.x < 320){
        int i = blockIdx.x * 256 + threadIdx.x;
        if (i < 65536){
            const float* src;
            const float* nw = nullptr;
            int base;
            if      (i < 12288){ src = s_in_w;  base = 0;     nw = sn1w; }
            else if (i < 16384){ src = s_out_w; base = 12288; }
            else if (i < 24576){ src = s_f1w;   base = 16384; nw = sn2w; }
            else if (i < 32768){ src = s_f2w;   base = 24576; }
            else if (i < 45056){ src = t_in_w;  base = 32768; }
            else if (i < 49152){ src = t_out_w; base = 45056; }
            else if (i < 57344){ src = t_f1w;   base = 49152; }
            else               { src = t_f2w;   base = 57344; }
            int loc = i - base;
            float4 v = *(const float4*)(src + loc * 4);
            if (nw){
                float4 w = *(const float4*)(nw + ((loc * 4) & 127));
                v.x *= w.x; v.y *= w.y; v.z *= w.z; v.w *= w.w;
            }
            ushort4 o; o.x = f2bf(v.x); o.y = f2bf(v.y); o.z = f2bf(v.z); o.w = f2bf(v.w);
            *(ushort4*)(WM + i * 4) = o;
        } else if (i < 81920){
            int j = i - 65536;                 // gcn transpose: 16384 elems
            int d = j >> 7, c = j & 127;
            WM[262144 + d * 128 + c] = f2bf(gcnw[c * 128 + d]);
        }
    } else {
        int r = (blockIdx.x - 320) * 256 + threadIdx.x;
        if (r >= NTR) return;
        float s[NJ]; int id[NJ];
        for (int j = 0; j < NJ; j++){ s[j] = sc[r * NJ + j]; id[j] = j; }
        for (int m = 1; m < NJ; m++){
            float sv = s[m]; int iv = id[m]; int p = m;
            while (p > 0 && s[p-1] < sv){ s[p] = s[p-1]; id[p] = id[p-1]; p--; }
            s[p] = sv; id[p] = iv;
        }
        for (int j = 0; j < NJ; j++) order[r * NJ + j] = id[j];
        for (int i = 0; i < NKEEP; i++)  slot[r * NJ + id[i]] = 1 + i;
        for (int i = NKEEP; i < NJ; i++) slot[r * NJ + id[i]] = 18;
        float m8 = s[NKEEP];
        float e[NDRP]; float sum = 0.f;
        for (int i = 0; i < NDRP; i++){ e[i] = expf(s[NKEEP + i] - m8); sum += e[i]; }
        float inv = 1.f / sum;
        for (int i = 0; i < NDRP; i++) ph[r * NDRP + i] = e[i] * inv;
    }
}

// ---------------------------------------------------------------- spatial transformer v9: fused GCN phase-0
// sm u16 layout: xs[48][136] | U1: xstage[64][136]/Pb[8][32][40] | U3: xgl[50][136]/qk[48][264] |
//                U2: vT[8][32][40] / ao[48][136]
__global__ __launch_bounds__(512, 4) void k_spatial9(
    const float* __restrict__ x, const unsigned short* __restrict__ GWt, const float* __restrict__ gnw,
    const int* __restrict__ order, const float* __restrict__ ph,
    const float* __restrict__ cls_tok,
    const unsigned short* __restrict__ WinB, const float* __restrict__ inb,
    const unsigned short* __restrict__ WoutB, const float* __restrict__ outb,
    const unsigned short* __restrict__ F1B, const float* __restrict__ f1b,
    const unsigned short* __restrict__ F2B, const float* __restrict__ f2b,
    unsigned short* __restrict__ xg_out,
    unsigned short* __restrict__ delta, float* __restrict__ next_attn)
{
    __shared__ __align__(16) unsigned short sm[39680];
    __shared__ float rstd[48];
    __shared__ float ss2[48];
    __shared__ float clsp[8][20];      // attention cls-probs; ALSO gss[64] scratch in phase-0
    __shared__ int   ord_s[2][NJ];
    __shared__ float ph_s[2][NDRP];
    unsigned short* xs     = sm;             // [48][136] x_slow -> x_msa
    unsigned short* xstage = sm + 6528;      // [64][136] phase-0 staging (overlays Pb)
    unsigned short* Pb     = sm + 6528;      // [8][32][40]
    unsigned short* xgl    = sm + 16768;     // [50][136] gcn output (overlays qk)
    unsigned short* qk     = sm + 16768;     // [48][264]
    unsigned short* vT     = sm + 29440;     // [8][32][40]
    unsigned short* ao     = sm + 29440;     // [48][136] overlays vT
    float* gss = &clsp[0][0];                // [64] gcn rms scratch

    int tid = threadIdx.x;
    int r0 = blockIdx.x * 2;
    int wv = tid >> 6, lane = tid & 63, cl = lane & 15, g = lane >> 4;
    const float scale = 0.17677669529663687f;

    if (tid < 2*NJ)   ord_s[tid/NJ][tid%NJ] = order[(r0 + tid/NJ)*NJ + tid%NJ];
    if (tid < 2*NDRP) ph_s[tid>>3][tid&7]   = ph[(r0 + (tid>>3))*NDRP + (tid&7)];
    if (tid < 48) ss2[tid] = 0.f;
    if (tid < 64) gss[tid] = 0.f;
    for (int i = tid; i < 1280; i += 512)
        *(uint4*)(vT + i*8) = make_uint4(0,0,0,0);   // zero U2 (pad keys must be 0)

    // ---- phase 0a: stage x (f32 -> bf16) rows 0..49, zero pad rows 50..63 ----
    {
        const float* xr = x + (size_t)r0 * NJ * 128;
        for (int i = tid; i < 2048; i += 512){
            int row = i >> 5, ch = i & 31;
            ushort4 u;
            if (row < 50){
                float4 v = *(const float4*)(xr + row*128 + ch*4);
                u.x = f2bf(v.x); u.y = f2bf(v.y); u.z = f2bf(v.z); u.w = f2bf(v.w);
            } else { u.x = 0; u.y = 0; u.z = 0; u.w = 0; }
            *(ushort4*)(xstage + row*136 + ch*4) = u;
        }
    }
    __syncthreads();   // ord_s/ph_s/gss/xstage visible

    // ---- phase 0b: GCN GEMM (B resident, col-tile = wv) + fused RMS stats ----
    f32x4 gacc[4];
    {
        int col = wv*16 + cl;
        bf16x8 Bg[4];
        #pragma unroll
        for (int ks = 0; ks < 4; ks++)
            Bg[ks] = *(const bf16x8*)(GWt + col*128 + ks*32 + g*8);
        #pragma unroll
        for (int rt = 0; rt < 4; rt++){
            bf16x8 A[4];
            #pragma unroll
            for (int ks = 0; ks < 4; ks++)
                A[ks] = *(const bf16x8*)(xstage + (rt*16 + cl)*136 + ks*32 + g*8);
            f32x4 acc = {0,0,0,0};
            #pragma unroll
            for (int ks = 0; ks < 4; ks++)
                acc = __builtin_amdgcn_mfma_f32_16x16x32_bf16(A[ks], Bg[ks], acc, 0, 0, 0);
            gacc[rt] = acc;
            #pragma unroll
            for (int reg = 0; reg < 4; reg++){
                int row = rt*16 + g*4 + reg;
                float p = acc[reg] * acc[reg];
                p += __shfl_xor(p, 1, 64); p += __shfl_xor(p, 2, 64);
                p += __shfl_xor(p, 4, 64); p += __shfl_xor(p, 8, 64);
                if (cl == 0) atomicAdd(&gss[row], p);
            }
        }
    }
    __syncthreads();
    if (tid < 64) gss[tid] = rsqrtf(gss[tid] * 0.0078125f + 1e-6f);
    __syncthreads();
    // ---- phase 0c: apply gnw * rstd -> xgl (LDS) ----
    {
        int col = wv*16 + cl;
        float gw = gnw[col];
        #pragma unroll
        for (int rt = 0; rt < 4; rt++){
            #pragma unroll
            for (int reg = 0; reg < 4; reg++){
                int row = rt*16 + g*4 + reg;
                if (row < 50)
                    xgl[row*136 + col] = f2bf(gacc[rt][reg] * gss[row] * gw);
            }
        }
    }
    __syncthreads();   // xgl complete

    // ---- phase 0d: vectorized copy xgl -> global XG (for k_scatter3) ----
    {
        unsigned short* dst = xg_out + (size_t)r0 * NJ * 128;
        for (int i = tid; i < 1600; i += 512){   // 50 rows x 32 quads
            int row = i >> 5, ch = i & 31;
            *(ushort4*)(dst + row*128 + ch*4) = *(const ushort4*)(xgl + row*136 + ch*4);
        }
    }

    // ---- build x_slow (gather from LDS xgl) + fused rmsnorm1 stats (32 lanes per row) ----
    {
        int ln = tid & 31;
        for (int j = tid >> 5; j < 48; j += 16){
            int rr = j / RSP, t = j - rr * RSP;
            const unsigned short* xgr = xgl + rr * NJ * 136;
            float v0, v1, v2, v3;
            if (t == 0){
                float4 cv = *(const float4*)(cls_tok + ln*4);
                v0 = cv.x; v1 = cv.y; v2 = cv.z; v3 = cv.w;
            } else if (t <= NKEEP){
                ushort4 u = *(const ushort4*)(xgr + ord_s[rr][t-1]*136 + ln*4);
                v0 = bf2f(u.x); v1 = bf2f(u.y); v2 = bf2f(u.z); v3 = bf2f(u.w);
            } else if (t == 18){
                v0 = v1 = v2 = v3 = 0.f;
                for (int i = 0; i < NDRP; i++){
                    ushort4 u = *(const ushort4*)(xgr + ord_s[rr][NKEEP+i]*136 + ln*4);
                    float w = ph_s[rr][i];
                    v0 = fmaf(bf2f(u.x),w,v0); v1 = fmaf(bf2f(u.y),w,v1);
                    v2 = fmaf(bf2f(u.z),w,v2); v3 = fmaf(bf2f(u.w),w,v3);
                }
            } else { v0 = v1 = v2 = v3 = 0.f; }
            ushort4 o4; o4.x=f2bf(v0); o4.y=f2bf(v1); o4.z=f2bf(v2); o4.w=f2bf(v3);
            *(ushort4*)(xs + j*136 + ln*4) = o4;
            float p = v0*v0 + v1*v1 + v2*v2 + v3*v3;
            p += __shfl_xor(p, 1, 64); p += __shfl_xor(p, 2, 64);
            p += __shfl_xor(p, 4, 64); p += __shfl_xor(p, 8, 64);
            p += __shfl_xor(p, 16, 64);
            if (ln == 0) rstd[j] = rsqrtf(p * 0.0078125f + 1e-6f);
        }
    }
    __syncthreads();   // xgl dead; qkv may overwrite qk region

    // ---- qkv GEMM on RAW xs (sn1w folded into WinB); epilogue scales by rstd[row] ----
    {
        int col = wv*16 + cl;
        bf16x8 Bq[4], Bk[4], Bv[4];
        #pragma unroll
        for (int ks = 0; ks < 4; ks++){
            Bq[ks] = *(const bf16x8*)(WinB + col*128        + ks*32 + g*8);
            Bk[ks] = *(const bf16x8*)(WinB + (128+col)*128  + ks*32 + g*8);
            Bv[ks] = *(const bf16x8*)(WinB + (256+col)*128  + ks*32 + g*8);
        }
        float bq = inb[col], bk = inb[128+col], bv = inb[256+col];
        int h = col >> 5, d = col & 31;
        #pragma unroll
        for (int rt = 0; rt < 3; rt++){
            bf16x8 A[4];
            #pragma unroll
            for (int ks = 0; ks < 4; ks++)
                A[ks] = *(const bf16x8*)(xs + (rt*16 + cl)*136 + ks*32 + g*8);
            f32x4 aq = {0,0,0,0}, ak = {0,0,0,0}, av = {0,0,0,0};
            #pragma unroll
            for (int ks = 0; ks < 4; ks++){
                aq = __builtin_amdgcn_mfma_f32_16x16x32_bf16(A[ks], Bq[ks], aq, 0, 0, 0);
                ak = __builtin_amdgcn_mfma_f32_16x16x32_bf16(A[ks], Bk[ks], ak, 0, 0, 0);
                av = __builtin_amdgcn_mfma_f32_16x16x32_bf16(A[ks], Bv[ks], av, 0, 0, 0);
            }
            #pragma unroll
            for (int reg = 0; reg < 4; reg++){
                int row = rt*16 + g*4 + reg;
                float rs = rstd[row];
                qk[row*264 + col]       = f2bf((aq[reg]*rs + bq) * scale);
                qk[row*264 + 128 + col] = f2bf(ak[reg]*rs + bk);
                int rr = row >= RSP; int key = row - rr*RSP;
                vT[(rr*4 + h)*1280 + d*40 + key] = f2bf(av[reg]*rs + bv);
            }
        }
    }
    __syncthreads();

    // ---- attention: 1 (rr,h) pair per wave; P region is per-wave -> NO mid barrier ----
    {
        int qh = wv;
        int rr = qh >> 2, h = qh & 3;
        bf16x8 aq[2];
        #pragma unroll
        for (int qt = 0; qt < 2; qt++)
            aq[qt] = *(const bf16x8*)(qk + (rr*RSP + qt*16 + cl)*264 + h*32 + g*8);
        f32x4 lg[2][2];
        #pragma unroll
        for (int kt = 0; kt < 2; kt++){
            bf16x8 bk = *(const bf16x8*)(qk + (rr*RSP + kt*16 + cl)*264 + 128 + h*32 + g*8);
            f32x4 z = {0.f, 0.f, 0.f, 0.f};
            lg[0][kt] = __builtin_amdgcn_mfma_f32_16x16x32_bf16(aq[0], bk, z, 0, 0, 0);
            lg[1][kt] = __builtin_amdgcn_mfma_f32_16x16x32_bf16(aq[1], bk, z, 0, 0, 0);
        }
        #pragma unroll
        for (int qt = 0; qt < 2; qt++){
            #pragma unroll
            for (int reg = 0; reg < 4; reg++){
                float l0 = lg[qt][0][reg];
                float l1 = (cl >= 3) ? -1e30f : lg[qt][1][reg];
                float m = fmaxf(l0, l1);
                m = fmaxf(m, __shfl_xor(m, 1, 64));
                m = fmaxf(m, __shfl_xor(m, 2, 64));
                m = fmaxf(m, __shfl_xor(m, 4, 64));
                m = fmaxf(m, __shfl_xor(m, 8, 64));
                float e0 = __expf(l0 - m), e1 = __expf(l1 - m);
                float ssum = e0 + e1;
                ssum += __shfl_xor(ssum, 1, 64); ssum += __shfl_xor(ssum, 2, 64);
                ssum += __shfl_xor(ssum, 4, 64); ssum += __shfl_xor(ssum, 8, 64);
                float inv = 1.f / ssum;
                e0 *= inv; e1 *= inv;
                int q = qt*16 + g*4 + reg;
                Pb[qh*1280 + q*40 + cl]      = f2bf(e0);
                Pb[qh*1280 + q*40 + 16 + cl] = f2bf(e1);
                if (qt == 0 && g == 0 && reg == 0){
                    clsp[qh][cl] = e0;
                    if (cl < 4) clsp[qh][16 + cl] = e1;
                }
            }
        }
        // no barrier: Pb[qh] and vT[qh] consumed only by this wave; PV writes only
        // the qk columns (h*32..) that this wave alone read as Q.
        bf16x8 ap[2];
        #pragma unroll
        for (int qt = 0; qt < 2; qt++)
            ap[qt] = *(const bf16x8*)(Pb + qh*1280 + (qt*16 + cl)*40 + g*8);
        #pragma unroll
        for (int dt = 0; dt < 2; dt++){
            bf16x8 bv = *(const bf16x8*)(vT + qh*1280 + (dt*16 + cl)*40 + g*8);
            #pragma unroll
            for (int qt = 0; qt < 2; qt++){
                f32x4 z = {0.f, 0.f, 0.f, 0.f};
                f32x4 oa = __builtin_amdgcn_mfma_f32_16x16x32_bf16(ap[qt], bv, z, 0, 0, 0);
                #pragma unroll
                for (int reg = 0; reg < 4; reg++){
                    int q = qt*16 + g*4 + reg;
                    if (q < 19)
                        qk[(rr*RSP + q)*264 + h*32 + dt*16 + cl] = f2bf(oa[reg]);
                    else if (q < RSP)
                        qk[(rr*RSP + q)*264 + h*32 + dt*16 + cl] = 0;
                }
            }
        }
        __syncthreads();
    }

    // ---- next_attn ----
    if (tid < 36){
        int rr2 = tid / 18, t = tid - rr2*18;
        float v = 0.25f * (clsp[rr2*4+0][1+t] + clsp[rr2*4+1][1+t] +
                           clsp[rr2*4+2][1+t] + clsp[rr2*4+3][1+t]);
        int r = r0 + rr2;
        if (t < NKEEP) next_attn[r*NJ + ord_s[rr2][t]] = v;
        else { for (int i = 0; i < NDRP; i++) next_attn[r*NJ + ord_s[rr2][NKEEP+i]] = v; }
    }

    // ---- out-proj: B resident; fused rmsnorm2 stats on x_msa ----
    {
        int col = wv*16 + cl;
        bf16x8 B[4];
        #pragma unroll
        for (int ks = 0; ks < 4; ks++)
            B[ks] = *(const bf16x8*)(WoutB + col*128 + ks*32 + g*8);
        float bias = outb[col];
        #pragma unroll
        for (int rt = 0; rt < 3; rt++){
            bf16x8 A[4];
            #pragma unroll
            for (int ks = 0; ks < 4; ks++)
                A[ks] = *(const bf16x8*)(qk + (rt*16 + cl)*264 + ks*32 + g*8);
            f32x4 acc = {0,0,0,0};
            #pragma unroll
            for (int ks = 0; ks < 4; ks++)
                acc = __builtin_amdgcn_mfma_f32_16x16x32_bf16(A[ks], B[ks], acc, 0, 0, 0);
            #pragma unroll
            for (int reg = 0; reg < 4; reg++){
                int row = rt*16 + g*4 + reg;
                float v = acc[reg] + bias;
                float msa = bf2f(xs[row*136 + col]) + v;
                ao[row*136 + col] = f2bf(v);
                xs[row*136 + col] = f2bf(msa);
                float p = msa * msa;
                p += __shfl_xor(p, 1, 64); p += __shfl_xor(p, 2, 64);
                p += __shfl_xor(p, 4, 64); p += __shfl_xor(p, 8, 64);
                if (cl == 0) atomicAdd(&ss2[row], p);
            }
        }
    }
    __syncthreads();

    if (tid < 48) rstd[tid] = rsqrtf(ss2[tid] * 0.0078125f + 1e-6f);
    __syncthreads();

    // ---- ffn1 + gelu on RAW x_msa (sn2w folded into F1B); epilogue scales by rstd[row] ----
    {
        int c0 = wv*16 + cl, c1 = c0 + 128;
        bf16x8 B0[4], B1[4];
        #pragma unroll
        for (int ks = 0; ks < 4; ks++){
            B0[ks] = *(const bf16x8*)(F1B + c0*128 + ks*32 + g*8);
            B1[ks] = *(const bf16x8*)(F1B + c1*128 + ks*32 + g*8);
        }
        float b0 = f1b[c0], b1 = f1b[c1];
        #pragma unroll
        for (int rt = 0; rt < 3; rt++){
            bf16x8 A[4];
            #pragma unroll
            for (int ks = 0; ks < 4; ks++)
                A[ks] = *(const bf16x8*)(xs + (rt*16 + cl)*136 + ks*32 + g*8);
            f32x4 a0 = {0,0,0,0}, a1 = {0,0,0,0};
            #pragma unroll
            for (int ks = 0; ks < 4; ks++){
                a0 = __builtin_amdgcn_mfma_f32_16x16x32_bf16(A[ks], B0[ks], a0, 0, 0, 0);
                a1 = __builtin_amdgcn_mfma_f32_16x16x32_bf16(A[ks], B1[ks], a1, 0, 0, 0);
            }
            #pragma unroll
            for (int reg = 0; reg < 4; reg++){
                int row = rt*16 + g*4 + reg;
                float rs = rstd[row];
                qk[row*264 + c0] = f2bf(gelu_exact(a0[reg]*rs + b0));
                qk[row*264 + c1] = f2bf(gelu_exact(a1[reg]*rs + b1));
            }
        }
    }
    __syncthreads();

    // ---- ffn2 + delta: B resident (8 k-slices) ----
    {
        int col = wv*16 + cl;
        bf16x8 B[8];
        #pragma unroll
        for (int ks = 0; ks < 8; ks++)
            B[ks] = *(const bf16x8*)(F2B + col*256 + ks*32 + g*8);
        float bias = f2b[col];
        #pragma unroll
        for (int rt = 0; rt < 3; rt++){
            bf16x8 A[8];
            #pragma unroll
            for (int ks = 0; ks < 8; ks++)
                A[ks] = *(const bf16x8*)(qk + (rt*16 + cl)*264 + ks*32 + g*8);
            f32x4 acc = {0,0,0,0};
            #pragma unroll
            for (int ks = 0; ks < 8; ks++)
                acc = __builtin_amdgcn_mfma_f32_16x16x32_bf16(A[ks], B[ks], acc, 0, 0, 0);
            #pragma unroll
            for (int reg = 0; reg < 4; reg++){
                int row = rt*16 + g*4 + reg;
                int rr = row >= RSP; int tok = row - rr*RSP;
                if (tok < 19){
                    float dv = acc[reg] + bias + bf2f(ao[row*136 + col]);
                    delta[((size_t)(r0 + rr)*19 + tok)*128 + col] = f2bf(dv);
                }
            }
        }
    }
}

// ---------------------------------------------------------------- scatter: 2 quads/thread (same row)
__global__ void k_scatter3(const unsigned short* __restrict__ xg, const unsigned short* __restrict__ delta,
                           const int* __restrict__ slot, unsigned short* __restrict__ xb){
    int i = blockIdx.x * 256 + threadIdx.x;   // 3,072,000 threads x 8 elems
    int e = i * 8;
    int c = e & 127; int rem = e >> 7;
    int t = rem % NTT; int nj = rem / NTT; int j = nj % NJ; int n = nj / NJ;
    int r = n * NTT + t;
    int sl = slot[r * NJ + j];
    const unsigned short* xp = xg + ((size_t)r * NJ + j) * 128 + c;
    const unsigned short* dp = delta + ((size_t)r * 19 + sl) * 128 + c;
    unsigned short* op = xb + e;
    #pragma unroll
    for (int q = 0; q < 2; q++){
        ushort4 xv = *(const ushort4*)(xp + q*4);
        ushort4 dv = *(const ushort4*)(dp + q*4);
        ushort4 ob;
        ob.x = f2bf(2.f * bf2f(xv.x) + bf2f(dv.x));
        ob.y = f2bf(2.f * bf2f(xv.y) + bf2f(dv.y));
        ob.z = f2bf(2.f * bf2f(xv.z) + bf2f(dv.z));
        ob.w = f2bf(2.f * bf2f(xv.w) + bf2f(dv.w));
        *(ushort4*)(op + q*4) = ob;
    }
}

// ---------------------------------------------------------------- temporal attention: 4 waves per (nj, head), bf16 out
// P region is per-wave -> NO barriers in the attention loop (waves drift freely)
__global__ __launch_bounds__(256, 3) void k_tattn2(
    const unsigned short* __restrict__ xb, const unsigned short* __restrict__ Wb,
    const float* __restrict__ inb, unsigned short* __restrict__ o)
{
    // LDS u16: q[120][40] | k[120][40] | vT[32][136] | P[4][16][136] = 45,312 B
    __shared__ __align__(16) unsigned short smem[22656];
    unsigned short* q_s = smem;
    unsigned short* k_s = smem + 4800;
    unsigned short* vT  = smem + 9600;
    unsigned short* P_s = smem + 13952;

    int tid = threadIdx.x;
    int l = tid & 63, cl = l & 15, g = l >> 4, wv = tid >> 6;
    int nj = blockIdx.x >> 2;
    int h  = blockIdx.x & 3;

    vT[(tid >> 3) * 136 + 120 + (tid & 7)] = 0;   // zero pad key cols

    const unsigned short* xrow = xb + (size_t)nj * (NTT * 128);
    const float scale = 0.17677669529663687f;

    bf16x8 bfr[6][4];
    float bias[6];
    #pragma unroll
    for (int pc = 0; pc < 6; ++pc){
        int p = pc >> 1, s = pc & 1;
        int col = p * 128 + h * 32 + s * 16 + cl;
        bias[pc] = inb[col];
        #pragma unroll
        for (int ks = 0; ks < 4; ++ks)
            bfr[pc][ks] = *(const bf16x8*)(Wb + col * 128 + ks * 32 + g * 8);
    }

    for (int mt = wv; mt < 8; mt += 4){
        bf16x8 af[4];
        #pragma unroll
        for (int ks = 0; ks < 4; ++ks)
            af[ks] = *(const bf16x8*)(xrow + (mt * 16 + cl) * 128 + ks * 32 + g * 8);
        #pragma unroll
        for (int pc = 0; pc < 6; ++pc){
            f32x4 acc = {0.f, 0.f, 0.f, 0.f};
            #pragma unroll
            for (int ks = 0; ks < 4; ++ks)
                acc = __builtin_amdgcn_mfma_f32_16x16x32_bf16(af[ks], bfr[pc][ks], acc, 0, 0, 0);
            int p = pc >> 1, s = pc & 1;
            int d = s * 16 + cl;
            #pragma unroll
            for (int reg = 0; reg < 4; ++reg){
                int t = mt * 16 + g * 4 + reg;
                if (t < NTT){
                    float v = acc[reg] + bias[pc];
                    if (p == 0)      q_s[t * 40 + d] = f2bf(v * scale);
                    else if (p == 1) k_s[t * 40 + d] = f2bf(v);
                    else             vT[d * 136 + t] = f2bf(v);
                }
            }
        }
    }
    __syncthreads();   // q/k/vT stable from here; below only per-wave P region is touched

    for (int s = 0; s < 2; ++s){
        int mt = wv + s * 4;
        bf16x8 aq = *(const bf16x8*)(q_s + (mt * 16 + cl) * 40 + g * 8);
        f32x4 lg[8];
        #pragma unroll
        for (int jt = 0; jt < 8; ++jt){
            bf16x8 bk = *(const bf16x8*)(k_s + (jt * 16 + cl) * 40 + g * 8);
            f32x4 z = {0.f, 0.f, 0.f, 0.f};
            lg[jt] = __builtin_amdgcn_mfma_f32_16x16x32_bf16(aq, bk, z, 0, 0, 0);
        }
        if (cl >= 8){ lg[7][0] = -1e30f; lg[7][1] = -1e30f; lg[7][2] = -1e30f; lg[7][3] = -1e30f; }

        float inv[4];
        #pragma unroll
        for (int reg = 0; reg < 4; ++reg){
            float m = lg[0][reg];
            #pragma unroll
            for (int jt = 1; jt < 8; ++jt) m = fmaxf(m, lg[jt][reg]);
            m = fmaxf(m, __shfl_xor(m, 1, 64));
            m = fmaxf(m, __shfl_xor(m, 2, 64));
            m = fmaxf(m, __shfl_xor(m, 4, 64));
            m = fmaxf(m, __shfl_xor(m, 8, 64));
            float sum = 0.f;
            #pragma unroll
            for (int jt = 0; jt < 8; ++jt){ float e = __expf(lg[jt][reg] - m); lg[jt][reg] = e; sum += e; }
            sum += __shfl_xor(sum, 1, 64); sum += __shfl_xor(sum, 2, 64);
            sum += __shfl_xor(sum, 4, 64); sum += __shfl_xor(sum, 8, 64);
            inv[reg] = 1.f / sum;
        }

        unsigned short* Pw = P_s + wv * 2176;   // per-wave region: no barriers needed
        #pragma unroll
        for (int jt = 0; jt < 8; ++jt){
            #pragma unroll
            for (int reg = 0; reg < 4; ++reg)
                Pw[(g * 4 + reg) * 136 + jt * 16 + cl] = f2bf(lg[jt][reg] * inv[reg]);
        }

        bf16x8 ap[4];
        #pragma unroll
        for (int ks = 0; ks < 4; ++ks)
            ap[ks] = *(const bf16x8*)(Pw + cl * 136 + ks * 32 + g * 8);
        #pragma unroll
        for (int nt = 0; nt < 2; ++nt){
            f32x4 oacc = {0.f, 0.f, 0.f, 0.f};
            #pragma unroll
            for (int ks = 0; ks < 4; ++ks){
                bf16x8 bv = *(const bf16x8*)(vT + (nt * 16 + cl) * 136 + ks * 32 + g * 8);
                oacc = __builtin_amdgcn_mfma_f32_16x16x32_bf16(ap[ks], bv, oacc, 0, 0, 0);
            }
            #pragma unroll
            for (int reg = 0; reg < 4; ++reg){
                int t = mt * 16 + g * 4 + reg;
                if (t < NTT)
                    o[((size_t)nj * NTT + t) * 128 + h * 32 + nt * 16 + cl] = f2bf(oacc[reg]);
            }
        }
    }
}

// ---------------------------------------------------------------- fused temporal MLP block
__global__ __launch_bounds__(256, 4) void k_tblock(
    const unsigned short* __restrict__ o, const unsigned short* __restrict__ WoB,
    const float* __restrict__ ob, const unsigned short* __restrict__ xbres,
    const float* __restrict__ lnw, const float* __restrict__ lnb,
    const unsigned short* __restrict__ F1B, const float* __restrict__ f1b,
    const unsigned short* __restrict__ F2B, const float* __restrict__ f2b,
    const float* __restrict__ ln2w, const float* __restrict__ ln2b,
    const float* __restrict__ tnw, const float* __restrict__ x,
    float* __restrict__ out)
{
    __shared__ __align__(16) float yf[32 * 132];            // also hb u16[32][264], then yf2
    __shared__ __align__(16) unsigned short xbuf[32 * 136];
    __shared__ int xib[32];
    int tid = threadIdx.x, wv = tid >> 6, lane = tid & 63, cl = lane & 15, g = lane >> 4;
    size_t row0 = (size_t)blockIdx.x * 32;

    if (tid < 32){
        int grow = (int)row0 + tid;
        int t = grow % NTT; int njq = grow / NTT; int j = njq % NJ; int n = njq / NJ;
        xib[tid] = ((n * NTT + t) * NJ + j) * 128;
    }

    // ---- phase 1: out-proj + residual -> yf ----
    {
        int c0 = wv*16 + cl, c1 = c0 + 64;
        bf16x8 B0[4], B1[4];
        #pragma unroll
        for (int ks = 0; ks < 4; ks++){
            B0[ks] = *(const bf16x8*)(WoB + c0*128 + ks*32 + g*8);
            B1[ks] = *(const bf16x8*)(WoB + c1*128 + ks*32 + g*8);
        }
        float b0 = ob[c0], b1 = ob[c1];
        #pragma unroll
        for (int rt = 0; rt < 2; rt++){
            bf16x8 A[4];
            #pragma unroll
            for (int ks = 0; ks < 4; ks++)
                A[ks] = *(const bf16x8*)(o + (row0 + rt*16 + cl)*128 + ks*32 + g*8);
            f32x4 a0 = {0,0,0,0}, a1 = {0,0,0,0};
            #pragma unroll
            for (int ks = 0; ks < 4; ks++){
                a0 = __builtin_amdgcn_mfma_f32_16x16x32_bf16(A[ks], B0[ks], a0, 0, 0, 0);
                a1 = __builtin_amdgcn_mfma_f32_16x16x32_bf16(A[ks], B1[ks], a1, 0, 0, 0);
            }
            #pragma unroll
            for (int reg = 0; reg < 4; reg++){
                int row = rt*16 + g*4 + reg;
                yf[row*132 + c0] = a0[reg] + b0 + bf2f(xbres[(row0 + row)*128 + c0]);
                yf[row*132 + c1] = a1[reg] + b1 + bf2f(xbres[(row0 + row)*128 + c1]);
            }
        }
    }
    __syncthreads();

    // ---- phase 2: LN1 stats + apply (8 lanes/row) -> xbuf ----
    {
        int row = tid >> 3, sub = tid & 7;
        float4 v[4];
        float s1 = 0.f, s2 = 0.f;
        #pragma unroll
        for (int k = 0; k < 4; k++){
            v[k] = *(const float4*)(yf + row*132 + sub*16 + k*4);
            s1 += v[k].x + v[k].y + v[k].z + v[k].w;
            s2 += v[k].x*v[k].x + v[k].y*v[k].y + v[k].z*v[k].z + v[k].w*v[k].w;
        }
        s1 += __shfl_xor(s1, 1, 64); s2 += __shfl_xor(s2, 1, 64);
        s1 += __shfl_xor(s1, 2, 64); s2 += __shfl_xor(s2, 2, 64);
        s1 += __shfl_xor(s1, 4, 64); s2 += __shfl_xor(s2, 4, 64);
        float m = s1 * 0.0078125f;
        float rv = rsqrtf(s2 * 0.0078125f - m*m + 1e-5f);
        #pragma unroll
        for (int k = 0; k < 4; k++){
            float4 w4 = *(const float4*)(lnw + sub*16 + k*4);
            float4 b4 = *(const float4*)(lnb + sub*16 + k*4);
            ushort4 u;
            u.x = f2bf((v[k].x - m) * rv * w4.x + b4.x);
            u.y = f2bf((v[k].y - m) * rv * w4.y + b4.y);
            u.z = f2bf((v[k].z - m) * rv * w4.z + b4.z);
            u.w = f2bf((v[k].w - m) * rv * w4.w + b4.w);
            *(ushort4*)(xbuf + row*136 + sub*16 + k*4) = u;
        }
    }
    __syncthreads();

    // ---- phase 3: FFN1 + gelu -> hb (overlays yf) ----
    unsigned short* hb = (unsigned short*)yf;   // [32][264]
    #pragma unroll
    for (int s = 0; s < 4; s++){
        int c = wv*16 + cl + s*64;
        bf16x8 B[4];
        #pragma unroll
        for (int ks = 0; ks < 4; ks++)
            B[ks] = *(const bf16x8*)(F1B + c*128 + ks*32 + g*8);
        float bias = f1b[c];
        #pragma unroll
        for (int rt = 0; rt < 2; rt++){
            bf16x8 A[4];
            #pragma unroll
            for (int ks = 0; ks < 4; ks++)
                A[ks] = *(const bf16x8*)(xbuf + (rt*16 + cl)*136 + ks*32 + g*8);
            f32x4 acc = {0,0,0,0};
            #pragma unroll
            for (int ks = 0; ks < 4; ks++)
                acc = __builtin_amdgcn_mfma_f32_16x16x32_bf16(A[ks], B[ks], acc, 0, 0, 0);
            #pragma unroll
            for (int reg = 0; reg < 4; reg++){
                int row = rt*16 + g*4 + reg;
                hb[row*264 + c] = f2bf(gelu_exact(acc[reg] + bias));
            }
        }
    }
    __syncthreads();

    // ---- phase 4: FFN2 into registers, then overlay-write yf2 ----
    float ys[2][2][4];
    #pragma unroll
    for (int s = 0; s < 2; s++){
        int c = wv*16 + cl + s*64;
        bf16x8 B[8];
        #pragma unroll
        for (int ks = 0; ks < 8; ks++)
            B[ks] = *(const bf16x8*)(F2B + c*256 + ks*32 + g*8);
        float bias = f2b[c];
        #pragma unroll
        for (int rt = 0; rt < 2; rt++){
            bf16x8 A[8];
            #pragma unroll
            for (int ks = 0; ks < 8; ks++)
                A[ks] = *(const bf16x8*)(hb + (rt*16 + cl)*264 + ks*32 + g*8);
            f32x4 acc = {0,0,0,0};
            #pragma unroll
            for (int ks = 0; ks < 8; ks++)
                acc = __builtin_amdgcn_mfma_f32_16x16x32_bf16(A[ks], B[ks], acc, 0, 0, 0);
            #pragma unroll
            for (int reg = 0; reg < 4; reg++){
                int row = rt*16 + g*4 + reg;
                ys[s][rt][reg] = acc[reg] + bias + bf2f(xbuf[row*136 + c]);
            }
        }
    }
    __syncthreads();
    #pragma unroll
    for (int s = 0; s < 2; s++){
        int c = wv*16 + cl + s*64;
        #pragma unroll
        for (int rt = 0; rt < 2; rt++)
            #pragma unroll
            for (int reg = 0; reg < 4; reg++)
                yf[(rt*16 + g*4 + reg)*132 + c] = ys[s][rt][reg];
    }
    __syncthreads();

    // ---- phase 5: LN2 + RMSNorm + residuals + final write ----
    {
        int row = tid >> 3, sub = tid & 7;
        float4 v[4];
        float s1 = 0.f, s2 = 0.f;
        #pragma unroll
        for (int k = 0; k < 4; k++){
            v[k] = *(const float4*)(yf + row*132 + sub*16 + k*4);
            s1 += v[k].x + v[k].y + v[k].z + v[k].w;
            s2 += v[k].x*v[k].x + v[k].y*v[k].y + v[k].z*v[k].z + v[k].w*v[k].w;
        }
        s1 += __shfl_xor(s1, 1, 64); s2 += __shfl_xor(s2, 1, 64);
        s1 += __shfl_xor(s1, 2, 64); s2 += __shfl_xor(s2, 2, 64);
        s1 += __shfl_xor(s1, 4, 64); s2 += __shfl_xor(s2, 4, 64);
        float m = s1 * 0.0078125f;
        float rv = rsqrtf(s2 * 0.0078125f - m*m + 1e-5f);
        float z[4][4];
        float s3 = 0.f;
        #pragma unroll
        for (int k = 0; k < 4; k++){
            float4 w4 = *(const float4*)(ln2w + sub*16 + k*4);
            float4 b4 = *(const float4*)(ln2b + sub*16 + k*4);
            z[k][0] = (v[k].x - m) * rv * w4.x + b4.x;
            z[k][1] = (v[k].y - m) * rv * w4.y + b4.y;
            z[k][2] = (v[k].z - m) * rv * w4.z + b4.z;
            z[k][3] = (v[k].w - m) * rv * w4.w + b4.w;
            s3 += z[k][0]*z[k][0] + z[k][1]*z[k][1] + z[k][2]*z[k][2] + z[k][3]*z[k][3];
        }
        s3 += __shfl_xor(s3, 1, 64); s3 += __shfl_xor(s3, 2, 64); s3 += __shfl_xor(s3, 4, 64);
        float sr = rsqrtf(s3 * 0.0078125f + 1e-6f);
        int xb0 = xib[row] + sub*16;
        #pragma unroll
        for (int k = 0; k < 4; k++){
            float4 tw4 = *(const float4*)(tnw + sub*16 + k*4);
            ushort4 xr = *(const ushort4*)(xbres + (row0 + row)*128 + sub*16 + k*4);
            float4 xv = *(const float4*)(x + xb0 + k*4);
            float4 ov;
            ov.x = z[k][0] * sr * tw4.x + bf2f(xr.x) + xv.x;
            ov.y = z[k][1] * sr * tw4.y + bf2f(xr.y) + xv.y;
            ov.z = z[k][2] * sr * tw4.z + bf2f(xr.z) + xv.z;
            ov.w = z[k][3] * sr * tw4.w + bf2f(xr.w) + xv.w;
            *(float4*)(out + xb0 + k*4) = ov;
        }
    }
}

// ================================================================ launch
extern "C" void kernel_launch(void* const* d_in, const int* in_sizes, int n_in,
                              void* d_out, int out_size, void* d_ws, size_t ws_size,
                              hipStream_t stream) {
    (void)in_sizes; (void)n_in; (void)out_size;
    const float* x      = (const float*)d_in[0];
    const float* sc     = (const float*)d_in[1];
    const float* gcnw   = (const float*)d_in[2];
    const float* gnw    = (const float*)d_in[3];
    const float* cls    = (const float*)d_in[4];
    const float* sn1    = (const float*)d_in[5];
    const float* sn2    = (const float*)d_in[6];
    const float* s_in_w = (const float*)d_in[7];
    const float* s_in_b = (const float*)d_in[8];
    const float* s_out_w= (const float*)d_in[9];
    const float* s_out_b= (const float*)d_in[10];
    const float* s_f1w  = (const float*)d_in[11];
    const float* s_f1b  = (const float*)d_in[12];
    const float* s_f2w  = (const float*)d_in[13];
    const float* s_f2b  = (const float*)d_in[14];
    const float* t_in_w = (const float*)d_in[15];
    const float* t_in_b = (const float*)d_in[16];
    const float* t_out_w= (const float*)d_in[17];
    const float* t_out_b= (const float*)d_in[18];
    const float* t_ln1w = (const float*)d_in[19];
    const float* t_ln1b = (const float*)d_in[20];
    const float* t_ln2w = (const float*)d_in[21];
    const float* t_ln2b = (const float*)d_in[22];
    const float* t_f1w  = (const float*)d_in[23];
    const float* t_f1b  = (const float*)d_in[24];
    const float* t_f2w  = (const float*)d_in[25];
    const float* t_f2b  = (const float*)d_in[26];
    const float* tnw    = (const float*)d_in[27];

    char* ws = (char*)d_ws;
    const size_t SZ_BIG = 98304000;                 // 192000*128*4
    char*  R1 = ws;                                 // xg (bf16)
    char*  R2 = ws + SZ_BIG;                        // o (bf16)
    char*  R3 = ws + 2 * SZ_BIG;                    // delta (bf16) | xb (bf16)
    char* p = ws + 3 * SZ_BIG;
    int*   ORD  = (int*)p;   p += 768000;
    int*   SLOT = (int*)p;   p += 768000;
    float* PH   = (float*)p; p += 245760;
    unsigned short* WM = (unsigned short*)p; p += 557056;
    if (ws_size < (size_t)(p - ws)) return;

    unsigned short* WinB  = WM;              // s_in_w·sn1w  [384][128]
    unsigned short* WoutB = WM + 49152;      // s_out_w [128][128]
    unsigned short* F1B   = WM + 65536;      // s_f1w·sn2w   [256][128]
    unsigned short* F2B   = WM + 98304;      // s_f2w   [128][256]
    unsigned short* WB    = WM + 131072;     // t_in_w  [384][128]
    unsigned short* WoBt  = WM + 180224;     // t_out_w [128][128]
    unsigned short* F1Bt  = WM + 196608;     // t_f1w   [256][128]
    unsigned short* F2Bt  = WM + 229376;     // t_f2w   [128][256]
    unsigned short* GWt   = WM + 262144;     // gcn_w[0]^T [128][128]

    unsigned short* XG  = (unsigned short*)R1;                    // xg bf16 [192000][128]
    unsigned short* DLT = (unsigned short*)R3;                    // delta [7680*19][128]
    unsigned short* XB  = (unsigned short*)(R3 + 37355520);       // xsp bf16 [192000][128]
    unsigned short* OB  = (unsigned short*)R2;                    // o bf16  [192000][128]

    float* out0 = (float*)d_out;
    float* next_attn = out0 + 24576000;

    k_prep2<<<350, 256, 0, stream>>>(s_in_w, s_out_w, s_f1w, s_f2w,
                                     t_in_w, t_out_w, t_f1w, t_f2w, gcnw,
                                     sn1, sn2, WM, sc, ORD, SLOT, PH);
    k_spatial9<<<3840, 512, 0, stream>>>(x, GWt, gnw, ORD, PH, cls,
                                         WinB, s_in_b, WoutB, s_out_b,
                                         F1B, s_f1b, F2B, s_f2b,
                                         XG, DLT, next_attn);
    k_scatter3<<<12000, 256, 0, stream>>>(XG, DLT, SLOT, XB);
    k_tattn2<<<6400, 256, 0, stream>>>(XB, WB, t_in_b, OB);
    k_tblock<<<6000, 256, 0, stream>>>(OB, WoBt, t_out_b, XB,
                                       t_ln1w, t_ln1b, F1Bt, t_f1b,
                                       F2Bt, t_f2b, t_ln2w, t_ln2b,
                                       tnw, x, out0);
}